// Round 3
// baseline (1144.542 us; speedup 1.0000x reference)
//
#include <hip/hip_runtime.h>
#include <stdint.h>

typedef uint16_t u16;
typedef __attribute__((ext_vector_type(8))) short short8;
typedef __attribute__((ext_vector_type(8))) unsigned short ushort8;
typedef __attribute__((ext_vector_type(4))) float f32x4;

__device__ __forceinline__ float b2f(u16 u){
  union{uint32_t i; float f;} v; v.i=((uint32_t)u)<<16; return v.f;
}
__device__ __forceinline__ u16 f2b(float f){
  union{uint32_t i; float f;} v; v.f=f;
  return (u16)((v.i + 0x7fffu + ((v.i>>16)&1u))>>16);
}

// ---------------- fp32 -> bf16 conversion (8 elems/thread) ----------------
__global__ void cvt_k(const float* in, u16* out, long n) {
  const long i = ((long)blockIdx.x*256 + threadIdx.x)*8;
  if (i >= n) return;
  float4 a = *(const float4*)&in[i];
  float4 b = *(const float4*)&in[i+4];
  ushort8 o;
  o[0]=f2b(a.x); o[1]=f2b(a.y); o[2]=f2b(a.z); o[3]=f2b(a.w);
  o[4]=f2b(b.x); o[5]=f2b(b.y); o[6]=f2b(b.z); o[7]=f2b(b.w);
  *(ushort8*)&out[i] = o;
}

// ---------------------------------------------------------------------------
// Generic NT GEMM on bf16 tiles: C = scale * A@B^T + bias. Batched over z.
// Tile 128x128, BK=32, 4 waves, mfma_f32_16x16x32_bf16, global_load_lds w16.
// bias is fp32; outf=1 writes fp32 C (final projection), else bf16.
// ---------------------------------------------------------------------------
struct GemmP {
  const u16* A; const u16* B; u16* C; const float* bias;
  long lda, ldb, ldc, aBz, bBz, cBz;
  int K, Nstore, act, outf;   // act: 0 none, 1 sigmoid
  float scale;
};

__global__ __launch_bounds__(256) void gemm_nt(GemmP p) {
  __shared__ __align__(16) u16 lA[4096];
  __shared__ __align__(16) u16 lB[4096];
  const int t = threadIdx.x;
  const int wave = t >> 6, lane = t & 63;
  const long z = blockIdx.z;
  const u16* A = p.A + z * p.aBz + (long)blockIdx.x * 128 * p.lda;
  const u16* B = p.B + z * p.bBz + (long)blockIdx.y * 128 * p.ldb;
  const int srow = t >> 2, skk = (t & 3) * 8;
  const int wr = wave >> 1, wc = wave & 1;
  const int fr = lane & 15, fk = (lane >> 4) * 8;
  f32x4 acc[4][4] = {};

  for (int k0 = 0; k0 < p.K; k0 += 32) {
    __syncthreads();   // protect LDS from previous iteration's readers
    #pragma unroll
    for (int i = 0; i < 2; ++i) {
      __builtin_amdgcn_global_load_lds(
        (const __attribute__((address_space(1))) void*)(A + (long)(i*64 + srow)*p.lda + k0 + skk),
        (__attribute__((address_space(3))) void*)&lA[(i*256 + wave*64)*8], 16, 0, 0);
      __builtin_amdgcn_global_load_lds(
        (const __attribute__((address_space(1))) void*)(B + (long)(i*64 + srow)*p.ldb + k0 + skk),
        (__attribute__((address_space(3))) void*)&lB[(i*256 + wave*64)*8], 16, 0, 0);
    }
    __syncthreads();   // drain vmcnt before fragment reads
    short8 av[4], bv[4];
    #pragma unroll
    for (int mi = 0; mi < 4; ++mi) av[mi] = *(const short8*)&lA[(wr*64 + mi*16 + fr)*32 + fk];
    #pragma unroll
    for (int ni = 0; ni < 4; ++ni) bv[ni] = *(const short8*)&lB[(wc*64 + ni*16 + fr)*32 + fk];
    #pragma unroll
    for (int mi = 0; mi < 4; ++mi)
      #pragma unroll
      for (int ni = 0; ni < 4; ++ni)
        acc[mi][ni] = __builtin_amdgcn_mfma_f32_16x16x32_bf16(av[mi], bv[ni], acc[mi][ni], 0, 0, 0);
  }

  const long cOff = z * p.cBz;
  const int rbase = blockIdx.x*128 + wr*64;
  const int cbase = blockIdx.y*128 + wc*64;
  const int rsub = (lane >> 4) * 4;
  #pragma unroll
  for (int ni = 0; ni < 4; ++ni) {
    const int col = cbase + ni*16 + fr;
    if (col >= p.Nstore) continue;
    const float bs = p.bias ? p.bias[col] : 0.f;
    #pragma unroll
    for (int mi = 0; mi < 4; ++mi) {
      #pragma unroll
      for (int j = 0; j < 4; ++j) {
        float v = acc[mi][ni][j] * p.scale + bs;
        if (p.act == 1) v = 1.f / (1.f + __expf(-v));
        const long idx = cOff + (long)(rbase + mi*16 + rsub + j) * p.ldc + col;
        if (p.outf) ((float*)p.C)[idx] = v;
        else        p.C[idx] = f2b(v);
      }
    }
  }
}

// ---------------- softmax over rows of 1024 (in-place, bf16) ----------------
__global__ void softmax_rows(u16* buf, int nrows) {
  const int wave = threadIdx.x >> 6, lane = threadIdx.x & 63;
  const int row = blockIdx.x * 4 + wave;
  if (row >= nrows) return;
  u16* r = buf + (long)row * 1024;
  ushort8 u0 = *(const ushort8*)&r[lane*8];
  ushort8 u1 = *(const ushort8*)&r[512 + lane*8];
  float v[16];
  #pragma unroll
  for (int i = 0; i < 8; ++i) { v[i] = b2f(u0[i]); v[8+i] = b2f(u1[i]); }
  float mx = -1e30f;
  #pragma unroll
  for (int i = 0; i < 16; ++i) mx = fmaxf(mx, v[i]);
  #pragma unroll
  for (int o = 32; o; o >>= 1) mx = fmaxf(mx, __shfl_xor(mx, o, 64));
  float s = 0.f;
  #pragma unroll
  for (int i = 0; i < 16; ++i) { v[i] = __expf(v[i] - mx); s += v[i]; }
  #pragma unroll
  for (int o = 32; o; o >>= 1) s += __shfl_xor(s, o, 64);
  const float inv = 1.f / s;
  ushort8 o0, o1;
  #pragma unroll
  for (int i = 0; i < 8; ++i) { o0[i] = f2b(v[i]*inv); o1[i] = f2b(v[8+i]*inv); }
  *(ushort8*)&r[lane*8] = o0;
  *(ushort8*)&r[512 + lane*8] = o1;
}

// ------- batched 2D transpose; blocks past validCols write zeros -------
struct TransP { const u16* in; u16* out; long inStride, outStride, inB, outB; int validCols; };
__global__ void transpose_k(TransP p) {
  __shared__ u16 tile[32][33];
  const u16* in = p.in + blockIdx.z * p.inB;
  u16* out = p.out + blockIdx.z * p.outB;
  const int tx = threadIdx.x & 31, ty = threadIdx.x >> 5;
  const int r0 = blockIdx.x * 32, c0 = blockIdx.y * 32;
  if (c0 < p.validCols) {
    #pragma unroll
    for (int i = 0; i < 32; i += 8)
      tile[ty + i][tx] = in[(long)(r0 + ty + i) * p.inStride + c0 + tx];
    __syncthreads();
    #pragma unroll
    for (int i = 0; i < 32; i += 8)
      out[(long)(c0 + ty + i) * p.outStride + r0 + tx] = tile[tx][ty + i];
  } else {
    #pragma unroll
    for (int i = 0; i < 32; i += 8)
      out[(long)(c0 + ty + i) * p.outStride + r0 + tx] = 0;
  }
}

// ---------------- summary-query projection: qs = sum_query @ wq^T + bq ------
__global__ void gemv_qs(const float* sq, const float* w, const float* b, float* out) {
  const int n = blockIdx.x * blockDim.x + threadIdx.x;   // 0..1023
  const float* row = w + (long)n * 1024;
  float s = 0.f;
  for (int k = 0; k < 1024; k += 4) {
    float4 ww = *(const float4*)&row[k];
    float4 qq = *(const float4*)&sq[k];
    s += qq.x*ww.x + qq.y*ww.y + qq.z*ww.z + qq.w*ww.w;
  }
  out[n] = s + b[n];
}

// ---------------- summarize attention: per (h, w) block of 64 threads -------
__global__ void sum_attend(const float* qs, const u16* sumkv, float* content, float* pall) {
  const int h = blockIdx.x, w = blockIdx.y, lane = threadIdx.x;
  __shared__ float qsh[64];
  __shared__ float sc[1024];
  qsh[lane] = qs[h*64 + lane];
  __syncthreads();
  const u16* kbase = sumkv + (long)w*1024*2048 + h*64;
  float loc[16];
  float mx = -1e30f;
  #pragma unroll
  for (int j = 0; j < 16; ++j) {
    const int k = j*64 + lane;
    const u16* krow = kbase + (long)k * 2048;
    float s = 0.f;
    for (int d = 0; d < 64; d += 8) {
      ushort8 kk = *(const ushort8*)&krow[d];
      #pragma unroll
      for (int q = 0; q < 8; ++q) s += qsh[d+q] * b2f(kk[q]);
    }
    s *= 0.125f;
    loc[j] = s;
    mx = fmaxf(mx, s);
  }
  #pragma unroll
  for (int o = 32; o; o >>= 1) mx = fmaxf(mx, __shfl_xor(mx, o, 64));
  float sum = 0.f;
  #pragma unroll
  for (int j = 0; j < 16; ++j) { loc[j] = __expf(loc[j] - mx); sum += loc[j]; }
  #pragma unroll
  for (int o = 32; o; o >>= 1) sum += __shfl_xor(sum, o, 64);
  const float inv = 1.f / sum;
  #pragma unroll
  for (int j = 0; j < 16; ++j) {
    const int k = j*64 + lane;
    const float pn = loc[j] * inv;
    sc[k] = pn;
    pall[((long)w*16 + h)*1024 + k] = pn;
  }
  __syncthreads();
  const u16* vbase = sumkv + (long)w*1024*2048 + 1024 + h*64;
  float o = 0.f;
  for (int k = 0; k < 1024; ++k) o += sc[k] * b2f(vbase[(long)k*2048 + lane]);
  content[(long)w*1024 + h*64 + lane] = o;
}

__global__ void wavg_k(const float* pall, float* wavg) {
  const int w = blockIdx.y, k = blockIdx.x*256 + threadIdx.x;
  float s = 0.f;
  #pragma unroll
  for (int h = 0; h < 16; ++h) s += pall[((long)w*16 + h)*1024 + k];
  wavg[w*1024 + k] = s * (1.f/16.f);
}

__global__ void contproj_k(const float* content, const float* w_, const float* b, float* out) {
  const int w = blockIdx.y, n = blockIdx.x*64 + threadIdx.x;
  const float* c = content + w*1024;
  const float* row = w_ + (long)n * 1024;
  float s = 0.f;
  for (int k = 0; k < 1024; k += 4) {
    float4 ww = *(const float4*)&row[k];
    s += c[k]*ww.x + c[k+1]*ww.y + c[k+2]*ww.z + c[k+3]*ww.w;
  }
  out[w*1024 + n] = s + b[n];
}

// ---------------- attn_stats: entropy, gini, max, top5 via rank counting ----
__global__ void stats_k(const float* wavg, float* stats) {
  const int w = blockIdx.x, t = threadIdx.x;
  __shared__ float a[1024];
  for (int i = t; i < 1024; i += 256) a[i] = wavg[w*1024 + i];
  __syncthreads();
  float ent = 0.f, gnum = 0.f, ssum = 0.f, mx = -1e30f, top5 = 0.f;
  for (int jj = 0; jj < 4; ++jj) {
    const int j = t*4 + jj;
    const float aj = a[j];
    int rank = 1;
    for (int i = 0; i < 1024; ++i) {
      const float ai = a[i];
      rank += (ai < aj) || (ai == aj && i < j);
    }
    ent -= aj * logf(aj + 1e-8f);
    gnum += (float)rank * aj;
    ssum += aj;
    mx = fmaxf(mx, aj);
    if (rank >= 1020) top5 += aj;
  }
  #pragma unroll
  for (int o = 32; o; o >>= 1) {
    ent += __shfl_xor(ent, o, 64);
    gnum += __shfl_xor(gnum, o, 64);
    ssum += __shfl_xor(ssum, o, 64);
    mx = fmaxf(mx, __shfl_xor(mx, o, 64));
    top5 += __shfl_xor(top5, o, 64);
  }
  __shared__ float rr[4][5];
  const int wv = t >> 6, ln = t & 63;
  if (ln == 0) { rr[wv][0]=ent; rr[wv][1]=gnum; rr[wv][2]=ssum; rr[wv][3]=mx; rr[wv][4]=top5; }
  __syncthreads();
  if (t == 0) {
    float E=0,G=0,S=0,M=-1e30f,T=0;
    for (int i = 0; i < 4; ++i) { E+=rr[i][0]; G+=rr[i][1]; S+=rr[i][2]; M=fmaxf(M,rr[i][3]); T+=rr[i][4]; }
    stats[w*4+0] = E;
    stats[w*4+1] = 2.f*G/(1024.f*S + 1e-8f) - 1025.f/1024.f;
    stats[w*4+2] = M;
    stats[w*4+3] = T;
  }
}

// ---------------- pat MLP + summary combine (fp32 weights) ----------------
__global__ void patsum_k(const float* stats, const float* contprj,
                         const float* pw1, const float* pb1, const float* pw2, const float* pb2,
                         const float* combw, const float* combb, float* summ) {
  const int w = blockIdx.x, t = threadIdx.x;   // 64 threads
  __shared__ float p1[64], pat[64];
  float s = 0.f;
  #pragma unroll
  for (int k = 0; k < 4; ++k) s += stats[w*4+k] * pw1[t*4+k];
  p1[t] = fmaxf(s + pb1[t], 0.f);
  __syncthreads();
  s = 0.f;
  for (int k = 0; k < 64; ++k) s += p1[k] * pw2[t*64+k];
  pat[t] = s + pb2[t];
  __syncthreads();
  const float* c = contprj + w*1024;
  const float* row = combw + (long)t * 1088;
  s = 0.f;
  for (int k = 0; k < 1024; ++k) s += c[k] * row[k];
  for (int k = 0; k < 64; ++k) s += pat[k] * row[1024+k];
  summ[w*64 + t] = s + combb[t];
}

// ---------------- meta attention + routing (1 block, 64 threads) ------------
__global__ void meta_k(const float* summ, const float* miw, const float* mib,
                       const float* mow, const float* mob, const float* rw1, const float* rb1,
                       const float* rw2, const float* rb2, float* routing) {
  const int t = threadIdx.x;
  __shared__ float qkv[4][192];
  __shared__ float sc[64];
  __shared__ float o[4][64];
  __shared__ float rf[4][64];
  __shared__ float t1[4][64];
  __shared__ float lg[4];
  for (int idx = t; idx < 768; idx += 64) {
    const int w = idx / 192, rrow = idx % 192;
    const float* rw = miw + (long)rrow * 64;
    float s = 0.f;
    for (int k = 0; k < 64; ++k) s += summ[w*64+k] * rw[k];
    qkv[w][rrow] = s + mib[rrow];
  }
  __syncthreads();
  {
    const int h = t >> 4, i = (t >> 2) & 3, j = t & 3;
    float s = 0.f;
    #pragma unroll
    for (int d = 0; d < 16; ++d) s += qkv[i][h*16+d] * qkv[j][64 + h*16+d];
    sc[t] = s * 0.25f;
  }
  __syncthreads();
  if (t < 16) {
    const float a0=sc[t*4], a1=sc[t*4+1], a2=sc[t*4+2], a3=sc[t*4+3];
    const float m = fmaxf(fmaxf(a0,a1), fmaxf(a2,a3));
    const float e0=__expf(a0-m), e1=__expf(a1-m), e2=__expf(a2-m), e3=__expf(a3-m);
    const float s = e0+e1+e2+e3;
    sc[t*4]=e0/s; sc[t*4+1]=e1/s; sc[t*4+2]=e2/s; sc[t*4+3]=e3/s;
  }
  __syncthreads();
  for (int idx = t; idx < 256; idx += 64) {
    const int i = idx >> 6, c = idx & 63, h = c >> 4;
    float s = 0.f;
    #pragma unroll
    for (int j = 0; j < 4; ++j) s += sc[(h*4+i)*4+j] * qkv[j][128 + c];
    o[i][c] = s;
  }
  __syncthreads();
  for (int idx = t; idx < 256; idx += 64) {
    const int i = idx >> 6, n = idx & 63;
    const float* rw = mow + (long)n * 64;
    float s = 0.f;
    for (int k = 0; k < 64; ++k) s += o[i][k] * rw[k];
    rf[i][n] = s + mob[n];
  }
  __syncthreads();
  for (int idx = t; idx < 256; idx += 64) {
    const int i = idx >> 6, n = idx & 63;
    const float* rw = rw1 + (long)n * 64;
    float s = 0.f;
    for (int k = 0; k < 64; ++k) s += rf[i][k] * rw[k];
    t1[i][n] = fmaxf(s + rb1[n], 0.f);
  }
  __syncthreads();
  if (t < 4) {
    float s = 0.f;
    for (int k = 0; k < 64; ++k) s += t1[t][k] * rw2[k];
    lg[t] = s + rb2[0];
  }
  __syncthreads();
  if (t == 0) {
    const float m = fmaxf(fmaxf(lg[0],lg[1]), fmaxf(lg[2],lg[3]));
    float e[4], s = 0.f;
    #pragma unroll
    for (int i = 0; i < 4; ++i) { e[i] = __expf(lg[i]-m); s += e[i]; }
    #pragma unroll
    for (int i = 0; i < 4; ++i) routing[i] = e[i]/s;
  }
}

// ---------------- routing-weighted kv mix ----------------
__global__ void kvr_k(const u16* local, const float* routing, u16* kvr) {
  const int r = blockIdx.y;
  const long e = ((long)blockIdx.x*256 + threadIdx.x) * 8;
  float rm[4]; float s = 0.f;
  #pragma unroll
  for (int w = 0; w < 4; ++w) { rm[w] = (w == r) ? 0.f : routing[w]; s += rm[w]; }
  const float inv = 1.f / (s + 1e-8f);
  ushort8 a0 = *(const ushort8*)&local[e];
  ushort8 a1 = *(const ushort8*)&local[1048576 + e];
  ushort8 a2 = *(const ushort8*)&local[2097152 + e];
  ushort8 a3 = *(const ushort8*)&local[3145728 + e];
  ushort8 out;
  #pragma unroll
  for (int j = 0; j < 8; ++j)
    out[j] = f2b((rm[0]*b2f(a0[j]) + rm[1]*b2f(a1[j]) + rm[2]*b2f(a2[j]) + rm[3]*b2f(a3[j])) * inv);
  *(ushort8*)&kvr[(long)r*1048576 + e] = out;
}

// ---------------- concat [local | cross] ----------------
__global__ void gcat_k(const u16* local, const u16* cross, u16* gcat) {
  const long e = ((long)blockIdx.x*256 + threadIdx.x) * 8;   // over 4096*2048
  const long row = e >> 11, col = e & 2047;
  const u16* src = (col < 1024) ? &local[row*1024 + col] : &cross[row*1024 + col - 1024];
  *(ushort8*)&gcat[e] = *(const ushort8*)src;
}

// ---------------- comb = g*cross + (1-g)*local ----------------
__global__ void comb_k(const u16* g, const u16* cross, const u16* local, u16* comb) {
  const long e = ((long)blockIdx.x*256 + threadIdx.x) * 8;
  ushort8 gg = *(const ushort8*)&g[e];
  ushort8 cc = *(const ushort8*)&cross[e];
  ushort8 ll = *(const ushort8*)&local[e];
  ushort8 out;
  #pragma unroll
  for (int j = 0; j < 8; ++j) {
    const float gf = b2f(gg[j]);
    out[j] = f2b(gf*b2f(cc[j]) + (1.f-gf)*b2f(ll[j]));
  }
  *(ushort8*)&comb[e] = out;
}

// ---------------------------------------------------------------------------
static void gemm(hipStream_t st, dim3 grid,
                 const u16* A, long lda, long aBz,
                 const u16* B, long ldb, long bBz,
                 u16* C, long ldc, long cBz,
                 const float* bias, int K, int Nstore, float scale, int act, int outf) {
  GemmP p; p.A=A; p.B=B; p.C=C; p.bias=bias;
  p.lda=lda; p.ldb=ldb; p.ldc=ldc; p.aBz=aBz; p.bBz=bBz; p.cBz=cBz;
  p.K=K; p.Nstore=Nstore; p.act=act; p.outf=outf; p.scale=scale;
  gemm_nt<<<grid, dim3(256), 0, st>>>(p);
}

extern "C" void kernel_launch(void* const* d_in, const int* in_sizes, int n_in,
                              void* d_out, int out_size, void* d_ws, size_t ws_size,
                              hipStream_t stream) {
  (void)in_sizes; (void)n_in; (void)out_size; (void)ws_size;
  const float* x   = (const float*)d_in[0];
  const float* liw = (const float*)d_in[1];
  const float* lib = (const float*)d_in[2];
  const float* low = (const float*)d_in[3];
  const float* lob = (const float*)d_in[4];
  const float* sq  = (const float*)d_in[5];
  const float* siw = (const float*)d_in[6];
  const float* sib = (const float*)d_in[7];
  const float* sow = (const float*)d_in[8];
  const float* sob = (const float*)d_in[9];
  const float* pw1 = (const float*)d_in[10];
  const float* pb1 = (const float*)d_in[11];
  const float* pw2 = (const float*)d_in[12];
  const float* pb2 = (const float*)d_in[13];
  const float* cbw = (const float*)d_in[14];
  const float* cbb = (const float*)d_in[15];
  const float* miw = (const float*)d_in[16];
  const float* mib = (const float*)d_in[17];
  const float* mow = (const float*)d_in[18];
  const float* mob = (const float*)d_in[19];
  const float* rw1 = (const float*)d_in[20];
  const float* rb1 = (const float*)d_in[21];
  const float* rw2 = (const float*)d_in[22];
  const float* rb2 = (const float*)d_in[23];
  const float* ciw = (const float*)d_in[24];
  const float* cib = (const float*)d_in[25];
  const float* cow = (const float*)d_in[26];
  const float* cob = (const float*)d_in[27];
  const float* gw  = (const float*)d_in[28];
  const float* gb  = (const float*)d_in[29];
  const float* pw  = (const float*)d_in[30];
  const float* pb  = (const float*)d_in[31];

  char* ws = (char*)d_ws;
  u16* qkv    = (u16*)(ws + 0);            // 4096x3072 bf16
  u16* aout   = (u16*)(ws + 25165824);     // 4096x1024
  u16* local  = (u16*)(ws + 33554432);     // 4096x1024
  u16* scores = (u16*)(ws + 41943040);     // 16 x 1024x1024 (first 6MB doubles as liwb)
  u16* vt     = (u16*)(ws + 75497472);     // 16 x 128x1024
  u16* s2048  = (u16*)(ws + 79691776);     // 4096x2048 (sumKV -> crossKV -> gatecat)
  u16* cq     = (u16*)(ws + 96468992);     // 4096x1024 (cross Q, later g)
  u16* kvr    = (u16*)(ws + 104857600);    // 4096x1024 (mixed kv, later comb)
  u16* crossb = (u16*)(ws + 113246208);    // 4096x1024 (doubles as xb before step 11)
  char* sf = ws + 121634816;
  float* qs      = (float*)(sf + 0);
  float* pall    = (float*)(sf + 4096);
  float* wavg    = (float*)(sf + 266240);
  float* content = (float*)(sf + 282624);
  float* contprj = (float*)(sf + 299008);
  float* stats   = (float*)(sf + 315392);
  float* summ    = (float*)(sf + 315456);
  float* routing = (float*)(sf + 316480);
  // bf16 weight copies
  u16* siwkvb = (u16*)(ws + 121951360);    // 2M el
  u16* lowb   = (u16*)(ws + 126145664);    // 1M el
  u16* ciwb   = (u16*)(ws + 128242816);    // 3M el
  u16* cowb   = (u16*)(ws + 134534272);    // 1M el
  u16* gwb    = (u16*)(ws + 136631424);    // 2M el
  u16* pwb    = (u16*)(ws + 140825728);    // 1M el
  u16* xb   = crossb;                      // alias: x bf16 (dead after step 1)
  u16* liwb = scores;                      // alias: liw bf16 (dead after step 1)

  // 0. fp32 -> bf16 conversions
  cvt_k<<<dim3(2048), dim3(256), 0, stream>>>(x, xb, 4194304);
  cvt_k<<<dim3(1536), dim3(256), 0, stream>>>(liw, liwb, 3145728);
  cvt_k<<<dim3(512),  dim3(256), 0, stream>>>(low, lowb, 1048576);
  cvt_k<<<dim3(1024), dim3(256), 0, stream>>>(siw + 1048576, siwkvb, 2097152);
  cvt_k<<<dim3(1536), dim3(256), 0, stream>>>(ciw, ciwb, 3145728);
  cvt_k<<<dim3(512),  dim3(256), 0, stream>>>(cow, cowb, 1048576);
  cvt_k<<<dim3(1024), dim3(256), 0, stream>>>(gw, gwb, 2097152);
  cvt_k<<<dim3(512),  dim3(256), 0, stream>>>(pw, pwb, 1048576);

  // 1. local QKV projection: (4096x1024)@(3072x1024)^T
  gemm(stream, dim3(32,24,1), xb,1024,0, liwb,1024,0, qkv,3072,0, lib, 1024, 3072, 1.f, 0, 0);

  // 2. local self-attention per window
  for (int w = 0; w < 4; ++w) {
    const u16* base = qkv + (long)w*1024*3072;
    gemm(stream, dim3(8,8,16), base,3072,64, base+1024,3072,64,
         scores,1024,1048576, nullptr, 64, 1024, 0.125f, 0, 0);
    softmax_rows<<<dim3(4096), dim3(256), 0, stream>>>(scores, 16384);
    TransP tp{base+2048, vt, 3072, 1024, 64, 131072, 64};
    transpose_k<<<dim3(32,4,16), dim3(256), 0, stream>>>(tp);
    gemm(stream, dim3(8,1,16), scores,1024,1048576, vt,1024,131072,
         aout + (long)w*1048576,1024,64, nullptr, 1024, 64, 1.f, 0, 0);
  }

  // 3. local out-projection
  gemm(stream, dim3(32,8,1), aout,1024,0, lowb,1024,0, local,1024,0, lob, 1024, 1024, 1.f, 0, 0);

  // 4. summary K/V projection (wk,wv rows of sum_in_w)
  gemm(stream, dim3(32,16,1), local,1024,0, siwkvb,1024,0, s2048,2048,0, sib+1024, 1024, 2048, 1.f, 0, 0);

  // 5. summaries
  gemv_qs<<<dim3(4), dim3(256), 0, stream>>>(sq, siw, sib, qs);
  sum_attend<<<dim3(16,4), dim3(64), 0, stream>>>(qs, s2048, content, pall);
  wavg_k<<<dim3(4,4), dim3(256), 0, stream>>>(pall, wavg);
  contproj_k<<<dim3(16,4), dim3(64), 0, stream>>>(content, sow, sob, contprj);
  stats_k<<<dim3(4), dim3(256), 0, stream>>>(wavg, stats);
  patsum_k<<<dim3(4), dim3(64), 0, stream>>>(stats, contprj, pw1, pb1, pw2, pb2, cbw, cbb, summ);

  // 6. meta attention + routing
  meta_k<<<dim3(1), dim3(64), 0, stream>>>(summ, miw, mib, mow, mob, rw1, rb1, rw2, rb2, routing);

  // 7. per-rank mixed kv
  kvr_k<<<dim3(512,4), dim3(256), 0, stream>>>(local, routing, kvr);

  // 8-9. cross Q / KV projections
  gemm(stream, dim3(32,8,1), local,1024,0, ciwb,1024,0, cq,1024,0, cib, 1024, 1024, 1.f, 0, 0);
  gemm(stream, dim3(32,16,1), kvr,1024,0, ciwb+1048576,1024,0, s2048,2048,0, cib+1024, 1024, 2048, 1.f, 0, 0);

  // 10. cross attention per rank
  for (int r = 0; r < 4; ++r) {
    const u16* cqb = cq + (long)r*1048576;
    const u16* ckb = s2048 + (long)r*2097152;
    gemm(stream, dim3(8,8,16), cqb,1024,64, ckb,2048,64,
         scores,1024,1048576, nullptr, 64, 1024, 0.125f, 0, 0);
    softmax_rows<<<dim3(4096), dim3(256), 0, stream>>>(scores, 16384);
    TransP tp{ckb+1024, vt, 2048, 1024, 64, 131072, 64};
    transpose_k<<<dim3(32,4,16), dim3(256), 0, stream>>>(tp);
    gemm(stream, dim3(8,1,16), scores,1024,1048576, vt,1024,131072,
         aout + (long)r*1048576,1024,64, nullptr, 1024, 64, 1.f, 0, 0);
  }

  // 11. cross out-projection
  gemm(stream, dim3(32,8,1), aout,1024,0, cowb,1024,0, crossb,1024,0, cob, 1024, 1024, 1.f, 0, 0);

  // 12-13. gate
  gcat_k<<<dim3(4096), dim3(256), 0, stream>>>(local, crossb, s2048);
  gemm(stream, dim3(32,8,1), s2048,2048,0, gwb,2048,0, cq,1024,0, gb, 2048, 1024, 1.f, 1, 0);

  // 14. comb = g*cross + (1-g)*local
  comb_k<<<dim3(2048), dim3(256), 0, stream>>>(cq, crossb, local, kvr);

  // 15. final projection -> d_out (fp32)
  gemm(stream, dim3(32,8,1), kvr,1024,0, pwb,1024,0, (u16*)d_out,1024,0, pb, 1024, 1024, 1.f, 0, 1);
}

// Round 5
// 944.491 us; speedup vs baseline: 1.2118x; 1.2118x over previous
//
#include <hip/hip_runtime.h>
#include <stdint.h>

typedef uint16_t u16;
typedef __attribute__((ext_vector_type(8))) short short8;
typedef __attribute__((ext_vector_type(8))) unsigned short ushort8;
typedef __attribute__((ext_vector_type(4))) float f32x4;

__device__ __forceinline__ float b2f(u16 u){
  union{uint32_t i; float f;} v; v.i=((uint32_t)u)<<16; return v.f;
}
__device__ __forceinline__ u16 f2b(float f){
  union{uint32_t i; float f;} v; v.f=f;
  return (u16)((v.i + 0x7fffu + ((v.i>>16)&1u))>>16);
}

// ---------------- fused fp32 -> bf16 conversions (8 segments, 1 launch) -----
struct CvtP { const float* src[8]; u16* dst[8]; long n[8]; };
__global__ void cvt_multi(CvtP p) {
  const int seg = blockIdx.y;
  const long i = ((long)blockIdx.x*256 + threadIdx.x)*8;
  if (i >= p.n[seg]) return;
  const float* in = p.src[seg];
  float4 a = *(const float4*)&in[i];
  float4 b = *(const float4*)&in[i+4];
  ushort8 o;
  o[0]=f2b(a.x); o[1]=f2b(a.y); o[2]=f2b(a.z); o[3]=f2b(a.w);
  o[4]=f2b(b.x); o[5]=f2b(b.y); o[6]=f2b(b.z); o[7]=f2b(b.w);
  *(ushort8*)&p.dst[seg][i] = o;
}

// ---------------------------------------------------------------------------
// Generic NT GEMM on bf16 tiles: C = scale * A@B^T + bias. Batched over z.
// Tile 128x128, BK=32, 4 waves, mfma_f32_16x16x32_bf16, global_load_lds w16.
// bias is fp32; outf=1 writes fp32 C (final projection), else bf16.
// ---------------------------------------------------------------------------
struct GemmP {
  const u16* A; const u16* B; u16* C; const float* bias;
  long lda, ldb, ldc, aBz, bBz, cBz;
  int K, Nstore, act, outf;   // act: 0 none, 1 sigmoid
  float scale;
};

__global__ __launch_bounds__(256) void gemm_nt(GemmP p) {
  __shared__ __align__(16) u16 lA[4096];
  __shared__ __align__(16) u16 lB[4096];
  const int t = threadIdx.x;
  const int wave = t >> 6, lane = t & 63;
  const long z = blockIdx.z;
  const u16* A = p.A + z * p.aBz + (long)blockIdx.x * 128 * p.lda;
  const u16* B = p.B + z * p.bBz + (long)blockIdx.y * 128 * p.ldb;
  const int srow = t >> 2, skk = (t & 3) * 8;
  const int wr = wave >> 1, wc = wave & 1;
  const int fr = lane & 15, fk = (lane >> 4) * 8;
  f32x4 acc[4][4] = {};

  for (int k0 = 0; k0 < p.K; k0 += 32) {
    __syncthreads();
    #pragma unroll
    for (int i = 0; i < 2; ++i) {
      __builtin_amdgcn_global_load_lds(
        (const __attribute__((address_space(1))) void*)(A + (long)(i*64 + srow)*p.lda + k0 + skk),
        (__attribute__((address_space(3))) void*)&lA[(i*256 + wave*64)*8], 16, 0, 0);
      __builtin_amdgcn_global_load_lds(
        (const __attribute__((address_space(1))) void*)(B + (long)(i*64 + srow)*p.ldb + k0 + skk),
        (__attribute__((address_space(3))) void*)&lB[(i*256 + wave*64)*8], 16, 0, 0);
    }
    __syncthreads();
    short8 av[4], bv[4];
    #pragma unroll
    for (int mi = 0; mi < 4; ++mi) av[mi] = *(const short8*)&lA[(wr*64 + mi*16 + fr)*32 + fk];
    #pragma unroll
    for (int ni = 0; ni < 4; ++ni) bv[ni] = *(const short8*)&lB[(wc*64 + ni*16 + fr)*32 + fk];
    #pragma unroll
    for (int mi = 0; mi < 4; ++mi)
      #pragma unroll
      for (int ni = 0; ni < 4; ++ni)
        acc[mi][ni] = __builtin_amdgcn_mfma_f32_16x16x32_bf16(av[mi], bv[ni], acc[mi][ni], 0, 0, 0);
  }

  const long cOff = z * p.cBz;
  const int rbase = blockIdx.x*128 + wr*64;
  const int cbase = blockIdx.y*128 + wc*64;
  const int rsub = (lane >> 4) * 4;
  #pragma unroll
  for (int ni = 0; ni < 4; ++ni) {
    const int col = cbase + ni*16 + fr;
    if (col >= p.Nstore) continue;
    const float bs = p.bias ? p.bias[col] : 0.f;
    #pragma unroll
    for (int mi = 0; mi < 4; ++mi) {
      #pragma unroll
      for (int j = 0; j < 4; ++j) {
        float v = acc[mi][ni][j] * p.scale + bs;
        if (p.act == 1) v = 1.f / (1.f + __expf(-v));
        const long idx = cOff + (long)(rbase + mi*16 + rsub + j) * p.ldc + col;
        if (p.outf) ((float*)p.C)[idx] = v;
        else        p.C[idx] = f2b(v);
      }
    }
  }
}

// ---------------- softmax over rows of 1024 (in-place, bf16) ----------------
__global__ void softmax_rows(u16* buf, int nrows) {
  const int wave = threadIdx.x >> 6, lane = threadIdx.x & 63;
  const int row = blockIdx.x * 4 + wave;
  if (row >= nrows) return;
  u16* r = buf + (long)row * 1024;
  ushort8 u0 = *(const ushort8*)&r[lane*8];
  ushort8 u1 = *(const ushort8*)&r[512 + lane*8];
  float v[16];
  #pragma unroll
  for (int i = 0; i < 8; ++i) { v[i] = b2f(u0[i]); v[8+i] = b2f(u1[i]); }
  float mx = -1e30f;
  #pragma unroll
  for (int i = 0; i < 16; ++i) mx = fmaxf(mx, v[i]);
  #pragma unroll
  for (int o = 32; o; o >>= 1) mx = fmaxf(mx, __shfl_xor(mx, o, 64));
  float s = 0.f;
  #pragma unroll
  for (int i = 0; i < 16; ++i) { v[i] = __expf(v[i] - mx); s += v[i]; }
  #pragma unroll
  for (int o = 32; o; o >>= 1) s += __shfl_xor(s, o, 64);
  const float inv = 1.f / s;
  ushort8 o0, o1;
  #pragma unroll
  for (int i = 0; i < 8; ++i) { o0[i] = f2b(v[i]*inv); o1[i] = f2b(v[8+i]*inv); }
  *(ushort8*)&r[lane*8] = o0;
  *(ushort8*)&r[512 + lane*8] = o1;
}

// ------- batched 2D transpose; blocks past validCols write zeros -------
struct TransP { const u16* in; u16* out; long inStride, outStride, inB, outB; int validCols; };
__global__ void transpose_k(TransP p) {
  __shared__ u16 tile[32][33];
  const u16* in = p.in + blockIdx.z * p.inB;
  u16* out = p.out + blockIdx.z * p.outB;
  const int tx = threadIdx.x & 31, ty = threadIdx.x >> 5;
  const int r0 = blockIdx.x * 32, c0 = blockIdx.y * 32;
  if (c0 < p.validCols) {
    #pragma unroll
    for (int i = 0; i < 32; i += 8)
      tile[ty + i][tx] = in[(long)(r0 + ty + i) * p.inStride + c0 + tx];
    __syncthreads();
    #pragma unroll
    for (int i = 0; i < 32; i += 8)
      out[(long)(c0 + ty + i) * p.outStride + r0 + tx] = tile[tx][ty + i];
  } else {
    #pragma unroll
    for (int i = 0; i < 32; i += 8)
      out[(long)(c0 + ty + i) * p.outStride + r0 + tx] = 0;
  }
}

// -------- qs = sum_query @ wq^T + bq  (grid 16, 256 thr, k-split) --------
__global__ void gemv_qs(const float* sq, const float* w, const float* b, float* out) {
  const int t = threadIdx.x, nl = t & 63, kq = t >> 6;
  const int n = blockIdx.x*64 + nl;
  const float* row = w + (long)n * 1024 + kq*256;
  const float* q = sq + kq*256;
  float s = 0.f;
  for (int k = 0; k < 256; k += 4) {
    float4 ww = *(const float4*)&row[k];
    float4 qq = *(const float4*)&q[k];
    s += qq.x*ww.x + qq.y*ww.y + qq.z*ww.z + qq.w*ww.w;
  }
  __shared__ float ps[4][64];
  ps[kq][nl] = s;
  __syncthreads();
  if (t < 64) out[blockIdx.x*64 + t] = ps[0][t]+ps[1][t]+ps[2][t]+ps[3][t] + b[blockIdx.x*64 + t];
}

// ------- summary attention: block (h,w), 256 threads, k-parallel -------
__global__ void sum_attend(const float* qs, const u16* sumkv, float* content, float* pall) {
  const int h = blockIdx.x, w = blockIdx.y, t = threadIdx.x;
  const int lane = t & 63, wv = t >> 6;
  __shared__ float qsh[64];
  __shared__ float sc[1024];
  __shared__ float rmax[4], rsum[4];
  __shared__ float po[4][64];
  if (t < 64) qsh[t] = qs[h*64 + t];
  __syncthreads();
  const u16* kbase = sumkv + (long)w*2097152 + h*64;
  float e[4];
  float mx = -1e30f;
  #pragma unroll
  for (int j = 0; j < 4; ++j) {
    const int k = j*256 + t;
    const u16* krow = kbase + (long)k * 2048;
    float s = 0.f;
    #pragma unroll
    for (int d = 0; d < 64; d += 8) {
      ushort8 kk = *(const ushort8*)&krow[d];
      #pragma unroll
      for (int q = 0; q < 8; ++q) s += qsh[d+q] * b2f(kk[q]);
    }
    s *= 0.125f;
    e[j] = s;
    mx = fmaxf(mx, s);
  }
  #pragma unroll
  for (int o = 32; o; o >>= 1) mx = fmaxf(mx, __shfl_xor(mx, o, 64));
  if (lane == 0) rmax[wv] = mx;
  __syncthreads();
  mx = fmaxf(fmaxf(rmax[0],rmax[1]), fmaxf(rmax[2],rmax[3]));
  float sum = 0.f;
  #pragma unroll
  for (int j = 0; j < 4; ++j) { e[j] = __expf(e[j]-mx); sum += e[j]; }
  #pragma unroll
  for (int o = 32; o; o >>= 1) sum += __shfl_xor(sum, o, 64);
  if (lane == 0) rsum[wv] = sum;
  __syncthreads();
  const float inv = 1.f / (rsum[0]+rsum[1]+rsum[2]+rsum[3]);
  float* pr = pall + ((long)w*16 + h)*1024;
  #pragma unroll
  for (int j = 0; j < 4; ++j) {
    const int k = j*256 + t;
    const float pn = e[j]*inv;
    sc[k] = pn;
    pr[k] = pn;
  }
  __syncthreads();
  const u16* vbase = sumkv + (long)w*2097152 + 1024 + h*64;
  float o = 0.f;
  const int k0 = wv*256;
  for (int k = k0; k < k0+256; ++k) o += sc[k] * b2f(vbase[(long)k*2048 + lane]);
  po[wv][lane] = o;
  __syncthreads();
  if (t < 64) content[(long)w*1024 + h*64 + t] = po[0][t]+po[1][t]+po[2][t]+po[3][t];
}

__global__ void wavg_k(const float* pall, float* wavg) {
  const int w = blockIdx.y, k = blockIdx.x*256 + threadIdx.x;
  float s = 0.f;
  #pragma unroll
  for (int h = 0; h < 16; ++h) s += pall[((long)w*16 + h)*1024 + k];
  wavg[w*1024 + k] = s * (1.f/16.f);
}

// ------- content projection (grid (16,4), 256 thr, k-split) -------
__global__ void contproj_k(const float* content, const float* w_, const float* b, float* out) {
  const int w = blockIdx.y, t = threadIdx.x;
  const int nl = t & 63, kq = t >> 6;
  const int n = blockIdx.x*64 + nl;
  const float* c = content + w*1024 + kq*256;
  const float* row = w_ + (long)n * 1024 + kq*256;
  float s = 0.f;
  for (int k = 0; k < 256; k += 4) {
    float4 ww = *(const float4*)&row[k];
    s += c[k]*ww.x + c[k+1]*ww.y + c[k+2]*ww.z + c[k+3]*ww.w;
  }
  __shared__ float ps[4][64];
  ps[kq][nl] = s;
  __syncthreads();
  if (t < 64) out[w*1024 + blockIdx.x*64 + t] = ps[0][t]+ps[1][t]+ps[2][t]+ps[3][t] + b[blockIdx.x*64 + t];
}

// ------- attn_stats phase A: parallel rank-count (grid (16,4), 256 thr) -----
__global__ void stats1_k(const float* wavg, float* part) {
  const int c = blockIdx.x, w = blockIdx.y, t = threadIdx.x;
  __shared__ float a[1024];
  for (int i = t; i < 1024; i += 256) a[i] = wavg[w*1024 + i];
  __syncthreads();
  const int jl = t & 63, iq = t >> 6;
  const int j = c*64 + jl;
  const float aj = a[j];
  int pr = 0;
  const int i0 = iq*256;
  #pragma unroll 8
  for (int i = i0; i < i0+256; ++i) {
    const float ai = a[i];
    pr += (ai < aj) || (ai == aj && i < j);
  }
  __shared__ int prs[4][64];
  prs[iq][jl] = pr;
  __syncthreads();
  if (t < 64) {
    const int rank = 1 + prs[0][jl] + prs[1][jl] + prs[2][jl] + prs[3][jl];
    float ent = -aj * logf(aj + 1e-8f);
    float gnum = (float)rank * aj;
    float ssum = aj;
    float mx = aj;
    float top5 = (rank >= 1020) ? aj : 0.f;
    #pragma unroll
    for (int o = 32; o; o >>= 1) {
      ent += __shfl_xor(ent, o, 64);
      gnum += __shfl_xor(gnum, o, 64);
      ssum += __shfl_xor(ssum, o, 64);
      mx = fmaxf(mx, __shfl_xor(mx, o, 64));
      top5 += __shfl_xor(top5, o, 64);
    }
    if (t == 0) {
      float* pp = part + ((w*16 + c) * 5);
      pp[0]=ent; pp[1]=gnum; pp[2]=ssum; pp[3]=mx; pp[4]=top5;
    }
  }
}

// ------- attn_stats phase B: reduce 16 chunk-partials (grid 4, 128 thr) -----
__global__ void stats2_k(const float* part, float* stats) {
  const int w = blockIdx.x, t = threadIdx.x;
  const int c = t & 15, stat = t >> 4;
  float v = 0.f;
  const bool active = stat < 5;
  if (active) v = part[(w*16 + c)*5 + stat];
  #pragma unroll
  for (int o = 8; o; o >>= 1) {
    const float ov = __shfl_xor(v, o, 64);
    v = (stat == 3) ? fmaxf(v, ov) : (v + ov);
  }
  __shared__ float r5[5];
  if (active && c == 0) r5[stat] = v;
  __syncthreads();
  if (t == 0) {
    stats[w*4+0] = r5[0];
    stats[w*4+1] = 2.f*r5[1]/(1024.f*r5[2] + 1e-8f) - 1025.f/1024.f;
    stats[w*4+2] = r5[3];
    stats[w*4+3] = r5[4];
  }
}

// ------- pat MLP + summary combine (grid 4, 256 thr, k-split) -------
__global__ void patsum_k(const float* stats, const float* contprj,
                         const float* pw1, const float* pb1, const float* pw2, const float* pb2,
                         const float* combw, const float* combb, float* summ) {
  const int w = blockIdx.x, t = threadIdx.x;
  const int nl = t & 63, kq = t >> 6;
  __shared__ float p1[64], pat[64];
  __shared__ float ps[4][64];
  __shared__ float ps2[4][64];
  if (t < 64) {
    float s = 0.f;
    #pragma unroll
    for (int k = 0; k < 4; ++k) s += stats[w*4+k] * pw1[t*4+k];
    p1[t] = fmaxf(s + pb1[t], 0.f);
  }
  __syncthreads();
  {
    float s = 0.f;
    const float* rw = pw2 + (long)nl*64 + kq*16;
    const float* pp = p1 + kq*16;
    #pragma unroll
    for (int k = 0; k < 16; ++k) s += pp[k] * rw[k];
    ps[kq][nl] = s;
  }
  __syncthreads();
  if (t < 64) pat[t] = ps[0][t]+ps[1][t]+ps[2][t]+ps[3][t] + pb2[t];
  __syncthreads();
  const float* c = contprj + w*1024;
  const float* row = combw + (long)nl * 1088;
  float s = 0.f;
  const int k0 = kq*272;
  for (int k = k0; k < k0+272; ++k) {
    const float rv = row[k];
    const float cv = (k < 1024) ? c[k] : pat[k-1024];
    s += cv * rv;
  }
  ps2[kq][nl] = s;
  __syncthreads();
  if (t < 64) summ[w*64 + t] = ps2[0][t]+ps2[1][t]+ps2[2][t]+ps2[3][t] + combb[t];
}

// ---------------- meta attention + routing (1 block, 64 threads) ------------
__global__ void meta_k(const float* summ, const float* miw, const float* mib,
                       const float* mow, const float* mob, const float* rw1, const float* rb1,
                       const float* rw2, const float* rb2, float* routing) {
  const int t = threadIdx.x;
  __shared__ float qkv[4][192];
  __shared__ float sc[64];
  __shared__ float o[4][64];
  __shared__ float rf[4][64];
  __shared__ float t1[4][64];
  __shared__ float lg[4];
  for (int idx = t; idx < 768; idx += 64) {
    const int w = idx / 192, rrow = idx % 192;
    const float* rw = miw + (long)rrow * 64;
    float s = 0.f;
    for (int k = 0; k < 64; ++k) s += summ[w*64+k] * rw[k];
    qkv[w][rrow] = s + mib[rrow];
  }
  __syncthreads();
  {
    const int h = t >> 4, i = (t >> 2) & 3, j = t & 3;
    float s = 0.f;
    #pragma unroll
    for (int d = 0; d < 16; ++d) s += qkv[i][h*16+d] * qkv[j][64 + h*16+d];
    sc[t] = s * 0.25f;
  }
  __syncthreads();
  if (t < 16) {
    const float a0=sc[t*4], a1=sc[t*4+1], a2=sc[t*4+2], a3=sc[t*4+3];
    const float m = fmaxf(fmaxf(a0,a1), fmaxf(a2,a3));
    const float e0=__expf(a0-m), e1=__expf(a1-m), e2=__expf(a2-m), e3=__expf(a3-m);
    const float s = e0+e1+e2+e3;
    sc[t*4]=e0/s; sc[t*4+1]=e1/s; sc[t*4+2]=e2/s; sc[t*4+3]=e3/s;
  }
  __syncthreads();
  for (int idx = t; idx < 256; idx += 64) {
    const int i = idx >> 6, c = idx & 63, h = c >> 4;
    float s = 0.f;
    #pragma unroll
    for (int j = 0; j < 4; ++j) s += sc[(h*4+i)*4+j] * qkv[j][128 + c];
    o[i][c] = s;
  }
  __syncthreads();
  for (int idx = t; idx < 256; idx += 64) {
    const int i = idx >> 6, n = idx & 63;
    const float* rw = mow + (long)n * 64;
    float s = 0.f;
    for (int k = 0; k < 64; ++k) s += o[i][k] * rw[k];
    rf[i][n] = s + mob[n];
  }
  __syncthreads();
  for (int idx = t; idx < 256; idx += 64) {
    const int i = idx >> 6, n = idx & 63;
    const float* rw = rw1 + (long)n * 64;
    float s = 0.f;
    for (int k = 0; k < 64; ++k) s += rf[i][k] * rw[k];
    t1[i][n] = fmaxf(s + rb1[n], 0.f);
  }
  __syncthreads();
  if (t < 4) {
    float s = 0.f;
    for (int k = 0; k < 64; ++k) s += t1[t][k] * rw2[k];
    lg[t] = s + rb2[0];
  }
  __syncthreads();
  if (t == 0) {
    const float m = fmaxf(fmaxf(lg[0],lg[1]), fmaxf(lg[2],lg[3]));
    float e[4], s = 0.f;
    #pragma unroll
    for (int i = 0; i < 4; ++i) { e[i] = __expf(lg[i]-m); s += e[i]; }
    #pragma unroll
    for (int i = 0; i < 4; ++i) routing[i] = e[i]/s;
  }
}

// ---------------- routing-weighted kv mix ----------------
__global__ void kvr_k(const u16* local, const float* routing, u16* kvr) {
  const int r = blockIdx.y;
  const long e = ((long)blockIdx.x*256 + threadIdx.x) * 8;
  float rm[4]; float s = 0.f;
  #pragma unroll
  for (int w = 0; w < 4; ++w) { rm[w] = (w == r) ? 0.f : routing[w]; s += rm[w]; }
  const float inv = 1.f / (s + 1e-8f);
  ushort8 a0 = *(const ushort8*)&local[e];
  ushort8 a1 = *(const ushort8*)&local[1048576 + e];
  ushort8 a2 = *(const ushort8*)&local[2097152 + e];
  ushort8 a3 = *(const ushort8*)&local[3145728 + e];
  ushort8 out;
  #pragma unroll
  for (int j = 0; j < 8; ++j)
    out[j] = f2b((rm[0]*b2f(a0[j]) + rm[1]*b2f(a1[j]) + rm[2]*b2f(a2[j]) + rm[3]*b2f(a3[j])) * inv);
  *(ushort8*)&kvr[(long)r*1048576 + e] = out;
}

// ---------------- concat [local | cross] ----------------
__global__ void gcat_k(const u16* local, const u16* cross, u16* gcat) {
  const long e = ((long)blockIdx.x*256 + threadIdx.x) * 8;
  const long row = e >> 11, col = e & 2047;
  const u16* src = (col < 1024) ? &local[row*1024 + col] : &cross[row*1024 + col - 1024];
  *(ushort8*)&gcat[e] = *(const ushort8*)src;
}

// ---------------- comb = g*cross + (1-g)*local ----------------
__global__ void comb_k(const u16* g, const u16* cross, const u16* local, u16* comb) {
  const long e = ((long)blockIdx.x*256 + threadIdx.x) * 8;
  ushort8 gg = *(const ushort8*)&g[e];
  ushort8 cc = *(const ushort8*)&cross[e];
  ushort8 ll = *(const ushort8*)&local[e];
  ushort8 out;
  #pragma unroll
  for (int j = 0; j < 8; ++j) {
    const float gf = b2f(gg[j]);
    out[j] = f2b(gf*b2f(cc[j]) + (1.f-gf)*b2f(ll[j]));
  }
  *(ushort8*)&comb[e] = out;
}

// ---------------------------------------------------------------------------
static void gemm(hipStream_t st, dim3 grid,
                 const u16* A, long lda, long aBz,
                 const u16* B, long ldb, long bBz,
                 u16* C, long ldc, long cBz,
                 const float* bias, int K, int Nstore, float scale, int act, int outf) {
  GemmP p; p.A=A; p.B=B; p.C=C; p.bias=bias;
  p.lda=lda; p.ldb=ldb; p.ldc=ldc; p.aBz=aBz; p.bBz=bBz; p.cBz=cBz;
  p.K=K; p.Nstore=Nstore; p.act=act; p.outf=outf; p.scale=scale;
  gemm_nt<<<grid, dim3(256), 0, st>>>(p);
}

extern "C" void kernel_launch(void* const* d_in, const int* in_sizes, int n_in,
                              void* d_out, int out_size, void* d_ws, size_t ws_size,
                              hipStream_t stream) {
  (void)in_sizes; (void)n_in; (void)out_size; (void)ws_size;
  const float* x   = (const float*)d_in[0];
  const float* liw = (const float*)d_in[1];
  const float* lib = (const float*)d_in[2];
  const float* low = (const float*)d_in[3];
  const float* lob = (const float*)d_in[4];
  const float* sq  = (const float*)d_in[5];
  const float* siw = (const float*)d_in[6];
  const float* sib = (const float*)d_in[7];
  const float* sow = (const float*)d_in[8];
  const float* sob = (const float*)d_in[9];
  const float* pw1 = (const float*)d_in[10];
  const float* pb1 = (const float*)d_in[11];
  const float* pw2 = (const float*)d_in[12];
  const float* pb2 = (const float*)d_in[13];
  const float* cbw = (const float*)d_in[14];
  const float* cbb = (const float*)d_in[15];
  const float* miw = (const float*)d_in[16];
  const float* mib = (const float*)d_in[17];
  const float* mow = (const float*)d_in[18];
  const float* mob = (const float*)d_in[19];
  const float* rw1 = (const float*)d_in[20];
  const float* rb1 = (const float*)d_in[21];
  const float* rw2 = (const float*)d_in[22];
  const float* rb2 = (const float*)d_in[23];
  const float* ciw = (const float*)d_in[24];
  const float* cib = (const float*)d_in[25];
  const float* cow = (const float*)d_in[26];
  const float* cob = (const float*)d_in[27];
  const float* gw  = (const float*)d_in[28];
  const float* gb  = (const float*)d_in[29];
  const float* pw  = (const float*)d_in[30];
  const float* pb  = (const float*)d_in[31];

  char* ws = (char*)d_ws;
  u16* qkv    = (u16*)(ws + 0);            // 4096x3072 bf16
  u16* aout   = (u16*)(ws + 25165824);     // 4096x1024
  u16* local  = (u16*)(ws + 33554432);     // 4096x1024
  u16* scores = (u16*)(ws + 41943040);     // 16 x 1024x1024 (first 6MB doubles as liwb)
  u16* vt     = (u16*)(ws + 75497472);     // 16 x 128x1024
  u16* s2048  = (u16*)(ws + 79691776);     // 4096x2048 (sumKV -> crossKV -> gatecat)
  u16* cq     = (u16*)(ws + 96468992);     // 4096x1024 (cross Q, later g)
  u16* kvr    = (u16*)(ws + 104857600);    // 4096x1024 (mixed kv, later comb)
  u16* crossb = (u16*)(ws + 113246208);    // 4096x1024 (doubles as xb before step 11)
  char* sf = ws + 121634816;               // fp32 scratch region (384 KB)
  float* qs      = (float*)(sf + 0);
  float* pall    = (float*)(sf + 4096);
  float* wavg    = (float*)(sf + 266240);
  float* content = (float*)(sf + 282624);
  float* contprj = (float*)(sf + 299008);
  float* stats   = (float*)(sf + 315392);
  float* summ    = (float*)(sf + 315456);
  float* routing = (float*)(sf + 316480);
  float* part    = (float*)(sf + 316544);  // 4*16*5 fp32 rank-count partials
  // bf16 weight copies
  u16* siwkvb = (u16*)(ws + 122028032);    // 2M el
  u16* lowb   = (u16*)(ws + 126222336);    // 1M el
  u16* ciwb   = (u16*)(ws + 128319488);    // 3M el
  u16* cowb   = (u16*)(ws + 134610944);    // 1M el
  u16* gwb    = (u16*)(ws + 136708096);    // 2M el
  u16* pwb    = (u16*)(ws + 140902400);    // 1M el
  u16* xb   = crossb;                      // alias: x bf16 (dead after step 1)
  u16* liwb = scores;                      // alias: liw bf16 (dead after step 1)

  // 0. fp32 -> bf16 conversions (one launch, 8 segments)
  CvtP cp;
  cp.src[0]=x;   cp.dst[0]=xb;     cp.n[0]=4194304;
  cp.src[1]=liw; cp.dst[1]=liwb;   cp.n[1]=3145728;
  cp.src[2]=low; cp.dst[2]=lowb;   cp.n[2]=1048576;
  cp.src[3]=siw+1048576; cp.dst[3]=siwkvb; cp.n[3]=2097152;
  cp.src[4]=ciw; cp.dst[4]=ciwb;   cp.n[4]=3145728;
  cp.src[5]=cow; cp.dst[5]=cowb;   cp.n[5]=1048576;
  cp.src[6]=gw;  cp.dst[6]=gwb;    cp.n[6]=2097152;
  cp.src[7]=pw;  cp.dst[7]=pwb;    cp.n[7]=1048576;
  cvt_multi<<<dim3(2048, 8), dim3(256), 0, stream>>>(cp);

  // 1. local QKV projection: (4096x1024)@(3072x1024)^T
  gemm(stream, dim3(32,24,1), xb,1024,0, liwb,1024,0, qkv,3072,0, lib, 1024, 3072, 1.f, 0, 0);

  // 2. local self-attention per window
  for (int w = 0; w < 4; ++w) {
    const u16* base = qkv + (long)w*1024*3072;
    gemm(stream, dim3(8,8,16), base,3072,64, base+1024,3072,64,
         scores,1024,1048576, nullptr, 64, 1024, 0.125f, 0, 0);
    softmax_rows<<<dim3(4096), dim3(256), 0, stream>>>(scores, 16384);
    TransP tp{base+2048, vt, 3072, 1024, 64, 131072, 64};
    transpose_k<<<dim3(32,4,16), dim3(256), 0, stream>>>(tp);
    gemm(stream, dim3(8,1,16), scores,1024,1048576, vt,1024,131072,
         aout + (long)w*1048576,1024,64, nullptr, 1024, 64, 1.f, 0, 0);
  }

  // 3. local out-projection
  gemm(stream, dim3(32,8,1), aout,1024,0, lowb,1024,0, local,1024,0, lob, 1024, 1024, 1.f, 0, 0);

  // 4. summary K/V projection (wk,wv rows of sum_in_w)
  gemm(stream, dim3(32,16,1), local,1024,0, siwkvb,1024,0, s2048,2048,0, sib+1024, 1024, 2048, 1.f, 0, 0);

  // 5. summaries
  gemv_qs<<<dim3(16), dim3(256), 0, stream>>>(sq, siw, sib, qs);
  sum_attend<<<dim3(16,4), dim3(256), 0, stream>>>(qs, s2048, content, pall);
  wavg_k<<<dim3(4,4), dim3(256), 0, stream>>>(pall, wavg);
  contproj_k<<<dim3(16,4), dim3(256), 0, stream>>>(content, sow, sob, contprj);
  stats1_k<<<dim3(16,4), dim3(256), 0, stream>>>(wavg, part);
  stats2_k<<<dim3(4), dim3(128), 0, stream>>>(part, stats);
  patsum_k<<<dim3(4), dim3(256), 0, stream>>>(stats, contprj, pw1, pb1, pw2, pb2, cbw, cbb, summ);

  // 6. meta attention + routing
  meta_k<<<dim3(1), dim3(64), 0, stream>>>(summ, miw, mib, mow, mob, rw1, rb1, rw2, rb2, routing);

  // 7. per-rank mixed kv
  kvr_k<<<dim3(512,4), dim3(256), 0, stream>>>(local, routing, kvr);

  // 8-9. cross Q / KV projections
  gemm(stream, dim3(32,8,1), local,1024,0, ciwb,1024,0, cq,1024,0, cib, 1024, 1024, 1.f, 0, 0);
  gemm(stream, dim3(32,16,1), kvr,1024,0, ciwb+1048576,1024,0, s2048,2048,0, cib+1024, 1024, 2048, 1.f, 0, 0);

  // 10. cross attention per rank
  for (int r = 0; r < 4; ++r) {
    const u16* cqb = cq + (long)r*1048576;
    const u16* ckb = s2048 + (long)r*2097152;
    gemm(stream, dim3(8,8,16), cqb,1024,64, ckb,2048,64,
         scores,1024,1048576, nullptr, 64, 1024, 0.125f, 0, 0);
    softmax_rows<<<dim3(4096), dim3(256), 0, stream>>>(scores, 16384);
    TransP tp{ckb+1024, vt, 2048, 1024, 64, 131072, 64};
    transpose_k<<<dim3(32,4,16), dim3(256), 0, stream>>>(tp);
    gemm(stream, dim3(8,1,16), scores,1024,1048576, vt,1024,131072,
         aout + (long)r*1048576,1024,64, nullptr, 1024, 64, 1.f, 0, 0);
  }

  // 11. cross out-projection
  gemm(stream, dim3(32,8,1), aout,1024,0, cowb,1024,0, crossb,1024,0, cob, 1024, 1024, 1.f, 0, 0);

  // 12-13. gate
  gcat_k<<<dim3(4096), dim3(256), 0, stream>>>(local, crossb, s2048);
  gemm(stream, dim3(32,8,1), s2048,2048,0, gwb,2048,0, cq,1024,0, gb, 2048, 1024, 1.f, 1, 0);

  // 14. comb = g*cross + (1-g)*local
  comb_k<<<dim3(2048), dim3(256), 0, stream>>>(cq, crossb, local, kvr);

  // 15. final projection -> d_out (fp32)
  gemm(stream, dim3(32,8,1), kvr,1024,0, pwb,1024,0, (u16*)d_out,1024,0, pb, 1024, 1024, 1.f, 0, 1);
}

// Round 6
// 498.378 us; speedup vs baseline: 2.2965x; 1.8951x over previous
//
#include <hip/hip_runtime.h>
#include <stdint.h>

typedef uint16_t u16;
typedef __attribute__((ext_vector_type(8))) short short8;
typedef __attribute__((ext_vector_type(8))) unsigned short ushort8;
typedef __attribute__((ext_vector_type(4))) float f32x4;

#define AS1 __attribute__((address_space(1)))
#define AS3 __attribute__((address_space(3)))

__device__ __forceinline__ float b2f(u16 u){
  union{uint32_t i; float f;} v; v.i=((uint32_t)u)<<16; return v.f;
}
__device__ __forceinline__ u16 f2b(float f){
  union{uint32_t i; float f;} v; v.f=f;
  return (u16)((v.i + 0x7fffu + ((v.i>>16)&1u))>>16);
}

// ---------------- fused fp32 -> bf16 conversions (8 segments, 1 launch) -----
struct CvtP { const float* src[8]; u16* dst[8]; long n[8]; };
__global__ void cvt_multi(CvtP p) {
  const int seg = blockIdx.y;
  const long i = ((long)blockIdx.x*256 + threadIdx.x)*8;
  if (i >= p.n[seg]) return;
  const float* in = p.src[seg];
  float4 a = *(const float4*)&in[i];
  float4 b = *(const float4*)&in[i+4];
  ushort8 o;
  o[0]=f2b(a.x); o[1]=f2b(a.y); o[2]=f2b(a.z); o[3]=f2b(a.w);
  o[4]=f2b(b.x); o[5]=f2b(b.y); o[6]=f2b(b.z); o[7]=f2b(b.w);
  *(ushort8*)&p.dst[seg][i] = o;
}

// ---------------------------------------------------------------------------
// NT GEMM, 128x128 tile, BK=32, 8 waves (512 thr), double-buffered LDS.
// Optional second y-segment (ySplit) with its own B/C/bias/ldb/ldc/Nstore,
// letting two independent GEMMs sharing the same A run as one launch.
// ---------------------------------------------------------------------------
struct GemmP {
  const u16* A; const u16* B; u16* C; const float* bias;
  const u16* B2; u16* C2; const float* bias2;
  long lda, ldb, ldc, ldb2, ldc2;
  int K, Nstore, Nstore2, ySplit, act, outf;   // act: 0 none, 1 sigmoid
  float scale;
};

__global__ __launch_bounds__(512) void gemm_nt(GemmP p) {
  __shared__ __align__(16) u16 lA[2][4096];
  __shared__ __align__(16) u16 lB[2][4096];
  const int t = threadIdx.x;
  const int wave = t >> 6, lane = t & 63;
  int by = blockIdx.y;
  const u16* Bp; u16* Cp; const float* bias; long ldb, ldc; int nst;
  if (by >= p.ySplit) {
    by -= p.ySplit; Bp = p.B2; Cp = p.C2; bias = p.bias2;
    ldb = p.ldb2; ldc = p.ldc2; nst = p.Nstore2;
  } else {
    Bp = p.B; Cp = p.C; bias = p.bias; ldb = p.ldb; ldc = p.ldc; nst = p.Nstore;
  }
  const u16* A = p.A + (long)blockIdx.x * 128 * p.lda;
  const u16* B = Bp + (long)by * 128 * ldb;
  const int srow = t >> 2, skk = (t & 3) * 8;   // 512 thr cover 128x32 in one shot
  const int wr = wave >> 2, wc = wave & 3;      // wave tile: 64 rows x 32 cols
  const int fr = lane & 15, fk = (lane >> 4) * 8;
  f32x4 acc[4][2] = {};

  // prologue: stage k-tile 0 into buffer 0
  __builtin_amdgcn_global_load_lds((const AS1 void*)(A + (long)srow*p.lda + skk),
                                   (AS3 void*)&lA[0][t*8], 16, 0, 0);
  __builtin_amdgcn_global_load_lds((const AS1 void*)(B + (long)srow*ldb + skk),
                                   (AS3 void*)&lB[0][t*8], 16, 0, 0);
  __syncthreads();
  int cur = 0;
  for (int k0 = 0; k0 < p.K; k0 += 32) {
    if (k0 + 32 < p.K) {   // prefetch next k-tile into the other buffer
      const int nb = cur ^ 1, kn = k0 + 32;
      __builtin_amdgcn_global_load_lds((const AS1 void*)(A + (long)srow*p.lda + kn + skk),
                                       (AS3 void*)&lA[nb][t*8], 16, 0, 0);
      __builtin_amdgcn_global_load_lds((const AS1 void*)(B + (long)srow*ldb + kn + skk),
                                       (AS3 void*)&lB[nb][t*8], 16, 0, 0);
    }
    short8 av[4], bv[2];
    #pragma unroll
    for (int mi = 0; mi < 4; ++mi) av[mi] = *(const short8*)&lA[cur][(wr*64 + mi*16 + fr)*32 + fk];
    #pragma unroll
    for (int ni = 0; ni < 2; ++ni) bv[ni] = *(const short8*)&lB[cur][(wc*32 + ni*16 + fr)*32 + fk];
    #pragma unroll
    for (int mi = 0; mi < 4; ++mi)
      #pragma unroll
      for (int ni = 0; ni < 2; ++ni)
        acc[mi][ni] = __builtin_amdgcn_mfma_f32_16x16x32_bf16(av[mi], bv[ni], acc[mi][ni], 0, 0, 0);
    __syncthreads();   // drains prefetch (vmcnt 0) + protects cur buffer
    cur ^= 1;
  }

  const int rbase = blockIdx.x*128 + wr*64;
  const int cbase = by*128 + wc*32;
  const int rsub = (lane >> 4) * 4;
  #pragma unroll
  for (int ni = 0; ni < 2; ++ni) {
    const int col = cbase + ni*16 + fr;
    if (col >= nst) continue;
    const float bs = bias ? bias[col] : 0.f;
    #pragma unroll
    for (int mi = 0; mi < 4; ++mi) {
      #pragma unroll
      for (int j = 0; j < 4; ++j) {
        float v = acc[mi][ni][j] * p.scale + bs;
        if (p.act == 1) v = 1.f / (1.f + __expf(-v));
        const long idx = (long)(rbase + mi*16 + rsub + j) * ldc + col;
        if (p.outf) ((float*)Cp)[idx] = v;
        else        Cp[idx] = f2b(v);
      }
    }
  }
}

// ---------------------------------------------------------------------------
// Fused flash attention: S=1024, head dim 64, scale 1/8.
// Grid (qtile=8, head=16, window=4); 256 threads (4 waves), wave = 32 q-rows.
// K tile 64 keys staged row-major in LDS; V staged transposed; P staged
// per-wave in LDS so PV uses the same frag layout as gemm_nt.
// ---------------------------------------------------------------------------
struct FlashP {
  const u16 *q, *k, *v; u16* o;
  long ldq, ldkv, ldo;   // row strides (elements)
  long qB, kvB, oB;      // per-window batch strides
};

__global__ __launch_bounds__(256) void flash_k(FlashP p) {
  const int t = threadIdx.x, w4 = t >> 6, lane = t & 63;
  const int qt = blockIdx.x, h = blockIdx.y, wz = blockIdx.z;
  const int fr = lane & 15, g = lane >> 4, fk = g * 8;
  __shared__ __align__(16) u16 kt[64][72];
  __shared__ __align__(16) u16 vt[64][72];
  __shared__ __align__(16) u16 pl[4][32][72];

  const u16* Q = p.q + (long)wz*p.qB + (long)(qt*128 + w4*32)*p.ldq + h*64;
  const u16* K = p.k + (long)wz*p.kvB + h*64;
  const u16* V = p.v + (long)wz*p.kvB + h*64;

  short8 aq[2][2];
  #pragma unroll
  for (int mi = 0; mi < 2; ++mi)
    #pragma unroll
    for (int ks = 0; ks < 2; ++ks)
      aq[mi][ks] = *(const short8*)&Q[(long)(mi*16 + fr)*p.ldq + ks*32 + fk];

  f32x4 acc[2][4] = {};
  float mst[2][4], lst[2][4];
  #pragma unroll
  for (int mi = 0; mi < 2; ++mi)
    #pragma unroll
    for (int j = 0; j < 4; ++j) { mst[mi][j] = -3e38f; lst[mi][j] = 0.f; }

  const int srow = t >> 2, sseg = (t & 3) * 16;   // staging role: key row, d segment

  for (int k0 = 0; k0 < 1024; k0 += 64) {
    // ---- stage K (row-major) and V (transposed) ----
    {
      const u16* Kr = K + (long)(k0 + srow)*p.ldkv + sseg;
      const u16* Vr = V + (long)(k0 + srow)*p.ldkv + sseg;
      *(short8*)&kt[srow][sseg]     = *(const short8*)Kr;
      *(short8*)&kt[srow][sseg + 8] = *(const short8*)(Kr + 8);
      ushort8 v0 = *(const ushort8*)Vr;
      ushort8 v1 = *(const ushort8*)(Vr + 8);
      #pragma unroll
      for (int e = 0; e < 8; ++e) {
        vt[sseg + e][srow]     = v0[e];
        vt[sseg + 8 + e][srow] = v1[e];
      }
    }
    __syncthreads();

    // ---- S = Q K^T (32 x 64 per wave) ----
    f32x4 s[2][4] = {};
    #pragma unroll
    for (int ni = 0; ni < 4; ++ni) {
      short8 bk0 = *(const short8*)&kt[ni*16 + fr][fk];
      short8 bk1 = *(const short8*)&kt[ni*16 + fr][32 + fk];
      #pragma unroll
      for (int mi = 0; mi < 2; ++mi) {
        s[mi][ni] = __builtin_amdgcn_mfma_f32_16x16x32_bf16(aq[mi][0], bk0, s[mi][ni], 0, 0, 0);
        s[mi][ni] = __builtin_amdgcn_mfma_f32_16x16x32_bf16(aq[mi][1], bk1, s[mi][ni], 0, 0, 0);
      }
    }
    #pragma unroll
    for (int mi = 0; mi < 2; ++mi)
      #pragma unroll
      for (int ni = 0; ni < 4; ++ni) s[mi][ni] *= 0.125f;

    // ---- online softmax (rows live on 16-lane groups; reduce via xor 1,2,4,8) ----
    #pragma unroll
    for (int mi = 0; mi < 2; ++mi) {
      #pragma unroll
      for (int j = 0; j < 4; ++j) {
        float rm = -3e38f;
        #pragma unroll
        for (int ni = 0; ni < 4; ++ni) rm = fmaxf(rm, s[mi][ni][j]);
        #pragma unroll
        for (int o = 8; o; o >>= 1) rm = fmaxf(rm, __shfl_xor(rm, o, 64));
        const float mnew = fmaxf(mst[mi][j], rm);
        const float alpha = __expf(mst[mi][j] - mnew);
        float rs = 0.f;
        #pragma unroll
        for (int ni = 0; ni < 4; ++ni) {
          const float pv = __expf(s[mi][ni][j] - mnew);
          s[mi][ni][j] = pv;
          rs += pv;
        }
        #pragma unroll
        for (int o = 8; o; o >>= 1) rs += __shfl_xor(rs, o, 64);
        lst[mi][j] = lst[mi][j]*alpha + rs;
        mst[mi][j] = mnew;
        #pragma unroll
        for (int ni = 0; ni < 4; ++ni) acc[mi][ni][j] *= alpha;
      }
    }

    // ---- P -> LDS (per-wave region, row-major [qrow][key]) ----
    #pragma unroll
    for (int mi = 0; mi < 2; ++mi)
      #pragma unroll
      for (int ni = 0; ni < 4; ++ni)
        #pragma unroll
        for (int j = 0; j < 4; ++j)
          pl[w4][mi*16 + g*4 + j][ni*16 + fr] = f2b(s[mi][ni][j]);

    // ---- PV accumulate: A = P (from pl), B = V^T (from vt) ----
    #pragma unroll
    for (int ks = 0; ks < 2; ++ks) {
      short8 pa0 = *(const short8*)&pl[w4][fr][ks*32 + fk];
      short8 pa1 = *(const short8*)&pl[w4][16 + fr][ks*32 + fk];
      #pragma unroll
      for (int nv = 0; nv < 4; ++nv) {
        short8 bvv = *(const short8*)&vt[nv*16 + fr][ks*32 + fk];
        acc[0][nv] = __builtin_amdgcn_mfma_f32_16x16x32_bf16(pa0, bvv, acc[0][nv], 0, 0, 0);
        acc[1][nv] = __builtin_amdgcn_mfma_f32_16x16x32_bf16(pa1, bvv, acc[1][nv], 0, 0, 0);
      }
    }
    __syncthreads();   // protect kt/vt before next tile staging
  }

  // ---- epilogue: out = acc / l ----
  u16* O = p.o + (long)wz*p.oB + (long)(qt*128 + w4*32)*p.ldo + h*64;
  #pragma unroll
  for (int mi = 0; mi < 2; ++mi) {
    #pragma unroll
    for (int j = 0; j < 4; ++j) {
      const float inv = 1.f / lst[mi][j];
      #pragma unroll
      for (int nv = 0; nv < 4; ++nv)
        O[(long)(mi*16 + g*4 + j)*p.ldo + nv*16 + fr] = f2b(acc[mi][nv][j] * inv);
    }
  }
}

// -------- qs = sum_query @ wq^T + bq  (grid 16, 256 thr, k-split) --------
__global__ void gemv_qs(const float* sq, const float* w, const float* b, float* out) {
  const int t = threadIdx.x, nl = t & 63, kq = t >> 6;
  const int n = blockIdx.x*64 + nl;
  const float* row = w + (long)n * 1024 + kq*256;
  const float* q = sq + kq*256;
  float s = 0.f;
  for (int k = 0; k < 256; k += 4) {
    float4 ww = *(const float4*)&row[k];
    float4 qq = *(const float4*)&q[k];
    s += qq.x*ww.x + qq.y*ww.y + qq.z*ww.z + qq.w*ww.w;
  }
  __shared__ float ps[4][64];
  ps[kq][nl] = s;
  __syncthreads();
  if (t < 64) out[blockIdx.x*64 + t] = ps[0][t]+ps[1][t]+ps[2][t]+ps[3][t] + b[blockIdx.x*64 + t];
}

// ------- summary attention: block (h,w), 256 threads, k-parallel -------
__global__ void sum_attend(const float* qs, const u16* sumkv, float* content, float* pall) {
  const int h = blockIdx.x, w = blockIdx.y, t = threadIdx.x;
  const int lane = t & 63, wv = t >> 6;
  __shared__ float qsh[64];
  __shared__ float sc[1024];
  __shared__ float rmax[4], rsum[4];
  __shared__ float po[4][64];
  if (t < 64) qsh[t] = qs[h*64 + t];
  __syncthreads();
  const u16* kbase = sumkv + (long)w*2097152 + h*64;
  float e[4];
  float mx = -1e30f;
  #pragma unroll
  for (int j = 0; j < 4; ++j) {
    const int k = j*256 + t;
    const u16* krow = kbase + (long)k * 2048;
    float s = 0.f;
    #pragma unroll
    for (int d = 0; d < 64; d += 8) {
      ushort8 kk = *(const ushort8*)&krow[d];
      #pragma unroll
      for (int q = 0; q < 8; ++q) s += qsh[d+q] * b2f(kk[q]);
    }
    s *= 0.125f;
    e[j] = s;
    mx = fmaxf(mx, s);
  }
  #pragma unroll
  for (int o = 32; o; o >>= 1) mx = fmaxf(mx, __shfl_xor(mx, o, 64));
  if (lane == 0) rmax[wv] = mx;
  __syncthreads();
  mx = fmaxf(fmaxf(rmax[0],rmax[1]), fmaxf(rmax[2],rmax[3]));
  float sum = 0.f;
  #pragma unroll
  for (int j = 0; j < 4; ++j) { e[j] = __expf(e[j]-mx); sum += e[j]; }
  #pragma unroll
  for (int o = 32; o; o >>= 1) sum += __shfl_xor(sum, o, 64);
  if (lane == 0) rsum[wv] = sum;
  __syncthreads();
  const float inv = 1.f / (rsum[0]+rsum[1]+rsum[2]+rsum[3]);
  float* pr = pall + ((long)w*16 + h)*1024;
  #pragma unroll
  for (int j = 0; j < 4; ++j) {
    const int k = j*256 + t;
    const float pn = e[j]*inv;
    sc[k] = pn;
    pr[k] = pn;
  }
  __syncthreads();
  const u16* vbase = sumkv + (long)w*2097152 + 1024 + h*64;
  float o = 0.f;
  const int k0 = wv*256;
  for (int k = k0; k < k0+256; ++k) o += sc[k] * b2f(vbase[(long)k*2048 + lane]);
  po[wv][lane] = o;
  __syncthreads();
  if (t < 64) content[(long)w*1024 + h*64 + t] = po[0][t]+po[1][t]+po[2][t]+po[3][t];
}

__global__ void wavg_k(const float* pall, float* wavg) {
  const int w = blockIdx.y, k = blockIdx.x*256 + threadIdx.x;
  float s = 0.f;
  #pragma unroll
  for (int h = 0; h < 16; ++h) s += pall[((long)w*16 + h)*1024 + k];
  wavg[w*1024 + k] = s * (1.f/16.f);
}

// ------- content projection (grid (16,4), 256 thr, k-split) -------
__global__ void contproj_k(const float* content, const float* w_, const float* b, float* out) {
  const int w = blockIdx.y, t = threadIdx.x;
  const int nl = t & 63, kq = t >> 6;
  const int n = blockIdx.x*64 + nl;
  const float* c = content + w*1024 + kq*256;
  const float* row = w_ + (long)n * 1024 + kq*256;
  float s = 0.f;
  for (int k = 0; k < 256; k += 4) {
    float4 ww = *(const float4*)&row[k];
    s += c[k]*ww.x + c[k+1]*ww.y + c[k+2]*ww.z + c[k+3]*ww.w;
  }
  __shared__ float ps[4][64];
  ps[kq][nl] = s;
  __syncthreads();
  if (t < 64) out[w*1024 + blockIdx.x*64 + t] = ps[0][t]+ps[1][t]+ps[2][t]+ps[3][t] + b[blockIdx.x*64 + t];
}

// ------- attn_stats phase A: parallel rank-count (grid (16,4), 256 thr) -----
__global__ void stats1_k(const float* wavg, float* part) {
  const int c = blockIdx.x, w = blockIdx.y, t = threadIdx.x;
  __shared__ float a[1024];
  for (int i = t; i < 1024; i += 256) a[i] = wavg[w*1024 + i];
  __syncthreads();
  const int jl = t & 63, iq = t >> 6;
  const int j = c*64 + jl;
  const float aj = a[j];
  int pr = 0;
  const int i0 = iq*256;
  #pragma unroll 8
  for (int i = i0; i < i0+256; ++i) {
    const float ai = a[i];
    pr += (ai < aj) || (ai == aj && i < j);
  }
  __shared__ int prs[4][64];
  prs[iq][jl] = pr;
  __syncthreads();
  if (t < 64) {
    const int rank = 1 + prs[0][jl] + prs[1][jl] + prs[2][jl] + prs[3][jl];
    float ent = -aj * logf(aj + 1e-8f);
    float gnum = (float)rank * aj;
    float ssum = aj;
    float mx = aj;
    float top5 = (rank >= 1020) ? aj : 0.f;
    #pragma unroll
    for (int o = 32; o; o >>= 1) {
      ent += __shfl_xor(ent, o, 64);
      gnum += __shfl_xor(gnum, o, 64);
      ssum += __shfl_xor(ssum, o, 64);
      mx = fmaxf(mx, __shfl_xor(mx, o, 64));
      top5 += __shfl_xor(top5, o, 64);
    }
    if (t == 0) {
      float* pp = part + ((w*16 + c) * 5);
      pp[0]=ent; pp[1]=gnum; pp[2]=ssum; pp[3]=mx; pp[4]=top5;
    }
  }
}

// ------- attn_stats phase B: reduce 16 chunk-partials (grid 4, 128 thr) -----
__global__ void stats2_k(const float* part, float* stats) {
  const int w = blockIdx.x, t = threadIdx.x;
  const int c = t & 15, stat = t >> 4;
  float v = 0.f;
  const bool active = stat < 5;
  if (active) v = part[(w*16 + c)*5 + stat];
  #pragma unroll
  for (int o = 8; o; o >>= 1) {
    const float ov = __shfl_xor(v, o, 64);
    v = (stat == 3) ? fmaxf(v, ov) : (v + ov);
  }
  __shared__ float r5[5];
  if (active && c == 0) r5[stat] = v;
  __syncthreads();
  if (t == 0) {
    stats[w*4+0] = r5[0];
    stats[w*4+1] = 2.f*r5[1]/(1024.f*r5[2] + 1e-8f) - 1025.f/1024.f;
    stats[w*4+2] = r5[3];
    stats[w*4+3] = r5[4];
  }
}

// ------- pat MLP + summary combine (grid 4, 256 thr, k-split) -------
__global__ void patsum_k(const float* stats, const float* contprj,
                         const float* pw1, const float* pb1, const float* pw2, const float* pb2,
                         const float* combw, const float* combb, float* summ) {
  const int w = blockIdx.x, t = threadIdx.x;
  const int nl = t & 63, kq = t >> 6;
  __shared__ float p1[64], pat[64];
  __shared__ float ps[4][64];
  __shared__ float ps2[4][64];
  if (t < 64) {
    float s = 0.f;
    #pragma unroll
    for (int k = 0; k < 4; ++k) s += stats[w*4+k] * pw1[t*4+k];
    p1[t] = fmaxf(s + pb1[t], 0.f);
  }
  __syncthreads();
  {
    float s = 0.f;
    const float* rw = pw2 + (long)nl*64 + kq*16;
    const float* pp = p1 + kq*16;
    #pragma unroll
    for (int k = 0; k < 16; ++k) s += pp[k] * rw[k];
    ps[kq][nl] = s;
  }
  __syncthreads();
  if (t < 64) pat[t] = ps[0][t]+ps[1][t]+ps[2][t]+ps[3][t] + pb2[t];
  __syncthreads();
  const float* c = contprj + w*1024;
  const float* row = combw + (long)nl * 1088;
  float s = 0.f;
  const int k0 = kq*272;
  for (int k = k0; k < k0+272; ++k) {
    const float rv = row[k];
    const float cv = (k < 1024) ? c[k] : pat[k-1024];
    s += cv * rv;
  }
  ps2[kq][nl] = s;
  __syncthreads();
  if (t < 64) summ[w*64 + t] = ps2[0][t]+ps2[1][t]+ps2[2][t]+ps2[3][t] + combb[t];
}

// ---------------- meta attention + routing (1 block, 64 threads) ------------
__global__ void meta_k(const float* summ, const float* miw, const float* mib,
                       const float* mow, const float* mob, const float* rw1, const float* rb1,
                       const float* rw2, const float* rb2, float* routing) {
  const int t = threadIdx.x;
  __shared__ float qkv[4][192];
  __shared__ float sc[64];
  __shared__ float o[4][64];
  __shared__ float rf[4][64];
  __shared__ float t1[4][64];
  __shared__ float lg[4];
  for (int idx = t; idx < 768; idx += 64) {
    const int w = idx / 192, rrow = idx % 192;
    const float* rw = miw + (long)rrow * 64;
    float s = 0.f;
    for (int k = 0; k < 64; ++k) s += summ[w*64+k] * rw[k];
    qkv[w][rrow] = s + mib[rrow];
  }
  __syncthreads();
  {
    const int h = t >> 4, i = (t >> 2) & 3, j = t & 3;
    float s = 0.f;
    #pragma unroll
    for (int d = 0; d < 16; ++d) s += qkv[i][h*16+d] * qkv[j][64 + h*16+d];
    sc[t] = s * 0.25f;
  }
  __syncthreads();
  if (t < 16) {
    const float a0=sc[t*4], a1=sc[t*4+1], a2=sc[t*4+2], a3=sc[t*4+3];
    const float m = fmaxf(fmaxf(a0,a1), fmaxf(a2,a3));
    const float e0=__expf(a0-m), e1=__expf(a1-m), e2=__expf(a2-m), e3=__expf(a3-m);
    const float s = e0+e1+e2+e3;
    sc[t*4]=e0/s; sc[t*4+1]=e1/s; sc[t*4+2]=e2/s; sc[t*4+3]=e3/s;
  }
  __syncthreads();
  for (int idx = t; idx < 256; idx += 64) {
    const int i = idx >> 6, c = idx & 63, h = c >> 4;
    float s = 0.f;
    #pragma unroll
    for (int j = 0; j < 4; ++j) s += sc[(h*4+i)*4+j] * qkv[j][128 + c];
    o[i][c] = s;
  }
  __syncthreads();
  for (int idx = t; idx < 256; idx += 64) {
    const int i = idx >> 6, n = idx & 63;
    const float* rw = mow + (long)n * 64;
    float s = 0.f;
    for (int k = 0; k < 64; ++k) s += o[i][k] * rw[k];
    rf[i][n] = s + mob[n];
  }
  __syncthreads();
  for (int idx = t; idx < 256; idx += 64) {
    const int i = idx >> 6, n = idx & 63;
    const float* rw = rw1 + (long)n * 64;
    float s = 0.f;
    for (int k = 0; k < 64; ++k) s += rf[i][k] * rw[k];
    t1[i][n] = fmaxf(s + rb1[n], 0.f);
  }
  __syncthreads();
  if (t < 4) {
    float s = 0.f;
    for (int k = 0; k < 64; ++k) s += t1[t][k] * rw2[k];
    lg[t] = s + rb2[0];
  }
  __syncthreads();
  if (t == 0) {
    const float m = fmaxf(fmaxf(lg[0],lg[1]), fmaxf(lg[2],lg[3]));
    float e[4], s = 0.f;
    #pragma unroll
    for (int i = 0; i < 4; ++i) { e[i] = __expf(lg[i]-m); s += e[i]; }
    #pragma unroll
    for (int i = 0; i < 4; ++i) routing[i] = e[i]/s;
  }
}

// ---------------- routing-weighted kv mix ----------------
__global__ void kvr_k(const u16* local, const float* routing, u16* kvr) {
  const int r = blockIdx.y;
  const long e = ((long)blockIdx.x*256 + threadIdx.x) * 8;
  float rm[4]; float s = 0.f;
  #pragma unroll
  for (int w = 0; w < 4; ++w) { rm[w] = (w == r) ? 0.f : routing[w]; s += rm[w]; }
  const float inv = 1.f / (s + 1e-8f);
  ushort8 a0 = *(const ushort8*)&local[e];
  ushort8 a1 = *(const ushort8*)&local[1048576 + e];
  ushort8 a2 = *(const ushort8*)&local[2097152 + e];
  ushort8 a3 = *(const ushort8*)&local[3145728 + e];
  ushort8 out;
  #pragma unroll
  for (int j = 0; j < 8; ++j)
    out[j] = f2b((rm[0]*b2f(a0[j]) + rm[1]*b2f(a1[j]) + rm[2]*b2f(a2[j]) + rm[3]*b2f(a3[j])) * inv);
  *(ushort8*)&kvr[(long)r*1048576 + e] = out;
}

// ---------------- concat [local | cross] ----------------
__global__ void gcat_k(const u16* local, const u16* cross, u16* gcat) {
  const long e = ((long)blockIdx.x*256 + threadIdx.x) * 8;
  const long row = e >> 11, col = e & 2047;
  const u16* src = (col < 1024) ? &local[row*1024 + col] : &cross[row*1024 + col - 1024];
  *(ushort8*)&gcat[e] = *(const ushort8*)src;
}

// ---------------- comb = g*cross + (1-g)*local ----------------
__global__ void comb_k(const u16* g, const u16* cross, const u16* local, u16* comb) {
  const long e = ((long)blockIdx.x*256 + threadIdx.x) * 8;
  ushort8 gg = *(const ushort8*)&g[e];
  ushort8 cc = *(const ushort8*)&cross[e];
  ushort8 ll = *(const ushort8*)&local[e];
  ushort8 out;
  #pragma unroll
  for (int j = 0; j < 8; ++j) {
    const float gf = b2f(gg[j]);
    out[j] = f2b(gf*b2f(cc[j]) + (1.f-gf)*b2f(ll[j]));
  }
  *(ushort8*)&comb[e] = out;
}

// ---------------------------------------------------------------------------
static void gemm1(hipStream_t st, dim3 grid,
                  const u16* A, long lda, const u16* B, long ldb,
                  u16* C, long ldc, const float* bias,
                  int K, int N, float scale, int act, int outf) {
  GemmP p = {};
  p.A=A; p.B=B; p.C=C; p.bias=bias;
  p.lda=lda; p.ldb=ldb; p.ldc=ldc;
  p.K=K; p.Nstore=N; p.ySplit=1<<30; p.act=act; p.outf=outf; p.scale=scale;
  gemm_nt<<<grid, dim3(512), 0, st>>>(p);
}

extern "C" void kernel_launch(void* const* d_in, const int* in_sizes, int n_in,
                              void* d_out, int out_size, void* d_ws, size_t ws_size,
                              hipStream_t stream) {
  (void)in_sizes; (void)n_in; (void)out_size; (void)ws_size;
  const float* x   = (const float*)d_in[0];
  const float* liw = (const float*)d_in[1];
  const float* lib = (const float*)d_in[2];
  const float* low = (const float*)d_in[3];
  const float* lob = (const float*)d_in[4];
  const float* sq  = (const float*)d_in[5];
  const float* siw = (const float*)d_in[6];
  const float* sib = (const float*)d_in[7];
  const float* sow = (const float*)d_in[8];
  const float* sob = (const float*)d_in[9];
  const float* pw1 = (const float*)d_in[10];
  const float* pb1 = (const float*)d_in[11];
  const float* pw2 = (const float*)d_in[12];
  const float* pb2 = (const float*)d_in[13];
  const float* cbw = (const float*)d_in[14];
  const float* cbb = (const float*)d_in[15];
  const float* miw = (const float*)d_in[16];
  const float* mib = (const float*)d_in[17];
  const float* mow = (const float*)d_in[18];
  const float* mob = (const float*)d_in[19];
  const float* rw1 = (const float*)d_in[20];
  const float* rb1 = (const float*)d_in[21];
  const float* rw2 = (const float*)d_in[22];
  const float* rb2 = (const float*)d_in[23];
  const float* ciw = (const float*)d_in[24];
  const float* cib = (const float*)d_in[25];
  const float* cow = (const float*)d_in[26];
  const float* cob = (const float*)d_in[27];
  const float* gw  = (const float*)d_in[28];
  const float* gb  = (const float*)d_in[29];
  const float* pw  = (const float*)d_in[30];
  const float* pb  = (const float*)d_in[31];

  char* ws = (char*)d_ws;
  u16* qkv    = (u16*)(ws + 0);            // 4096x3072 bf16
  u16* aout   = (u16*)(ws + 25165824);     // 4096x1024 (local attn out, later cross attn out)
  u16* local  = (u16*)(ws + 33554432);     // 4096x1024
  u16* scratch= (u16*)(ws + 41943040);     // (ex-scores; first 6MB doubles as liwb)
  u16* s2048  = (u16*)(ws + 79691776);     // 4096x2048 (sumKV -> crossKV -> gatecat)
  u16* cq     = (u16*)(ws + 96468992);     // 4096x1024 (cross Q, later g)
  u16* kvr    = (u16*)(ws + 104857600);    // 4096x1024 (mixed kv, later comb)
  u16* crossb = (u16*)(ws + 113246208);    // 4096x1024 (doubles as xb before step 11)
  char* sf = ws + 121634816;               // fp32 scratch region
  float* qs      = (float*)(sf + 0);
  float* pall    = (float*)(sf + 4096);
  float* wavg    = (float*)(sf + 266240);
  float* content = (float*)(sf + 282624);
  float* contprj = (float*)(sf + 299008);
  float* stats   = (float*)(sf + 315392);
  float* summ    = (float*)(sf + 315456);
  float* routing = (float*)(sf + 316480);
  float* part    = (float*)(sf + 316544);
  // bf16 weight copies
  u16* siwkvb = (u16*)(ws + 122028032);    // 2M el
  u16* lowb   = (u16*)(ws + 126222336);    // 1M el
  u16* ciwb   = (u16*)(ws + 128319488);    // 3M el
  u16* cowb   = (u16*)(ws + 134610944);    // 1M el
  u16* gwb    = (u16*)(ws + 136708096);    // 2M el
  u16* pwb    = (u16*)(ws + 140902400);    // 1M el
  u16* xb   = crossb;                      // alias: x bf16 (dead after step 1)
  u16* liwb = scratch;                     // alias: liw bf16 (dead after step 1)

  // 0. fp32 -> bf16 conversions (one launch, 8 segments)
  CvtP cp;
  cp.src[0]=x;   cp.dst[0]=xb;     cp.n[0]=4194304;
  cp.src[1]=liw; cp.dst[1]=liwb;   cp.n[1]=3145728;
  cp.src[2]=low; cp.dst[2]=lowb;   cp.n[2]=1048576;
  cp.src[3]=siw+1048576; cp.dst[3]=siwkvb; cp.n[3]=2097152;
  cp.src[4]=ciw; cp.dst[4]=ciwb;   cp.n[4]=3145728;
  cp.src[5]=cow; cp.dst[5]=cowb;   cp.n[5]=1048576;
  cp.src[6]=gw;  cp.dst[6]=gwb;    cp.n[6]=2097152;
  cp.src[7]=pw;  cp.dst[7]=pwb;    cp.n[7]=1048576;
  cvt_multi<<<dim3(2048, 8), dim3(256), 0, stream>>>(cp);

  // 1. local QKV projection
  gemm1(stream, dim3(32,24), xb,1024, liwb,1024, qkv,3072, lib, 1024, 3072, 1.f, 0, 0);

  // 2. fused local self-attention (all 4 windows, 16 heads)
  {
    FlashP fp;
    fp.q = qkv; fp.k = qkv + 1024; fp.v = qkv + 2048; fp.o = aout;
    fp.ldq = 3072; fp.ldkv = 3072; fp.ldo = 1024;
    fp.qB = 3145728; fp.kvB = 3145728; fp.oB = 1048576;
    flash_k<<<dim3(8,16,4), dim3(256), 0, stream>>>(fp);
  }

  // 3. local out-projection
  gemm1(stream, dim3(32,8), aout,1024, lowb,1024, local,1024, lob, 1024, 1024, 1.f, 0, 0);

  // 4. combined crossQ (y<8) + summary K/V (y>=8) projections — same A
  {
    GemmP p = {};
    p.A = local; p.lda = 1024; p.K = 1024; p.scale = 1.f;
    p.B = ciwb;   p.C = cq;    p.bias = cib;      p.ldb = 1024; p.ldc = 1024; p.Nstore = 1024;
    p.B2 = siwkvb; p.C2 = s2048; p.bias2 = sib+1024; p.ldb2 = 1024; p.ldc2 = 2048; p.Nstore2 = 2048;
    p.ySplit = 8;
    gemm_nt<<<dim3(32,24), dim3(512), 0, stream>>>(p);
  }

  // 5. summaries
  gemv_qs<<<dim3(16), dim3(256), 0, stream>>>(sq, siw, sib, qs);
  sum_attend<<<dim3(16,4), dim3(256), 0, stream>>>(qs, s2048, content, pall);
  wavg_k<<<dim3(4,4), dim3(256), 0, stream>>>(pall, wavg);
  contproj_k<<<dim3(16,4), dim3(256), 0, stream>>>(content, sow, sob, contprj);
  stats1_k<<<dim3(16,4), dim3(256), 0, stream>>>(wavg, part);
  stats2_k<<<dim3(4), dim3(128), 0, stream>>>(part, stats);
  patsum_k<<<dim3(4), dim3(256), 0, stream>>>(stats, contprj, pw1, pb1, pw2, pb2, cbw, cbb, summ);

  // 6. meta attention + routing
  meta_k<<<dim3(1), dim3(64), 0, stream>>>(summ, miw, mib, mow, mob, rw1, rb1, rw2, rb2, routing);

  // 7. per-rank mixed kv
  kvr_k<<<dim3(512,4), dim3(256), 0, stream>>>(local, routing, kvr);

  // 8. cross K/V projection (overwrites s2048 after summaries consumed it)
  gemm1(stream, dim3(32,16), kvr,1024, ciwb+1048576,1024, s2048,2048, cib+1024, 1024, 2048, 1.f, 0, 0);

  // 9. fused cross attention (all 4 ranks, 16 heads)
  {
    FlashP fp;
    fp.q = cq; fp.k = s2048; fp.v = s2048 + 1024; fp.o = aout;
    fp.ldq = 1024; fp.ldkv = 2048; fp.ldo = 1024;
    fp.qB = 1048576; fp.kvB = 2097152; fp.oB = 1048576;
    flash_k<<<dim3(8,16,4), dim3(256), 0, stream>>>(fp);
  }

  // 10. cross out-projection
  gemm1(stream, dim3(32,8), aout,1024, cowb,1024, crossb,1024, cob, 1024, 1024, 1.f, 0, 0);

  // 11-12. gate
  gcat_k<<<dim3(4096), dim3(256), 0, stream>>>(local, crossb, s2048);
  gemm1(stream, dim3(32,8), s2048,2048, gwb,2048, cq,1024, gb, 2048, 1024, 1.f, 1, 0);

  // 13. comb = g*cross + (1-g)*local
  comb_k<<<dim3(2048), dim3(256), 0, stream>>>(cq, crossb, local, kvr);

  // 14. final projection -> d_out (fp32)
  gemm1(stream, dim3(32,8), kvr,1024, pwb,1024, (u16*)d_out,1024, pb, 1024, 1024, 1.f, 0, 1);
}

// Round 7
// 463.080 us; speedup vs baseline: 2.4716x; 1.0762x over previous
//
#include <hip/hip_runtime.h>
#include <hip/hip_bf16.h>
#include <stdint.h>

typedef uint16_t u16;
typedef __attribute__((ext_vector_type(8))) short short8;
typedef __attribute__((ext_vector_type(8))) unsigned short ushort8;
typedef __attribute__((ext_vector_type(4))) float f32x4;

#define AS1 __attribute__((address_space(1)))
#define AS3 __attribute__((address_space(3)))

__device__ __forceinline__ float b2f(u16 u){
  union{uint32_t i; float f;} v; v.i=((uint32_t)u)<<16; return v.f;
}
__device__ __forceinline__ u16 f2b(float f){
  union{uint32_t i; float f;} v; v.f=f;
  return (u16)((v.i + 0x7fffu + ((v.i>>16)&1u))>>16);
}
__device__ __forceinline__ u16 f2bf(float f){   // hw-friendly convert (RTE)
  __hip_bfloat16 h = __float2bfloat16(f);
  return *reinterpret_cast<u16*>(&h);
}

// ---------------- fused fp32 -> bf16 conversions (8 segments, 1 launch) -----
struct CvtP { const float* src[8]; u16* dst[8]; long n[8]; };
__global__ void cvt_multi(CvtP p) {
  const int seg = blockIdx.y;
  const long i = ((long)blockIdx.x*256 + threadIdx.x)*8;
  if (i >= p.n[seg]) return;
  const float* in = p.src[seg];
  float4 a = *(const float4*)&in[i];
  float4 b = *(const float4*)&in[i+4];
  ushort8 o;
  o[0]=f2b(a.x); o[1]=f2b(a.y); o[2]=f2b(a.z); o[3]=f2b(a.w);
  o[4]=f2b(b.x); o[5]=f2b(b.y); o[6]=f2b(b.z); o[7]=f2b(b.w);
  *(ushort8*)&p.dst[seg][i] = o;
}

// ---------------------------------------------------------------------------
// NT GEMM, 128x128 tile, BK=32, 8 waves (512 thr), double-buffered LDS.
// Optional second y-segment (ySplit) with its own B/C/bias/ldb/ldc/Nstore.
// ---------------------------------------------------------------------------
struct GemmP {
  const u16* A; const u16* B; u16* C; const float* bias;
  const u16* B2; u16* C2; const float* bias2;
  long lda, ldb, ldc, ldb2, ldc2;
  int K, Nstore, Nstore2, ySplit, act, outf;   // act: 0 none, 1 sigmoid
  float scale;
};

__global__ __launch_bounds__(512) void gemm_nt(GemmP p) {
  __shared__ __align__(16) u16 lA[2][4096];
  __shared__ __align__(16) u16 lB[2][4096];
  const int t = threadIdx.x;
  const int wave = t >> 6, lane = t & 63;
  int by = blockIdx.y;
  const u16* Bp; u16* Cp; const float* bias; long ldb, ldc; int nst;
  if (by >= p.ySplit) {
    by -= p.ySplit; Bp = p.B2; Cp = p.C2; bias = p.bias2;
    ldb = p.ldb2; ldc = p.ldc2; nst = p.Nstore2;
  } else {
    Bp = p.B; Cp = p.C; bias = p.bias; ldb = p.ldb; ldc = p.ldc; nst = p.Nstore;
  }
  const u16* A = p.A + (long)blockIdx.x * 128 * p.lda;
  const u16* B = Bp + (long)by * 128 * ldb;
  const int srow = t >> 2, skk = (t & 3) * 8;
  const int wr = wave >> 2, wc = wave & 3;
  const int fr = lane & 15, fk = (lane >> 4) * 8;
  f32x4 acc[4][2] = {};

  __builtin_amdgcn_global_load_lds((const AS1 void*)(A + (long)srow*p.lda + skk),
                                   (AS3 void*)&lA[0][t*8], 16, 0, 0);
  __builtin_amdgcn_global_load_lds((const AS1 void*)(B + (long)srow*ldb + skk),
                                   (AS3 void*)&lB[0][t*8], 16, 0, 0);
  __syncthreads();
  int cur = 0;
  for (int k0 = 0; k0 < p.K; k0 += 32) {
    if (k0 + 32 < p.K) {
      const int nb = cur ^ 1, kn = k0 + 32;
      __builtin_amdgcn_global_load_lds((const AS1 void*)(A + (long)srow*p.lda + kn + skk),
                                       (AS3 void*)&lA[nb][t*8], 16, 0, 0);
      __builtin_amdgcn_global_load_lds((const AS1 void*)(B + (long)srow*ldb + kn + skk),
                                       (AS3 void*)&lB[nb][t*8], 16, 0, 0);
    }
    short8 av[4], bv[2];
    #pragma unroll
    for (int mi = 0; mi < 4; ++mi) av[mi] = *(const short8*)&lA[cur][(wr*64 + mi*16 + fr)*32 + fk];
    #pragma unroll
    for (int ni = 0; ni < 2; ++ni) bv[ni] = *(const short8*)&lB[cur][(wc*32 + ni*16 + fr)*32 + fk];
    #pragma unroll
    for (int mi = 0; mi < 4; ++mi)
      #pragma unroll
      for (int ni = 0; ni < 2; ++ni)
        acc[mi][ni] = __builtin_amdgcn_mfma_f32_16x16x32_bf16(av[mi], bv[ni], acc[mi][ni], 0, 0, 0);
    __syncthreads();
    cur ^= 1;
  }

  const int rbase = blockIdx.x*128 + wr*64;
  const int cbase = by*128 + wc*32;
  const int rsub = (lane >> 4) * 4;
  #pragma unroll
  for (int ni = 0; ni < 2; ++ni) {
    const int col = cbase + ni*16 + fr;
    if (col >= nst) continue;
    const float bs = bias ? bias[col] : 0.f;
    #pragma unroll
    for (int mi = 0; mi < 4; ++mi) {
      #pragma unroll
      for (int j = 0; j < 4; ++j) {
        float v = acc[mi][ni][j] * p.scale + bs;
        if (p.act == 1) v = 1.f / (1.f + __expf(-v));
        const long idx = (long)(rbase + mi*16 + rsub + j) * ldc + col;
        if (p.outf) ((float*)Cp)[idx] = v;
        else        Cp[idx] = f2b(v);
      }
    }
  }
}

// ---------------------------------------------------------------------------
// Fused flash attention: S=1024, head dim 64, scale 1/8.
// Grid (qtile=16, head=16, window=4); 256 thr / 4 waves; wave = 16 q-rows.
// KVBLK=64. K row-major; V packed-transposed (b32 pair writes, 2-way banks);
// P per-wave in LDS. Prefetch next K/V tile into regs during compute.
// ---------------------------------------------------------------------------
struct FlashP {
  const u16 *q, *k, *v; u16* o;
  long ldq, ldkv, ldo;
  long qB, kvB, oB;
};

__global__ __launch_bounds__(256) void flash_k(FlashP p) {
  const int t = threadIdx.x, w4 = t >> 6, lane = t & 63;
  const int qt = blockIdx.x, h = blockIdx.y, wz = blockIdx.z;
  const int fr = lane & 15, g = lane >> 4, fk = g * 8;
  __shared__ __align__(16) u16 kt[64][72];
  __shared__ __align__(16) u16 vt[64][72];
  __shared__ __align__(16) u16 pl[4][16][72];

  const u16* Q = p.q + (long)wz*p.qB + (long)(qt*64 + w4*16)*p.ldq + h*64;
  const u16* K = p.k + (long)wz*p.kvB + h*64;
  const u16* V = p.v + (long)wz*p.kvB + h*64;

  short8 aq[2];
  aq[0] = *(const short8*)&Q[(long)fr*p.ldq + fk];
  aq[1] = *(const short8*)&Q[(long)fr*p.ldq + 32 + fk];

  f32x4 acc[4] = {};
  float mst[4], lst[4];
  #pragma unroll
  for (int j = 0; j < 4; ++j) { mst[j] = -3e38f; lst[j] = 0.f; }

  // staging roles: K coalesced rows; V key-pairs for packed transpose writes
  const int krow = t >> 2, kseg = (t & 3) * 16;
  const int vp = t & 31, vc = (t >> 5) * 8;

  short8 kr0, kr1, vr0, vr1;
  kr0 = *(const short8*)&K[(long)krow*p.ldkv + kseg];
  kr1 = *(const short8*)&K[(long)krow*p.ldkv + kseg + 8];
  vr0 = *(const short8*)&V[(long)(2*vp)*p.ldkv + vc];
  vr1 = *(const short8*)&V[(long)(2*vp + 1)*p.ldkv + vc];

  for (int it = 0; it < 16; ++it) {
    // ---- write staged regs to LDS ----
    *(short8*)&kt[krow][kseg]     = kr0;
    *(short8*)&kt[krow][kseg + 8] = kr1;
    #pragma unroll
    for (int e = 0; e < 8; ++e) {
      const uint32_t pk = (uint32_t)(uint16_t)vr0[e] | ((uint32_t)(uint16_t)vr1[e] << 16);
      *(uint32_t*)&vt[vc + e][2*vp] = pk;   // banks: 4e + vp -> 2-way, free
    }
    __syncthreads();

    // ---- prefetch next tile into regs (latency hides under compute) ----
    if (it + 1 < 16) {
      const int kn = (it + 1) * 64;
      kr0 = *(const short8*)&K[(long)(kn + krow)*p.ldkv + kseg];
      kr1 = *(const short8*)&K[(long)(kn + krow)*p.ldkv + kseg + 8];
      vr0 = *(const short8*)&V[(long)(kn + 2*vp)*p.ldkv + vc];
      vr1 = *(const short8*)&V[(long)(kn + 2*vp + 1)*p.ldkv + vc];
    }

    // ---- S = Q K^T (16 x 64 per wave) ----
    f32x4 s[4] = {};
    __builtin_amdgcn_s_setprio(1);
    #pragma unroll
    for (int ni = 0; ni < 4; ++ni) {
      short8 bk0 = *(const short8*)&kt[ni*16 + fr][fk];
      short8 bk1 = *(const short8*)&kt[ni*16 + fr][32 + fk];
      s[ni] = __builtin_amdgcn_mfma_f32_16x16x32_bf16(aq[0], bk0, s[ni], 0, 0, 0);
      s[ni] = __builtin_amdgcn_mfma_f32_16x16x32_bf16(aq[1], bk1, s[ni], 0, 0, 0);
    }
    __builtin_amdgcn_s_setprio(0);
    #pragma unroll
    for (int ni = 0; ni < 4; ++ni) s[ni] *= 0.125f;

    // ---- online softmax (row = g*4+j; reduce across 16-lane key groups) ----
    #pragma unroll
    for (int j = 0; j < 4; ++j) {
      float rm = fmaxf(fmaxf(s[0][j], s[1][j]), fmaxf(s[2][j], s[3][j]));
      #pragma unroll
      for (int o = 8; o; o >>= 1) rm = fmaxf(rm, __shfl_xor(rm, o, 64));
      const float mnew = fmaxf(mst[j], rm);
      const float alpha = __expf(mst[j] - mnew);
      float rs = 0.f;
      #pragma unroll
      for (int ni = 0; ni < 4; ++ni) {
        const float pv = __expf(s[ni][j] - mnew);
        s[ni][j] = pv;
        rs += pv;
      }
      #pragma unroll
      for (int o = 8; o; o >>= 1) rs += __shfl_xor(rs, o, 64);
      lst[j] = lst[j]*alpha + rs;
      mst[j] = mnew;
      #pragma unroll
      for (int nv = 0; nv < 4; ++nv) acc[nv][j] *= alpha;
    }

    // ---- P -> LDS (wave-private; same-wave RAW needs no barrier) ----
    #pragma unroll
    for (int ni = 0; ni < 4; ++ni)
      #pragma unroll
      for (int j = 0; j < 4; ++j)
        pl[w4][g*4 + j][ni*16 + fr] = f2bf(s[ni][j]);

    // ---- PV accumulate ----
    __builtin_amdgcn_s_setprio(1);
    #pragma unroll
    for (int ks = 0; ks < 2; ++ks) {
      short8 pa = *(const short8*)&pl[w4][fr][ks*32 + fk];
      #pragma unroll
      for (int nv = 0; nv < 4; ++nv) {
        short8 bvv = *(const short8*)&vt[nv*16 + fr][ks*32 + fk];
        acc[nv] = __builtin_amdgcn_mfma_f32_16x16x32_bf16(pa, bvv, acc[nv], 0, 0, 0);
      }
    }
    __builtin_amdgcn_s_setprio(0);
    __syncthreads();   // protect kt/vt before next tile's LDS writes
  }

  // ---- epilogue ----
  u16* O = p.o + (long)wz*p.oB + (long)(qt*64 + w4*16)*p.ldo + h*64;
  #pragma unroll
  for (int j = 0; j < 4; ++j) {
    const float inv = 1.f / lst[j];
    #pragma unroll
    for (int nv = 0; nv < 4; ++nv)
      O[(long)(g*4 + j)*p.ldo + nv*16 + fr] = f2bf(acc[nv][j] * inv);
  }
}

// -------- qs = sum_query @ wq^T + bq  (grid 16, 256 thr, k-split) --------
__global__ void gemv_qs(const float* sq, const float* w, const float* b, float* out) {
  const int t = threadIdx.x, nl = t & 63, kq = t >> 6;
  const int n = blockIdx.x*64 + nl;
  const float* row = w + (long)n * 1024 + kq*256;
  const float* q = sq + kq*256;
  float s = 0.f;
  for (int k = 0; k < 256; k += 4) {
    float4 ww = *(const float4*)&row[k];
    float4 qq = *(const float4*)&q[k];
    s += qq.x*ww.x + qq.y*ww.y + qq.z*ww.z + qq.w*ww.w;
  }
  __shared__ float ps[4][64];
  ps[kq][nl] = s;
  __syncthreads();
  if (t < 64) out[blockIdx.x*64 + t] = ps[0][t]+ps[1][t]+ps[2][t]+ps[3][t] + b[blockIdx.x*64 + t];
}

// ------- summary attention: block (h,w), 256 threads, k-parallel -------
__global__ void sum_attend(const float* qs, const u16* sumkv, float* content, float* pall) {
  const int h = blockIdx.x, w = blockIdx.y, t = threadIdx.x;
  const int lane = t & 63, wv = t >> 6;
  __shared__ float qsh[64];
  __shared__ float sc[1024];
  __shared__ float rmax[4], rsum[4];
  __shared__ float po[4][64];
  if (t < 64) qsh[t] = qs[h*64 + t];
  __syncthreads();
  const u16* kbase = sumkv + (long)w*2097152 + h*64;
  float e[4];
  float mx = -1e30f;
  #pragma unroll
  for (int j = 0; j < 4; ++j) {
    const int k = j*256 + t;
    const u16* krow = kbase + (long)k * 2048;
    float s = 0.f;
    #pragma unroll
    for (int d = 0; d < 64; d += 8) {
      ushort8 kk = *(const ushort8*)&krow[d];
      #pragma unroll
      for (int q = 0; q < 8; ++q) s += qsh[d+q] * b2f(kk[q]);
    }
    s *= 0.125f;
    e[j] = s;
    mx = fmaxf(mx, s);
  }
  #pragma unroll
  for (int o = 32; o; o >>= 1) mx = fmaxf(mx, __shfl_xor(mx, o, 64));
  if (lane == 0) rmax[wv] = mx;
  __syncthreads();
  mx = fmaxf(fmaxf(rmax[0],rmax[1]), fmaxf(rmax[2],rmax[3]));
  float sum = 0.f;
  #pragma unroll
  for (int j = 0; j < 4; ++j) { e[j] = __expf(e[j]-mx); sum += e[j]; }
  #pragma unroll
  for (int o = 32; o; o >>= 1) sum += __shfl_xor(sum, o, 64);
  if (lane == 0) rsum[wv] = sum;
  __syncthreads();
  const float inv = 1.f / (rsum[0]+rsum[1]+rsum[2]+rsum[3]);
  float* pr = pall + ((long)w*16 + h)*1024;
  #pragma unroll
  for (int j = 0; j < 4; ++j) {
    const int k = j*256 + t;
    const float pn = e[j]*inv;
    sc[k] = pn;
    pr[k] = pn;
  }
  __syncthreads();
  const u16* vbase = sumkv + (long)w*2097152 + 1024 + h*64;
  float o = 0.f;
  const int k0 = wv*256;
  for (int k = k0; k < k0+256; ++k) o += sc[k] * b2f(vbase[(long)k*2048 + lane]);
  po[wv][lane] = o;
  __syncthreads();
  if (t < 64) content[(long)w*1024 + h*64 + t] = po[0][t]+po[1][t]+po[2][t]+po[3][t];
}

__global__ void wavg_k(const float* pall, float* wavg) {
  const int w = blockIdx.y, k = blockIdx.x*256 + threadIdx.x;
  float s = 0.f;
  #pragma unroll
  for (int h = 0; h < 16; ++h) s += pall[((long)w*16 + h)*1024 + k];
  wavg[w*1024 + k] = s * (1.f/16.f);
}

// ------- content projection (grid (16,4), 256 thr, k-split) -------
__global__ void contproj_k(const float* content, const float* w_, const float* b, float* out) {
  const int w = blockIdx.y, t = threadIdx.x;
  const int nl = t & 63, kq = t >> 6;
  const int n = blockIdx.x*64 + nl;
  const float* c = content + w*1024 + kq*256;
  const float* row = w_ + (long)n * 1024 + kq*256;
  float s = 0.f;
  for (int k = 0; k < 256; k += 4) {
    float4 ww = *(const float4*)&row[k];
    s += c[k]*ww.x + c[k+1]*ww.y + c[k+2]*ww.z + c[k+3]*ww.w;
  }
  __shared__ float ps[4][64];
  ps[kq][nl] = s;
  __syncthreads();
  if (t < 64) out[w*1024 + blockIdx.x*64 + t] = ps[0][t]+ps[1][t]+ps[2][t]+ps[3][t] + b[blockIdx.x*64 + t];
}

// ------- attn_stats phase A: parallel rank-count (grid (16,4), 256 thr) -----
__global__ void stats1_k(const float* wavg, float* part) {
  const int c = blockIdx.x, w = blockIdx.y, t = threadIdx.x;
  __shared__ float a[1024];
  for (int i = t; i < 1024; i += 256) a[i] = wavg[w*1024 + i];
  __syncthreads();
  const int jl = t & 63, iq = t >> 6;
  const int j = c*64 + jl;
  const float aj = a[j];
  int pr = 0;
  const int i0 = iq*256;
  #pragma unroll 8
  for (int i = i0; i < i0+256; ++i) {
    const float ai = a[i];
    pr += (ai < aj) || (ai == aj && i < j);
  }
  __shared__ int prs[4][64];
  prs[iq][jl] = pr;
  __syncthreads();
  if (t < 64) {
    const int rank = 1 + prs[0][jl] + prs[1][jl] + prs[2][jl] + prs[3][jl];
    float ent = -aj * logf(aj + 1e-8f);
    float gnum = (float)rank * aj;
    float ssum = aj;
    float mx = aj;
    float top5 = (rank >= 1020) ? aj : 0.f;
    #pragma unroll
    for (int o = 32; o; o >>= 1) {
      ent += __shfl_xor(ent, o, 64);
      gnum += __shfl_xor(gnum, o, 64);
      ssum += __shfl_xor(ssum, o, 64);
      mx = fmaxf(mx, __shfl_xor(mx, o, 64));
      top5 += __shfl_xor(top5, o, 64);
    }
    if (t == 0) {
      float* pp = part + ((w*16 + c) * 5);
      pp[0]=ent; pp[1]=gnum; pp[2]=ssum; pp[3]=mx; pp[4]=top5;
    }
  }
}

// ------- attn_stats phase B: reduce 16 chunk-partials (grid 4, 128 thr) -----
__global__ void stats2_k(const float* part, float* stats) {
  const int w = blockIdx.x, t = threadIdx.x;
  const int c = t & 15, stat = t >> 4;
  float v = 0.f;
  const bool active = stat < 5;
  if (active) v = part[(w*16 + c)*5 + stat];
  #pragma unroll
  for (int o = 8; o; o >>= 1) {
    const float ov = __shfl_xor(v, o, 64);
    v = (stat == 3) ? fmaxf(v, ov) : (v + ov);
  }
  __shared__ float r5[5];
  if (active && c == 0) r5[stat] = v;
  __syncthreads();
  if (t == 0) {
    stats[w*4+0] = r5[0];
    stats[w*4+1] = 2.f*r5[1]/(1024.f*r5[2] + 1e-8f) - 1025.f/1024.f;
    stats[w*4+2] = r5[3];
    stats[w*4+3] = r5[4];
  }
}

// ------- pat MLP + summary combine (grid 4, 256 thr, k-split) -------
__global__ void patsum_k(const float* stats, const float* contprj,
                         const float* pw1, const float* pb1, const float* pw2, const float* pb2,
                         const float* combw, const float* combb, float* summ) {
  const int w = blockIdx.x, t = threadIdx.x;
  const int nl = t & 63, kq = t >> 6;
  __shared__ float p1[64], pat[64];
  __shared__ float ps[4][64];
  __shared__ float ps2[4][64];
  if (t < 64) {
    float s = 0.f;
    #pragma unroll
    for (int k = 0; k < 4; ++k) s += stats[w*4+k] * pw1[t*4+k];
    p1[t] = fmaxf(s + pb1[t], 0.f);
  }
  __syncthreads();
  {
    float s = 0.f;
    const float* rw = pw2 + (long)nl*64 + kq*16;
    const float* pp = p1 + kq*16;
    #pragma unroll
    for (int k = 0; k < 16; ++k) s += pp[k] * rw[k];
    ps[kq][nl] = s;
  }
  __syncthreads();
  if (t < 64) pat[t] = ps[0][t]+ps[1][t]+ps[2][t]+ps[3][t] + pb2[t];
  __syncthreads();
  const float* c = contprj + w*1024;
  const float* row = combw + (long)nl * 1088;
  float s = 0.f;
  const int k0 = kq*272;
  for (int k = k0; k < k0+272; ++k) {
    const float rv = row[k];
    const float cv = (k < 1024) ? c[k] : pat[k-1024];
    s += cv * rv;
  }
  ps2[kq][nl] = s;
  __syncthreads();
  if (t < 64) summ[w*64 + t] = ps2[0][t]+ps2[1][t]+ps2[2][t]+ps2[3][t] + combb[t];
}

// ---------------- meta attention + routing (1 block, 64 threads) ------------
__global__ void meta_k(const float* summ, const float* miw, const float* mib,
                       const float* mow, const float* mob, const float* rw1, const float* rb1,
                       const float* rw2, const float* rb2, float* routing) {
  const int t = threadIdx.x;
  __shared__ float qkv[4][192];
  __shared__ float sc[64];
  __shared__ float o[4][64];
  __shared__ float rf[4][64];
  __shared__ float t1[4][64];
  __shared__ float lg[4];
  for (int idx = t; idx < 768; idx += 64) {
    const int w = idx / 192, rrow = idx % 192;
    const float* rw = miw + (long)rrow * 64;
    float s = 0.f;
    for (int k = 0; k < 64; ++k) s += summ[w*64+k] * rw[k];
    qkv[w][rrow] = s + mib[rrow];
  }
  __syncthreads();
  {
    const int h = t >> 4, i = (t >> 2) & 3, j = t & 3;
    float s = 0.f;
    #pragma unroll
    for (int d = 0; d < 16; ++d) s += qkv[i][h*16+d] * qkv[j][64 + h*16+d];
    sc[t] = s * 0.25f;
  }
  __syncthreads();
  if (t < 16) {
    const float a0=sc[t*4], a1=sc[t*4+1], a2=sc[t*4+2], a3=sc[t*4+3];
    const float m = fmaxf(fmaxf(a0,a1), fmaxf(a2,a3));
    const float e0=__expf(a0-m), e1=__expf(a1-m), e2=__expf(a2-m), e3=__expf(a3-m);
    const float s = e0+e1+e2+e3;
    sc[t*4]=e0/s; sc[t*4+1]=e1/s; sc[t*4+2]=e2/s; sc[t*4+3]=e3/s;
  }
  __syncthreads();
  for (int idx = t; idx < 256; idx += 64) {
    const int i = idx >> 6, c = idx & 63, h = c >> 4;
    float s = 0.f;
    #pragma unroll
    for (int j = 0; j < 4; ++j) s += sc[(h*4+i)*4+j] * qkv[j][128 + c];
    o[i][c] = s;
  }
  __syncthreads();
  for (int idx = t; idx < 256; idx += 64) {
    const int i = idx >> 6, n = idx & 63;
    const float* rw = mow + (long)n * 64;
    float s = 0.f;
    for (int k = 0; k < 64; ++k) s += o[i][k] * rw[k];
    rf[i][n] = s + mob[n];
  }
  __syncthreads();
  for (int idx = t; idx < 256; idx += 64) {
    const int i = idx >> 6, n = idx & 63;
    const float* rw = rw1 + (long)n * 64;
    float s = 0.f;
    for (int k = 0; k < 64; ++k) s += rf[i][k] * rw[k];
    t1[i][n] = fmaxf(s + rb1[n], 0.f);
  }
  __syncthreads();
  if (t < 4) {
    float s = 0.f;
    for (int k = 0; k < 64; ++k) s += t1[t][k] * rw2[k];
    lg[t] = s + rb2[0];
  }
  __syncthreads();
  if (t == 0) {
    const float m = fmaxf(fmaxf(lg[0],lg[1]), fmaxf(lg[2],lg[3]));
    float e[4], s = 0.f;
    #pragma unroll
    for (int i = 0; i < 4; ++i) { e[i] = __expf(lg[i]-m); s += e[i]; }
    #pragma unroll
    for (int i = 0; i < 4; ++i) routing[i] = e[i]/s;
  }
}

// ---------------- routing-weighted kv mix ----------------
__global__ void kvr_k(const u16* local, const float* routing, u16* kvr) {
  const int r = blockIdx.y;
  const long e = ((long)blockIdx.x*256 + threadIdx.x) * 8;
  float rm[4]; float s = 0.f;
  #pragma unroll
  for (int w = 0; w < 4; ++w) { rm[w] = (w == r) ? 0.f : routing[w]; s += rm[w]; }
  const float inv = 1.f / (s + 1e-8f);
  ushort8 a0 = *(const ushort8*)&local[e];
  ushort8 a1 = *(const ushort8*)&local[1048576 + e];
  ushort8 a2 = *(const ushort8*)&local[2097152 + e];
  ushort8 a3 = *(const ushort8*)&local[3145728 + e];
  ushort8 out;
  #pragma unroll
  for (int j = 0; j < 8; ++j)
    out[j] = f2b((rm[0]*b2f(a0[j]) + rm[1]*b2f(a1[j]) + rm[2]*b2f(a2[j]) + rm[3]*b2f(a3[j])) * inv);
  *(ushort8*)&kvr[(long)r*1048576 + e] = out;
}

// ---------------- concat [local | cross] ----------------
__global__ void gcat_k(const u16* local, const u16* cross, u16* gcat) {
  const long e = ((long)blockIdx.x*256 + threadIdx.x) * 8;
  const long row = e >> 11, col = e & 2047;
  const u16* src = (col < 1024) ? &local[row*1024 + col] : &cross[row*1024 + col - 1024];
  *(ushort8*)&gcat[e] = *(const ushort8*)src;
}

// ---------------- comb = g*cross + (1-g)*local ----------------
__global__ void comb_k(const u16* g, const u16* cross, const u16* local, u16* comb) {
  const long e = ((long)blockIdx.x*256 + threadIdx.x) * 8;
  ushort8 gg = *(const ushort8*)&g[e];
  ushort8 cc = *(const ushort8*)&cross[e];
  ushort8 ll = *(const ushort8*)&local[e];
  ushort8 out;
  #pragma unroll
  for (int j = 0; j < 8; ++j) {
    const float gf = b2f(gg[j]);
    out[j] = f2b(gf*b2f(cc[j]) + (1.f-gf)*b2f(ll[j]));
  }
  *(ushort8*)&comb[e] = out;
}

// ---------------------------------------------------------------------------
static void gemm1(hipStream_t st, dim3 grid,
                  const u16* A, long lda, const u16* B, long ldb,
                  u16* C, long ldc, const float* bias,
                  int K, int N, float scale, int act, int outf) {
  GemmP p = {};
  p.A=A; p.B=B; p.C=C; p.bias=bias;
  p.lda=lda; p.ldb=ldb; p.ldc=ldc;
  p.K=K; p.Nstore=N; p.ySplit=1<<30; p.act=act; p.outf=outf; p.scale=scale;
  gemm_nt<<<grid, dim3(512), 0, st>>>(p);
}

extern "C" void kernel_launch(void* const* d_in, const int* in_sizes, int n_in,
                              void* d_out, int out_size, void* d_ws, size_t ws_size,
                              hipStream_t stream) {
  (void)in_sizes; (void)n_in; (void)out_size; (void)ws_size;
  const float* x   = (const float*)d_in[0];
  const float* liw = (const float*)d_in[1];
  const float* lib = (const float*)d_in[2];
  const float* low = (const float*)d_in[3];
  const float* lob = (const float*)d_in[4];
  const float* sq  = (const float*)d_in[5];
  const float* siw = (const float*)d_in[6];
  const float* sib = (const float*)d_in[7];
  const float* sow = (const float*)d_in[8];
  const float* sob = (const float*)d_in[9];
  const float* pw1 = (const float*)d_in[10];
  const float* pb1 = (const float*)d_in[11];
  const float* pw2 = (const float*)d_in[12];
  const float* pb2 = (const float*)d_in[13];
  const float* cbw = (const float*)d_in[14];
  const float* cbb = (const float*)d_in[15];
  const float* miw = (const float*)d_in[16];
  const float* mib = (const float*)d_in[17];
  const float* mow = (const float*)d_in[18];
  const float* mob = (const float*)d_in[19];
  const float* rw1 = (const float*)d_in[20];
  const float* rb1 = (const float*)d_in[21];
  const float* rw2 = (const float*)d_in[22];
  const float* rb2 = (const float*)d_in[23];
  const float* ciw = (const float*)d_in[24];
  const float* cib = (const float*)d_in[25];
  const float* cow = (const float*)d_in[26];
  const float* cob = (const float*)d_in[27];
  const float* gw  = (const float*)d_in[28];
  const float* gb  = (const float*)d_in[29];
  const float* pw  = (const float*)d_in[30];
  const float* pb  = (const float*)d_in[31];

  char* ws = (char*)d_ws;
  u16* qkv    = (u16*)(ws + 0);            // 4096x3072 bf16
  u16* aout   = (u16*)(ws + 25165824);     // 4096x1024
  u16* local  = (u16*)(ws + 33554432);     // 4096x1024
  u16* scratch= (u16*)(ws + 41943040);     // first 6MB doubles as liwb
  u16* s2048  = (u16*)(ws + 79691776);     // 4096x2048 (sumKV -> crossKV -> gatecat)
  u16* cq     = (u16*)(ws + 96468992);     // 4096x1024 (cross Q, later g)
  u16* kvr    = (u16*)(ws + 104857600);    // 4096x1024 (mixed kv, later comb)
  u16* crossb = (u16*)(ws + 113246208);    // 4096x1024 (doubles as xb)
  char* sf = ws + 121634816;
  float* qs      = (float*)(sf + 0);
  float* pall    = (float*)(sf + 4096);
  float* wavg    = (float*)(sf + 266240);
  float* content = (float*)(sf + 282624);
  float* contprj = (float*)(sf + 299008);
  float* stats   = (float*)(sf + 315392);
  float* summ    = (float*)(sf + 315456);
  float* routing = (float*)(sf + 316480);
  float* part    = (float*)(sf + 316544);
  u16* siwkvb = (u16*)(ws + 122028032);
  u16* lowb   = (u16*)(ws + 126222336);
  u16* ciwb   = (u16*)(ws + 128319488);
  u16* cowb   = (u16*)(ws + 134610944);
  u16* gwb    = (u16*)(ws + 136708096);
  u16* pwb    = (u16*)(ws + 140902400);
  u16* xb   = crossb;
  u16* liwb = scratch;

  // 0. fp32 -> bf16 conversions
  CvtP cp;
  cp.src[0]=x;   cp.dst[0]=xb;     cp.n[0]=4194304;
  cp.src[1]=liw; cp.dst[1]=liwb;   cp.n[1]=3145728;
  cp.src[2]=low; cp.dst[2]=lowb;   cp.n[2]=1048576;
  cp.src[3]=siw+1048576; cp.dst[3]=siwkvb; cp.n[3]=2097152;
  cp.src[4]=ciw; cp.dst[4]=ciwb;   cp.n[4]=3145728;
  cp.src[5]=cow; cp.dst[5]=cowb;   cp.n[5]=1048576;
  cp.src[6]=gw;  cp.dst[6]=gwb;    cp.n[6]=2097152;
  cp.src[7]=pw;  cp.dst[7]=pwb;    cp.n[7]=1048576;
  cvt_multi<<<dim3(2048, 8), dim3(256), 0, stream>>>(cp);

  // 1. local QKV projection
  gemm1(stream, dim3(32,24), xb,1024, liwb,1024, qkv,3072, lib, 1024, 3072, 1.f, 0, 0);

  // 2. fused local self-attention
  {
    FlashP fp;
    fp.q = qkv; fp.k = qkv + 1024; fp.v = qkv + 2048; fp.o = aout;
    fp.ldq = 3072; fp.ldkv = 3072; fp.ldo = 1024;
    fp.qB = 3145728; fp.kvB = 3145728; fp.oB = 1048576;
    flash_k<<<dim3(16,16,4), dim3(256), 0, stream>>>(fp);
  }

  // 3. local out-projection
  gemm1(stream, dim3(32,8), aout,1024, lowb,1024, local,1024, lob, 1024, 1024, 1.f, 0, 0);

  // 4. combined crossQ (y<8) + summary K/V (y>=8) projections
  {
    GemmP p = {};
    p.A = local; p.lda = 1024; p.K = 1024; p.scale = 1.f;
    p.B = ciwb;   p.C = cq;    p.bias = cib;      p.ldb = 1024; p.ldc = 1024; p.Nstore = 1024;
    p.B2 = siwkvb; p.C2 = s2048; p.bias2 = sib+1024; p.ldb2 = 1024; p.ldc2 = 2048; p.Nstore2 = 2048;
    p.ySplit = 8;
    gemm_nt<<<dim3(32,24), dim3(512), 0, stream>>>(p);
  }

  // 5. summaries
  gemv_qs<<<dim3(16), dim3(256), 0, stream>>>(sq, siw, sib, qs);
  sum_attend<<<dim3(16,4), dim3(256), 0, stream>>>(qs, s2048, content, pall);
  wavg_k<<<dim3(4,4), dim3(256), 0, stream>>>(pall, wavg);
  contproj_k<<<dim3(16,4), dim3(256), 0, stream>>>(content, sow, sob, contprj);
  stats1_k<<<dim3(16,4), dim3(256), 0, stream>>>(wavg, part);
  stats2_k<<<dim3(4), dim3(128), 0, stream>>>(part, stats);
  patsum_k<<<dim3(4), dim3(256), 0, stream>>>(stats, contprj, pw1, pb1, pw2, pb2, cbw, cbb, summ);

  // 6. meta attention + routing
  meta_k<<<dim3(1), dim3(64), 0, stream>>>(summ, miw, mib, mow, mob, rw1, rb1, rw2, rb2, routing);

  // 7. per-rank mixed kv
  kvr_k<<<dim3(512,4), dim3(256), 0, stream>>>(local, routing, kvr);

  // 8. cross K/V projection
  gemm1(stream, dim3(32,16), kvr,1024, ciwb+1048576,1024, s2048,2048, cib+1024, 1024, 2048, 1.f, 0, 0);

  // 9. fused cross attention
  {
    FlashP fp;
    fp.q = cq; fp.k = s2048; fp.v = s2048 + 1024; fp.o = aout;
    fp.ldq = 1024; fp.ldkv = 2048; fp.ldo = 1024;
    fp.qB = 1048576; fp.kvB = 2097152; fp.oB = 1048576;
    flash_k<<<dim3(16,16,4), dim3(256), 0, stream>>>(fp);
  }

  // 10. cross out-projection
  gemm1(stream, dim3(32,8), aout,1024, cowb,1024, crossb,1024, cob, 1024, 1024, 1.f, 0, 0);

  // 11-12. gate
  gcat_k<<<dim3(4096), dim3(256), 0, stream>>>(local, crossb, s2048);
  gemm1(stream, dim3(32,8), s2048,2048, gwb,2048, cq,1024, gb, 2048, 1024, 1.f, 1, 0);

  // 13. comb = g*cross + (1-g)*local
  comb_k<<<dim3(2048), dim3(256), 0, stream>>>(cq, crossb, local, kvr);

  // 14. final projection -> d_out (fp32)
  gemm1(stream, dim3(32,8), kvr,1024, pwb,1024, (u16*)d_out,1024, pb, 1024, 1024, 1.f, 0, 1);
}

// Round 8
// 433.194 us; speedup vs baseline: 2.6421x; 1.0690x over previous
//
#include <hip/hip_runtime.h>
#include <hip/hip_bf16.h>
#include <stdint.h>

typedef uint16_t u16;
typedef __attribute__((ext_vector_type(8))) short short8;
typedef __attribute__((ext_vector_type(4))) short short4v;
typedef __attribute__((ext_vector_type(8))) unsigned short ushort8;
typedef __attribute__((ext_vector_type(4))) float f32x4;

#define AS1 __attribute__((address_space(1)))
#define AS3 __attribute__((address_space(3)))

__device__ __forceinline__ float b2f(u16 u){
  union{uint32_t i; float f;} v; v.i=((uint32_t)u)<<16; return v.f;
}
__device__ __forceinline__ u16 f2b(float f){
  union{uint32_t i; float f;} v; v.f=f;
  return (u16)((v.i + 0x7fffu + ((v.i>>16)&1u))>>16);
}
__device__ __forceinline__ u16 f2bf(float f){   // hw-friendly convert (RTE)
  __hip_bfloat16 h = __float2bfloat16(f);
  return *reinterpret_cast<u16*>(&h);
}

// ---------------- fused fp32 -> bf16 conversions (8 segments, 1 launch) -----
struct CvtP { const float* src[8]; u16* dst[8]; long n[8]; };
__global__ void cvt_multi(CvtP p) {
  const int seg = blockIdx.y;
  const long i = ((long)blockIdx.x*256 + threadIdx.x)*8;
  if (i >= p.n[seg]) return;
  const float* in = p.src[seg];
  float4 a = *(const float4*)&in[i];
  float4 b = *(const float4*)&in[i+4];
  ushort8 o;
  o[0]=f2b(a.x); o[1]=f2b(a.y); o[2]=f2b(a.z); o[3]=f2b(a.w);
  o[4]=f2b(b.x); o[5]=f2b(b.y); o[6]=f2b(b.z); o[7]=f2b(b.w);
  *(ushort8*)&p.dst[seg][i] = o;
}

// ---------------------------------------------------------------------------
// NT GEMM, 128x128 tile, BK=32, 8 waves (512 thr), double-buffered LDS.
// Optional second y-segment (ySplit) with its own B/C/bias/ldb/ldc/Nstore.
// ---------------------------------------------------------------------------
struct GemmP {
  const u16* A; const u16* B; u16* C; const float* bias;
  const u16* B2; u16* C2; const float* bias2;
  long lda, ldb, ldc, ldb2, ldc2;
  int K, Nstore, Nstore2, ySplit, act, outf;   // act: 0 none, 1 sigmoid
  float scale;
};

__global__ __launch_bounds__(512) void gemm_nt(GemmP p) {
  __shared__ __align__(16) u16 lA[2][4096];
  __shared__ __align__(16) u16 lB[2][4096];
  const int t = threadIdx.x;
  const int wave = t >> 6, lane = t & 63;
  int by = blockIdx.y;
  const u16* Bp; u16* Cp; const float* bias; long ldb, ldc; int nst;
  if (by >= p.ySplit) {
    by -= p.ySplit; Bp = p.B2; Cp = p.C2; bias = p.bias2;
    ldb = p.ldb2; ldc = p.ldc2; nst = p.Nstore2;
  } else {
    Bp = p.B; Cp = p.C; bias = p.bias; ldb = p.ldb; ldc = p.ldc; nst = p.Nstore;
  }
  const u16* A = p.A + (long)blockIdx.x * 128 * p.lda;
  const u16* B = Bp + (long)by * 128 * ldb;
  const int srow = t >> 2, skk = (t & 3) * 8;
  const int wr = wave >> 2, wc = wave & 3;
  const int fr = lane & 15, fk = (lane >> 4) * 8;
  f32x4 acc[4][2] = {};

  __builtin_amdgcn_global_load_lds((const AS1 void*)(A + (long)srow*p.lda + skk),
                                   (AS3 void*)&lA[0][t*8], 16, 0, 0);
  __builtin_amdgcn_global_load_lds((const AS1 void*)(B + (long)srow*ldb + skk),
                                   (AS3 void*)&lB[0][t*8], 16, 0, 0);
  __syncthreads();
  int cur = 0;
  for (int k0 = 0; k0 < p.K; k0 += 32) {
    if (k0 + 32 < p.K) {
      const int nb = cur ^ 1, kn = k0 + 32;
      __builtin_amdgcn_global_load_lds((const AS1 void*)(A + (long)srow*p.lda + kn + skk),
                                       (AS3 void*)&lA[nb][t*8], 16, 0, 0);
      __builtin_amdgcn_global_load_lds((const AS1 void*)(B + (long)srow*ldb + kn + skk),
                                       (AS3 void*)&lB[nb][t*8], 16, 0, 0);
    }
    short8 av[4], bv[2];
    #pragma unroll
    for (int mi = 0; mi < 4; ++mi) av[mi] = *(const short8*)&lA[cur][(wr*64 + mi*16 + fr)*32 + fk];
    #pragma unroll
    for (int ni = 0; ni < 2; ++ni) bv[ni] = *(const short8*)&lB[cur][(wc*32 + ni*16 + fr)*32 + fk];
    #pragma unroll
    for (int mi = 0; mi < 4; ++mi)
      #pragma unroll
      for (int ni = 0; ni < 2; ++ni)
        acc[mi][ni] = __builtin_amdgcn_mfma_f32_16x16x32_bf16(av[mi], bv[ni], acc[mi][ni], 0, 0, 0);
    __syncthreads();
    cur ^= 1;
  }

  const int rbase = blockIdx.x*128 + wr*64;
  const int cbase = by*128 + wc*32;
  const int rsub = (lane >> 4) * 4;
  #pragma unroll
  for (int ni = 0; ni < 2; ++ni) {
    const int col = cbase + ni*16 + fr;
    if (col >= nst) continue;
    const float bs = bias ? bias[col] : 0.f;
    #pragma unroll
    for (int mi = 0; mi < 4; ++mi) {
      #pragma unroll
      for (int j = 0; j < 4; ++j) {
        float v = acc[mi][ni][j] * p.scale + bs;
        if (p.act == 1) v = 1.f / (1.f + __expf(-v));
        const long idx = (long)(rbase + mi*16 + rsub + j) * ldc + col;
        if (p.outf) ((float*)Cp)[idx] = v;
        else        Cp[idx] = f2b(v);
      }
    }
  }
}

// ---------------------------------------------------------------------------
// Fused flash attention, swapped-QK^T softmax (lane-local rows).
// Grid (qtile=16, head=16, window=4); 256 thr / 4 waves; wave = 16 q-rows.
// S^T = mfma(K,Q): lane (g,fr) holds scores[key=ni*16+g*4+j][qrow=fr] ->
// row max/sum are in-lane + 2 shfl_xor. exp folded: p = exp2(raw*C - ml).
// Defer-max (THR=11.5 log2 units) skips acc rescale on most tiles.
// ---------------------------------------------------------------------------
struct FlashP {
  const u16 *q, *k, *v; u16* o;
  long ldq, ldkv, ldo;
  long qB, kvB, oB;
};

__global__ __launch_bounds__(256) void flash_k(FlashP p) {
  const int t = threadIdx.x, w4 = t >> 6, lane = t & 63;
  const int qt = blockIdx.x, h = blockIdx.y, wz = blockIdx.z;
  const int fr = lane & 15, g = lane >> 4, fk = g * 8;
  __shared__ __align__(16) u16 kt[64][72];
  __shared__ __align__(16) u16 vt[64][72];
  __shared__ __align__(16) u16 pl[4][16][72];

  const u16* Q = p.q + (long)wz*p.qB + (long)(qt*64 + w4*16)*p.ldq + h*64;
  const u16* K = p.k + (long)wz*p.kvB + h*64;
  const u16* V = p.v + (long)wz*p.kvB + h*64;

  short8 aq[2];
  aq[0] = *(const short8*)&Q[(long)fr*p.ldq + fk];
  aq[1] = *(const short8*)&Q[(long)fr*p.ldq + 32 + fk];

  f32x4 acc[4] = {};
  float ml = -3e38f, ll = 0.f;              // per-lane state for q-row `fr`
  const float C = 0.125f * 1.44269504f;     // score-scale * log2(e)

  // staging roles: K coalesced rows; V key-pairs for packed transpose writes
  const int krow = t >> 2, kseg = (t & 3) * 16;
  const int vp = t & 31, vc = (t >> 5) * 8;

  short8 kr0, kr1, vr0, vr1;
  kr0 = *(const short8*)&K[(long)krow*p.ldkv + kseg];
  kr1 = *(const short8*)&K[(long)krow*p.ldkv + kseg + 8];
  vr0 = *(const short8*)&V[(long)(2*vp)*p.ldkv + vc];
  vr1 = *(const short8*)&V[(long)(2*vp + 1)*p.ldkv + vc];

  for (int it = 0; it < 16; ++it) {
    // ---- write staged regs to LDS ----
    *(short8*)&kt[krow][kseg]     = kr0;
    *(short8*)&kt[krow][kseg + 8] = kr1;
    #pragma unroll
    for (int e = 0; e < 8; ++e) {
      const uint32_t pk = (uint32_t)(uint16_t)vr0[e] | ((uint32_t)(uint16_t)vr1[e] << 16);
      *(uint32_t*)&vt[vc + e][2*vp] = pk;
    }
    __syncthreads();

    // ---- prefetch next tile into regs ----
    if (it + 1 < 16) {
      const int kn = (it + 1) * 64;
      kr0 = *(const short8*)&K[(long)(kn + krow)*p.ldkv + kseg];
      kr1 = *(const short8*)&K[(long)(kn + krow)*p.ldkv + kseg + 8];
      vr0 = *(const short8*)&V[(long)(kn + 2*vp)*p.ldkv + vc];
      vr1 = *(const short8*)&V[(long)(kn + 2*vp + 1)*p.ldkv + vc];
    }

    // ---- S^T = K Q^T: lane (g,fr) gets scores[key=ni*16+g*4+j][qrow=fr] ----
    f32x4 s[4] = {};
    __builtin_amdgcn_s_setprio(1);
    #pragma unroll
    for (int ni = 0; ni < 4; ++ni) {
      short8 bk0 = *(const short8*)&kt[ni*16 + fr][fk];
      short8 bk1 = *(const short8*)&kt[ni*16 + fr][32 + fk];
      s[ni] = __builtin_amdgcn_mfma_f32_16x16x32_bf16(bk0, aq[0], s[ni], 0, 0, 0);
      s[ni] = __builtin_amdgcn_mfma_f32_16x16x32_bf16(bk1, aq[1], s[ni], 0, 0, 0);
    }
    __builtin_amdgcn_s_setprio(0);

    // ---- online softmax, lane-local row ----
    float rm = s[0][0];
    #pragma unroll
    for (int ni = 0; ni < 4; ++ni)
      #pragma unroll
      for (int j = 0; j < 4; ++j) rm = fmaxf(rm, s[ni][j]);
    rm = fmaxf(rm, __shfl_xor(rm, 16, 64));
    rm = fmaxf(rm, __shfl_xor(rm, 32, 64));
    const float rml = rm * C;

    if (__any(rml > ml + 11.5f)) {          // defer-max: rescale only when needed
      const float mnl = fmaxf(ml, rml);
      const float al = exp2f(ml - mnl);
      const float a0 = __shfl(al, g*4 + 0, 64);
      const float a1 = __shfl(al, g*4 + 1, 64);
      const float a2 = __shfl(al, g*4 + 2, 64);
      const float a3 = __shfl(al, g*4 + 3, 64);
      #pragma unroll
      for (int nv = 0; nv < 4; ++nv) {
        acc[nv][0] *= a0; acc[nv][1] *= a1; acc[nv][2] *= a2; acc[nv][3] *= a3;
      }
      ll *= al;
      ml = mnl;
    }

    float rs = 0.f;
    u16 pb[4][4];
    #pragma unroll
    for (int ni = 0; ni < 4; ++ni)
      #pragma unroll
      for (int j = 0; j < 4; ++j) {
        const float pv = exp2f(s[ni][j]*C - ml);
        rs += pv;
        pb[ni][j] = f2bf(pv);
      }
    rs += __shfl_xor(rs, 16, 64);
    rs += __shfl_xor(rs, 32, 64);
    ll += rs;

    // ---- P -> LDS: lane owns 4 consecutive keys per ni -> packed b64 ----
    #pragma unroll
    for (int ni = 0; ni < 4; ++ni) {
      short4v pk4;
      pk4[0] = (short)pb[ni][0]; pk4[1] = (short)pb[ni][1];
      pk4[2] = (short)pb[ni][2]; pk4[3] = (short)pb[ni][3];
      *(short4v*)&pl[w4][fr][ni*16 + g*4] = pk4;
    }

    // ---- PV accumulate: A = P[qrow][key], B = V^T[d][key] ----
    __builtin_amdgcn_s_setprio(1);
    #pragma unroll
    for (int ks = 0; ks < 2; ++ks) {
      short8 pa = *(const short8*)&pl[w4][fr][ks*32 + fk];
      #pragma unroll
      for (int nv = 0; nv < 4; ++nv) {
        short8 bvv = *(const short8*)&vt[nv*16 + fr][ks*32 + fk];
        acc[nv] = __builtin_amdgcn_mfma_f32_16x16x32_bf16(pa, bvv, acc[nv], 0, 0, 0);
      }
    }
    __builtin_amdgcn_s_setprio(0);
    __syncthreads();   // protect kt/vt before next tile's LDS writes
  }

  // ---- epilogue: fetch l for acc rows (owners are lanes fr = row) ----
  const float l0 = __shfl(ll, g*4 + 0, 64);
  const float l1 = __shfl(ll, g*4 + 1, 64);
  const float l2 = __shfl(ll, g*4 + 2, 64);
  const float l3 = __shfl(ll, g*4 + 3, 64);
  const float inv[4] = {1.f/l0, 1.f/l1, 1.f/l2, 1.f/l3};
  u16* O = p.o + (long)wz*p.oB + (long)(qt*64 + w4*16)*p.ldo + h*64;
  #pragma unroll
  for (int j = 0; j < 4; ++j)
    #pragma unroll
    for (int nv = 0; nv < 4; ++nv)
      O[(long)(g*4 + j)*p.ldo + nv*16 + fr] = f2bf(acc[nv][j] * inv[j]);
}

// -------- qs = sum_query @ wq^T + bq  (grid 16, 256 thr, k-split) --------
__global__ void gemv_qs(const float* sq, const float* w, const float* b, float* out) {
  const int t = threadIdx.x, nl = t & 63, kq = t >> 6;
  const int n = blockIdx.x*64 + nl;
  const float* row = w + (long)n * 1024 + kq*256;
  const float* q = sq + kq*256;
  float s = 0.f;
  for (int k = 0; k < 256; k += 4) {
    float4 ww = *(const float4*)&row[k];
    float4 qq = *(const float4*)&q[k];
    s += qq.x*ww.x + qq.y*ww.y + qq.z*ww.z + qq.w*ww.w;
  }
  __shared__ float ps[4][64];
  ps[kq][nl] = s;
  __syncthreads();
  if (t < 64) out[blockIdx.x*64 + t] = ps[0][t]+ps[1][t]+ps[2][t]+ps[3][t] + b[blockIdx.x*64 + t];
}

// ------- summary attention: block (h,w), 256 threads, k-parallel -------
__global__ void sum_attend(const float* qs, const u16* sumkv, float* content, float* pall) {
  const int h = blockIdx.x, w = blockIdx.y, t = threadIdx.x;
  const int lane = t & 63, wv = t >> 6;
  __shared__ float qsh[64];
  __shared__ float sc[1024];
  __shared__ float rmax[4], rsum[4];
  __shared__ float po[4][64];
  if (t < 64) qsh[t] = qs[h*64 + t];
  __syncthreads();
  const u16* kbase = sumkv + (long)w*2097152 + h*64;
  float e[4];
  float mx = -1e30f;
  #pragma unroll
  for (int j = 0; j < 4; ++j) {
    const int k = j*256 + t;
    const u16* krow = kbase + (long)k * 2048;
    float s = 0.f;
    #pragma unroll
    for (int d = 0; d < 64; d += 8) {
      ushort8 kk = *(const ushort8*)&krow[d];
      #pragma unroll
      for (int q = 0; q < 8; ++q) s += qsh[d+q] * b2f(kk[q]);
    }
    s *= 0.125f;
    e[j] = s;
    mx = fmaxf(mx, s);
  }
  #pragma unroll
  for (int o = 32; o; o >>= 1) mx = fmaxf(mx, __shfl_xor(mx, o, 64));
  if (lane == 0) rmax[wv] = mx;
  __syncthreads();
  mx = fmaxf(fmaxf(rmax[0],rmax[1]), fmaxf(rmax[2],rmax[3]));
  float sum = 0.f;
  #pragma unroll
  for (int j = 0; j < 4; ++j) { e[j] = __expf(e[j]-mx); sum += e[j]; }
  #pragma unroll
  for (int o = 32; o; o >>= 1) sum += __shfl_xor(sum, o, 64);
  if (lane == 0) rsum[wv] = sum;
  __syncthreads();
  const float inv = 1.f / (rsum[0]+rsum[1]+rsum[2]+rsum[3]);
  float* pr = pall + ((long)w*16 + h)*1024;
  #pragma unroll
  for (int j = 0; j < 4; ++j) {
    const int k = j*256 + t;
    const float pn = e[j]*inv;
    sc[k] = pn;
    pr[k] = pn;
  }
  __syncthreads();
  const u16* vbase = sumkv + (long)w*2097152 + 1024 + h*64;
  float o = 0.f;
  const int k0 = wv*256;
  for (int k = k0; k < k0+256; ++k) o += sc[k] * b2f(vbase[(long)k*2048 + lane]);
  po[wv][lane] = o;
  __syncthreads();
  if (t < 64) content[(long)w*1024 + h*64 + t] = po[0][t]+po[1][t]+po[2][t]+po[3][t];
}

__global__ void wavg_k(const float* pall, float* wavg) {
  const int w = blockIdx.y, k = blockIdx.x*256 + threadIdx.x;
  float s = 0.f;
  #pragma unroll
  for (int h = 0; h < 16; ++h) s += pall[((long)w*16 + h)*1024 + k];
  wavg[w*1024 + k] = s * (1.f/16.f);
}

// ------- content projection (grid (16,4), 256 thr, k-split) -------
__global__ void contproj_k(const float* content, const float* w_, const float* b, float* out) {
  const int w = blockIdx.y, t = threadIdx.x;
  const int nl = t & 63, kq = t >> 6;
  const int n = blockIdx.x*64 + nl;
  const float* c = content + w*1024 + kq*256;
  const float* row = w_ + (long)n * 1024 + kq*256;
  float s = 0.f;
  for (int k = 0; k < 256; k += 4) {
    float4 ww = *(const float4*)&row[k];
    s += c[k]*ww.x + c[k+1]*ww.y + c[k+2]*ww.z + c[k+3]*ww.w;
  }
  __shared__ float ps[4][64];
  ps[kq][nl] = s;
  __syncthreads();
  if (t < 64) out[w*1024 + blockIdx.x*64 + t] = ps[0][t]+ps[1][t]+ps[2][t]+ps[3][t] + b[blockIdx.x*64 + t];
}

// ------- attn_stats phase A: parallel rank-count (grid (16,4), 256 thr) -----
__global__ void stats1_k(const float* wavg, float* part) {
  const int c = blockIdx.x, w = blockIdx.y, t = threadIdx.x;
  __shared__ float a[1024];
  for (int i = t; i < 1024; i += 256) a[i] = wavg[w*1024 + i];
  __syncthreads();
  const int jl = t & 63, iq = t >> 6;
  const int j = c*64 + jl;
  const float aj = a[j];
  int pr = 0;
  const int i0 = iq*256;
  #pragma unroll 8
  for (int i = i0; i < i0+256; ++i) {
    const float ai = a[i];
    pr += (ai < aj) || (ai == aj && i < j);
  }
  __shared__ int prs[4][64];
  prs[iq][jl] = pr;
  __syncthreads();
  if (t < 64) {
    const int rank = 1 + prs[0][jl] + prs[1][jl] + prs[2][jl] + prs[3][jl];
    float ent = -aj * logf(aj + 1e-8f);
    float gnum = (float)rank * aj;
    float ssum = aj;
    float mx = aj;
    float top5 = (rank >= 1020) ? aj : 0.f;
    #pragma unroll
    for (int o = 32; o; o >>= 1) {
      ent += __shfl_xor(ent, o, 64);
      gnum += __shfl_xor(gnum, o, 64);
      ssum += __shfl_xor(ssum, o, 64);
      mx = fmaxf(mx, __shfl_xor(mx, o, 64));
      top5 += __shfl_xor(top5, o, 64);
    }
    if (t == 0) {
      float* pp = part + ((w*16 + c) * 5);
      pp[0]=ent; pp[1]=gnum; pp[2]=ssum; pp[3]=mx; pp[4]=top5;
    }
  }
}

// ------- attn_stats phase B: reduce 16 chunk-partials (grid 4, 128 thr) -----
__global__ void stats2_k(const float* part, float* stats) {
  const int w = blockIdx.x, t = threadIdx.x;
  const int c = t & 15, stat = t >> 4;
  float v = 0.f;
  const bool active = stat < 5;
  if (active) v = part[(w*16 + c)*5 + stat];
  #pragma unroll
  for (int o = 8; o; o >>= 1) {
    const float ov = __shfl_xor(v, o, 64);
    v = (stat == 3) ? fmaxf(v, ov) : (v + ov);
  }
  __shared__ float r5[5];
  if (active && c == 0) r5[stat] = v;
  __syncthreads();
  if (t == 0) {
    stats[w*4+0] = r5[0];
    stats[w*4+1] = 2.f*r5[1]/(1024.f*r5[2] + 1e-8f) - 1025.f/1024.f;
    stats[w*4+2] = r5[3];
    stats[w*4+3] = r5[4];
  }
}

// ------- pat MLP + summary combine (grid 4, 256 thr, k-split) -------
__global__ void patsum_k(const float* stats, const float* contprj,
                         const float* pw1, const float* pb1, const float* pw2, const float* pb2,
                         const float* combw, const float* combb, float* summ) {
  const int w = blockIdx.x, t = threadIdx.x;
  const int nl = t & 63, kq = t >> 6;
  __shared__ float p1[64], pat[64];
  __shared__ float ps[4][64];
  __shared__ float ps2[4][64];
  if (t < 64) {
    float s = 0.f;
    #pragma unroll
    for (int k = 0; k < 4; ++k) s += stats[w*4+k] * pw1[t*4+k];
    p1[t] = fmaxf(s + pb1[t], 0.f);
  }
  __syncthreads();
  {
    float s = 0.f;
    const float* rw = pw2 + (long)nl*64 + kq*16;
    const float* pp = p1 + kq*16;
    #pragma unroll
    for (int k = 0; k < 16; ++k) s += pp[k] * rw[k];
    ps[kq][nl] = s;
  }
  __syncthreads();
  if (t < 64) pat[t] = ps[0][t]+ps[1][t]+ps[2][t]+ps[3][t] + pb2[t];
  __syncthreads();
  const float* c = contprj + w*1024;
  const float* row = combw + (long)nl * 1088;
  float s = 0.f;
  const int k0 = kq*272;
  for (int k = k0; k < k0+272; ++k) {
    const float rv = row[k];
    const float cv = (k < 1024) ? c[k] : pat[k-1024];
    s += cv * rv;
  }
  ps2[kq][nl] = s;
  __syncthreads();
  if (t < 64) summ[w*64 + t] = ps2[0][t]+ps2[1][t]+ps2[2][t]+ps2[3][t] + combb[t];
}

// ---------------- meta attention + routing (1 block, 64 threads) ------------
__global__ void meta_k(const float* summ, const float* miw, const float* mib,
                       const float* mow, const float* mob, const float* rw1, const float* rb1,
                       const float* rw2, const float* rb2, float* routing) {
  const int t = threadIdx.x;
  __shared__ float qkv[4][192];
  __shared__ float sc[64];
  __shared__ float o[4][64];
  __shared__ float rf[4][64];
  __shared__ float t1[4][64];
  __shared__ float lg[4];
  for (int idx = t; idx < 768; idx += 64) {
    const int w = idx / 192, rrow = idx % 192;
    const float* rw = miw + (long)rrow * 64;
    float s = 0.f;
    for (int k = 0; k < 64; ++k) s += summ[w*64+k] * rw[k];
    qkv[w][rrow] = s + mib[rrow];
  }
  __syncthreads();
  {
    const int h = t >> 4, i = (t >> 2) & 3, j = t & 3;
    float s = 0.f;
    #pragma unroll
    for (int d = 0; d < 16; ++d) s += qkv[i][h*16+d] * qkv[j][64 + h*16+d];
    sc[t] = s * 0.25f;
  }
  __syncthreads();
  if (t < 16) {
    const float a0=sc[t*4], a1=sc[t*4+1], a2=sc[t*4+2], a3=sc[t*4+3];
    const float m = fmaxf(fmaxf(a0,a1), fmaxf(a2,a3));
    const float e0=__expf(a0-m), e1=__expf(a1-m), e2=__expf(a2-m), e3=__expf(a3-m);
    const float s = e0+e1+e2+e3;
    sc[t*4]=e0/s; sc[t*4+1]=e1/s; sc[t*4+2]=e2/s; sc[t*4+3]=e3/s;
  }
  __syncthreads();
  for (int idx = t; idx < 256; idx += 64) {
    const int i = idx >> 6, c = idx & 63, h = c >> 4;
    float s = 0.f;
    #pragma unroll
    for (int j = 0; j < 4; ++j) s += sc[(h*4+i)*4+j] * qkv[j][128 + c];
    o[i][c] = s;
  }
  __syncthreads();
  for (int idx = t; idx < 256; idx += 64) {
    const int i = idx >> 6, n = idx & 63;
    const float* rw = mow + (long)n * 64;
    float s = 0.f;
    for (int k = 0; k < 64; ++k) s += o[i][k] * rw[k];
    rf[i][n] = s + mob[n];
  }
  __syncthreads();
  for (int idx = t; idx < 256; idx += 64) {
    const int i = idx >> 6, n = idx & 63;
    const float* rw = rw1 + (long)n * 64;
    float s = 0.f;
    for (int k = 0; k < 64; ++k) s += rf[i][k] * rw[k];
    t1[i][n] = fmaxf(s + rb1[n], 0.f);
  }
  __syncthreads();
  if (t < 4) {
    float s = 0.f;
    for (int k = 0; k < 64; ++k) s += t1[t][k] * rw2[k];
    lg[t] = s + rb2[0];
  }
  __syncthreads();
  if (t == 0) {
    const float m = fmaxf(fmaxf(lg[0],lg[1]), fmaxf(lg[2],lg[3]));
    float e[4], s = 0.f;
    #pragma unroll
    for (int i = 0; i < 4; ++i) { e[i] = __expf(lg[i]-m); s += e[i]; }
    #pragma unroll
    for (int i = 0; i < 4; ++i) routing[i] = e[i]/s;
  }
}

// ---------------- routing-weighted kv mix ----------------
__global__ void kvr_k(const u16* local, const float* routing, u16* kvr) {
  const int r = blockIdx.y;
  const long e = ((long)blockIdx.x*256 + threadIdx.x) * 8;
  float rm[4]; float s = 0.f;
  #pragma unroll
  for (int w = 0; w < 4; ++w) { rm[w] = (w == r) ? 0.f : routing[w]; s += rm[w]; }
  const float inv = 1.f / (s + 1e-8f);
  ushort8 a0 = *(const ushort8*)&local[e];
  ushort8 a1 = *(const ushort8*)&local[1048576 + e];
  ushort8 a2 = *(const ushort8*)&local[2097152 + e];
  ushort8 a3 = *(const ushort8*)&local[3145728 + e];
  ushort8 out;
  #pragma unroll
  for (int j = 0; j < 8; ++j)
    out[j] = f2b((rm[0]*b2f(a0[j]) + rm[1]*b2f(a1[j]) + rm[2]*b2f(a2[j]) + rm[3]*b2f(a3[j])) * inv);
  *(ushort8*)&kvr[(long)r*1048576 + e] = out;
}

// ---------------- concat [local | cross] ----------------
__global__ void gcat_k(const u16* local, const u16* cross, u16* gcat) {
  const long e = ((long)blockIdx.x*256 + threadIdx.x) * 8;
  const long row = e >> 11, col = e & 2047;
  const u16* src = (col < 1024) ? &local[row*1024 + col] : &cross[row*1024 + col - 1024];
  *(ushort8*)&gcat[e] = *(const ushort8*)src;
}

// ---------------- comb = g*cross + (1-g)*local ----------------
__global__ void comb_k(const u16* g, const u16* cross, const u16* local, u16* comb) {
  const long e = ((long)blockIdx.x*256 + threadIdx.x) * 8;
  ushort8 gg = *(const ushort8*)&g[e];
  ushort8 cc = *(const ushort8*)&cross[e];
  ushort8 ll = *(const ushort8*)&local[e];
  ushort8 out;
  #pragma unroll
  for (int j = 0; j < 8; ++j) {
    const float gf = b2f(gg[j]);
    out[j] = f2b(gf*b2f(cc[j]) + (1.f-gf)*b2f(ll[j]));
  }
  *(ushort8*)&comb[e] = out;
}

// ---------------------------------------------------------------------------
static void gemm1(hipStream_t st, dim3 grid,
                  const u16* A, long lda, const u16* B, long ldb,
                  u16* C, long ldc, const float* bias,
                  int K, int N, float scale, int act, int outf) {
  GemmP p = {};
  p.A=A; p.B=B; p.C=C; p.bias=bias;
  p.lda=lda; p.ldb=ldb; p.ldc=ldc;
  p.K=K; p.Nstore=N; p.ySplit=1<<30; p.act=act; p.outf=outf; p.scale=scale;
  gemm_nt<<<grid, dim3(512), 0, st>>>(p);
}

extern "C" void kernel_launch(void* const* d_in, const int* in_sizes, int n_in,
                              void* d_out, int out_size, void* d_ws, size_t ws_size,
                              hipStream_t stream) {
  (void)in_sizes; (void)n_in; (void)out_size; (void)ws_size;
  const float* x   = (const float*)d_in[0];
  const float* liw = (const float*)d_in[1];
  const float* lib = (const float*)d_in[2];
  const float* low = (const float*)d_in[3];
  const float* lob = (const float*)d_in[4];
  const float* sq  = (const float*)d_in[5];
  const float* siw = (const float*)d_in[6];
  const float* sib = (const float*)d_in[7];
  const float* sow = (const float*)d_in[8];
  const float* sob = (const float*)d_in[9];
  const float* pw1 = (const float*)d_in[10];
  const float* pb1 = (const float*)d_in[11];
  const float* pw2 = (const float*)d_in[12];
  const float* pb2 = (const float*)d_in[13];
  const float* cbw = (const float*)d_in[14];
  const float* cbb = (const float*)d_in[15];
  const float* miw = (const float*)d_in[16];
  const float* mib = (const float*)d_in[17];
  const float* mow = (const float*)d_in[18];
  const float* mob = (const float*)d_in[19];
  const float* rw1 = (const float*)d_in[20];
  const float* rb1 = (const float*)d_in[21];
  const float* rw2 = (const float*)d_in[22];
  const float* rb2 = (const float*)d_in[23];
  const float* ciw = (const float*)d_in[24];
  const float* cib = (const float*)d_in[25];
  const float* cow = (const float*)d_in[26];
  const float* cob = (const float*)d_in[27];
  const float* gw  = (const float*)d_in[28];
  const float* gb  = (const float*)d_in[29];
  const float* pw  = (const float*)d_in[30];
  const float* pb  = (const float*)d_in[31];

  char* ws = (char*)d_ws;
  u16* qkv    = (u16*)(ws + 0);
  u16* aout   = (u16*)(ws + 25165824);
  u16* local  = (u16*)(ws + 33554432);
  u16* scratch= (u16*)(ws + 41943040);
  u16* s2048  = (u16*)(ws + 79691776);
  u16* cq     = (u16*)(ws + 96468992);
  u16* kvr    = (u16*)(ws + 104857600);
  u16* crossb = (u16*)(ws + 113246208);
  char* sf = ws + 121634816;
  float* qs      = (float*)(sf + 0);
  float* pall    = (float*)(sf + 4096);
  float* wavg    = (float*)(sf + 266240);
  float* content = (float*)(sf + 282624);
  float* contprj = (float*)(sf + 299008);
  float* stats   = (float*)(sf + 315392);
  float* summ    = (float*)(sf + 315456);
  float* routing = (float*)(sf + 316480);
  float* part    = (float*)(sf + 316544);
  u16* siwkvb = (u16*)(ws + 122028032);
  u16* lowb   = (u16*)(ws + 126222336);
  u16* ciwb   = (u16*)(ws + 128319488);
  u16* cowb   = (u16*)(ws + 134610944);
  u16* gwb    = (u16*)(ws + 136708096);
  u16* pwb    = (u16*)(ws + 140902400);
  u16* xb   = crossb;
  u16* liwb = scratch;

  // 0. fp32 -> bf16 conversions
  CvtP cp;
  cp.src[0]=x;   cp.dst[0]=xb;     cp.n[0]=4194304;
  cp.src[1]=liw; cp.dst[1]=liwb;   cp.n[1]=3145728;
  cp.src[2]=low; cp.dst[2]=lowb;   cp.n[2]=1048576;
  cp.src[3]=siw+1048576; cp.dst[3]=siwkvb; cp.n[3]=2097152;
  cp.src[4]=ciw; cp.dst[4]=ciwb;   cp.n[4]=3145728;
  cp.src[5]=cow; cp.dst[5]=cowb;   cp.n[5]=1048576;
  cp.src[6]=gw;  cp.dst[6]=gwb;    cp.n[6]=2097152;
  cp.src[7]=pw;  cp.dst[7]=pwb;    cp.n[7]=1048576;
  cvt_multi<<<dim3(2048, 8), dim3(256), 0, stream>>>(cp);

  // 1. local QKV projection
  gemm1(stream, dim3(32,24), xb,1024, liwb,1024, qkv,3072, lib, 1024, 3072, 1.f, 0, 0);

  // 2. fused local self-attention
  {
    FlashP fp;
    fp.q = qkv; fp.k = qkv + 1024; fp.v = qkv + 2048; fp.o = aout;
    fp.ldq = 3072; fp.ldkv = 3072; fp.ldo = 1024;
    fp.qB = 3145728; fp.kvB = 3145728; fp.oB = 1048576;
    flash_k<<<dim3(16,16,4), dim3(256), 0, stream>>>(fp);
  }

  // 3. local out-projection
  gemm1(stream, dim3(32,8), aout,1024, lowb,1024, local,1024, lob, 1024, 1024, 1.f, 0, 0);

  // 4. combined crossQ (y<8) + summary K/V (y>=8) projections
  {
    GemmP p = {};
    p.A = local; p.lda = 1024; p.K = 1024; p.scale = 1.f;
    p.B = ciwb;   p.C = cq;    p.bias = cib;      p.ldb = 1024; p.ldc = 1024; p.Nstore = 1024;
    p.B2 = siwkvb; p.C2 = s2048; p.bias2 = sib+1024; p.ldb2 = 1024; p.ldc2 = 2048; p.Nstore2 = 2048;
    p.ySplit = 8;
    gemm_nt<<<dim3(32,24), dim3(512), 0, stream>>>(p);
  }

  // 5. summaries
  gemv_qs<<<dim3(16), dim3(256), 0, stream>>>(sq, siw, sib, qs);
  sum_attend<<<dim3(16,4), dim3(256), 0, stream>>>(qs, s2048, content, pall);
  wavg_k<<<dim3(4,4), dim3(256), 0, stream>>>(pall, wavg);
  contproj_k<<<dim3(16,4), dim3(256), 0, stream>>>(content, sow, sob, contprj);
  stats1_k<<<dim3(16,4), dim3(256), 0, stream>>>(wavg, part);
  stats2_k<<<dim3(4), dim3(128), 0, stream>>>(part, stats);
  patsum_k<<<dim3(4), dim3(256), 0, stream>>>(stats, contprj, pw1, pb1, pw2, pb2, cbw, cbb, summ);

  // 6. meta attention + routing
  meta_k<<<dim3(1), dim3(64), 0, stream>>>(summ, miw, mib, mow, mob, rw1, rb1, rw2, rb2, routing);

  // 7. per-rank mixed kv
  kvr_k<<<dim3(512,4), dim3(256), 0, stream>>>(local, routing, kvr);

  // 8. cross K/V projection
  gemm1(stream, dim3(32,16), kvr,1024, ciwb+1048576,1024, s2048,2048, cib+1024, 1024, 2048, 1.f, 0, 0);

  // 9. fused cross attention
  {
    FlashP fp;
    fp.q = cq; fp.k = s2048; fp.v = s2048 + 1024; fp.o = aout;
    fp.ldq = 1024; fp.ldkv = 2048; fp.ldo = 1024;
    fp.qB = 1048576; fp.kvB = 2097152; fp.oB = 1048576;
    flash_k<<<dim3(16,16,4), dim3(256), 0, stream>>>(fp);
  }

  // 10. cross out-projection
  gemm1(stream, dim3(32,8), aout,1024, cowb,1024, crossb,1024, cob, 1024, 1024, 1.f, 0, 0);

  // 11-12. gate
  gcat_k<<<dim3(4096), dim3(256), 0, stream>>>(local, crossb, s2048);
  gemm1(stream, dim3(32,8), s2048,2048, gwb,2048, cq,1024, gb, 2048, 1024, 1.f, 1, 0);

  // 13. comb = g*cross + (1-g)*local
  comb_k<<<dim3(2048), dim3(256), 0, stream>>>(cq, crossb, local, kvr);

  // 14. final projection -> d_out (fp32)
  gemm1(stream, dim3(32,8), kvr,1024, pwb,1024, (u16*)d_out,1024, pb, 1024, 1024, 1.f, 0, 1);
}

// Round 9
// 428.184 us; speedup vs baseline: 2.6730x; 1.0117x over previous
//
#include <hip/hip_runtime.h>
#include <hip/hip_bf16.h>
#include <stdint.h>

typedef uint16_t u16;
typedef __attribute__((ext_vector_type(8))) short short8;
typedef __attribute__((ext_vector_type(4))) short short4v;
typedef __attribute__((ext_vector_type(8))) unsigned short ushort8;
typedef __attribute__((ext_vector_type(4))) float f32x4;

#define AS1 __attribute__((address_space(1)))
#define AS3 __attribute__((address_space(3)))

__device__ __forceinline__ float b2f(u16 u){
  union{uint32_t i; float f;} v; v.i=((uint32_t)u)<<16; return v.f;
}
__device__ __forceinline__ u16 f2b(float f){
  union{uint32_t i; float f;} v; v.f=f;
  return (u16)((v.i + 0x7fffu + ((v.i>>16)&1u))>>16);
}
__device__ __forceinline__ u16 f2bf(float f){   // hw-friendly convert (RTE)
  __hip_bfloat16 h = __float2bfloat16(f);
  return *reinterpret_cast<u16*>(&h);
}

// ---------------- fused fp32 -> bf16 conversions (8 segments, 1 launch) -----
struct CvtP { const float* src[8]; u16* dst[8]; long n[8]; };
__global__ void cvt_multi(CvtP p) {
  const int seg = blockIdx.y;
  const long i = ((long)blockIdx.x*256 + threadIdx.x)*8;
  if (i >= p.n[seg]) return;
  const float* in = p.src[seg];
  float4 a = *(const float4*)&in[i];
  float4 b = *(const float4*)&in[i+4];
  ushort8 o;
  o[0]=f2b(a.x); o[1]=f2b(a.y); o[2]=f2b(a.z); o[3]=f2b(a.w);
  o[4]=f2b(b.x); o[5]=f2b(b.y); o[6]=f2b(b.z); o[7]=f2b(b.w);
  *(ushort8*)&p.dst[seg][i] = o;
}

// ---------------------------------------------------------------------------
// NT GEMM, 128x128 tile, BK=32, 8 waves (512 thr), double-buffered LDS.
// Optional second y-segment (ySplit); optional dual-K (A2: accumulate a
// second A@B' over the next K columns of B); act 2 = fused sigmoid-gate comb.
// ---------------------------------------------------------------------------
struct GemmP {
  const u16* A; const u16* B; u16* C; const float* bias;
  const u16* B2; u16* C2; const float* bias2;
  const u16* A2; const u16* lr; const u16* cr;   // dual-K + comb inputs
  long lda, ldb, ldc, ldb2, ldc2;
  int K, Nstore, Nstore2, ySplit, act, outf;   // act: 0 none, 1 sigmoid, 2 gate-comb
  float scale;
};

__global__ __launch_bounds__(512) void gemm_nt(GemmP p) {
  __shared__ __align__(16) u16 lA[2][4096];
  __shared__ __align__(16) u16 lB[2][4096];
  const int t = threadIdx.x;
  const int wave = t >> 6, lane = t & 63;
  int by = blockIdx.y;
  const u16* Bp; u16* Cp; const float* bias; long ldb, ldc; int nst;
  if (by >= p.ySplit) {
    by -= p.ySplit; Bp = p.B2; Cp = p.C2; bias = p.bias2;
    ldb = p.ldb2; ldc = p.ldc2; nst = p.Nstore2;
  } else {
    Bp = p.B; Cp = p.C; bias = p.bias; ldb = p.ldb; ldc = p.ldc; nst = p.Nstore;
  }
  const u16* B = Bp + (long)by * 128 * ldb;
  const int srow = t >> 2, skk = (t & 3) * 8;
  const int wr = wave >> 2, wc = wave & 3;
  const int fr = lane & 15, fk = (lane >> 4) * 8;
  f32x4 acc[4][2] = {};

  const int nseg = p.A2 ? 2 : 1;
  int cur = 0;
  for (int seg = 0; seg < nseg; ++seg) {
    const u16* A = (seg ? p.A2 : p.A) + (long)blockIdx.x * 128 * p.lda;
    const u16* Bs = B + (long)seg * p.K;
    __builtin_amdgcn_global_load_lds((const AS1 void*)(A + (long)srow*p.lda + skk),
                                     (AS3 void*)&lA[cur][t*8], 16, 0, 0);
    __builtin_amdgcn_global_load_lds((const AS1 void*)(Bs + (long)srow*ldb + skk),
                                     (AS3 void*)&lB[cur][t*8], 16, 0, 0);
    __syncthreads();
    for (int k0 = 0; k0 < p.K; k0 += 32) {
      if (k0 + 32 < p.K) {
        const int nb = cur ^ 1, kn = k0 + 32;
        __builtin_amdgcn_global_load_lds((const AS1 void*)(A + (long)srow*p.lda + kn + skk),
                                         (AS3 void*)&lA[nb][t*8], 16, 0, 0);
        __builtin_amdgcn_global_load_lds((const AS1 void*)(Bs + (long)srow*ldb + kn + skk),
                                         (AS3 void*)&lB[nb][t*8], 16, 0, 0);
      }
      short8 av[4], bv[2];
      #pragma unroll
      for (int mi = 0; mi < 4; ++mi) av[mi] = *(const short8*)&lA[cur][(wr*64 + mi*16 + fr)*32 + fk];
      #pragma unroll
      for (int ni = 0; ni < 2; ++ni) bv[ni] = *(const short8*)&lB[cur][(wc*32 + ni*16 + fr)*32 + fk];
      #pragma unroll
      for (int mi = 0; mi < 4; ++mi)
        #pragma unroll
        for (int ni = 0; ni < 2; ++ni)
          acc[mi][ni] = __builtin_amdgcn_mfma_f32_16x16x32_bf16(av[mi], bv[ni], acc[mi][ni], 0, 0, 0);
      __syncthreads();
      cur ^= 1;
    }
  }

  const int rbase = blockIdx.x*128 + wr*64;
  const int cbase = by*128 + wc*32;
  const int rsub = (lane >> 4) * 4;
  #pragma unroll
  for (int ni = 0; ni < 2; ++ni) {
    const int col = cbase + ni*16 + fr;
    if (col >= nst) continue;
    const float bs = bias ? bias[col] : 0.f;
    #pragma unroll
    for (int mi = 0; mi < 4; ++mi) {
      #pragma unroll
      for (int j = 0; j < 4; ++j) {
        float v = acc[mi][ni][j] * p.scale + bs;
        const long idx = (long)(rbase + mi*16 + rsub + j) * ldc + col;
        if (p.act == 2) {
          const float gv = 1.f / (1.f + __expf(-v));
          const float cv = b2f(p.cr[idx]);
          const float lv = b2f(p.lr[idx]);
          Cp[idx] = f2b(gv*cv + (1.f - gv)*lv);
        } else {
          if (p.act == 1) v = 1.f / (1.f + __expf(-v));
          if (p.outf) ((float*)Cp)[idx] = v;
          else        Cp[idx] = f2b(v);
        }
      }
    }
  }
}

// ---------------------------------------------------------------------------
// Fused flash attention, swapped-QK^T softmax, 2 Q-frags per wave (32 rows).
// Grid (qtile=8, head=16, window=4); 256 thr / 4 waves; block = 128 q-rows.
// kt/vt A/B-operand LDS reads are shared across both Q-frags -> ~1.8x less
// LDS read traffic per output than the 16-row/wave version.
// ---------------------------------------------------------------------------
struct FlashP {
  const u16 *q, *k, *v; u16* o;
  long ldq, ldkv, ldo;
  long qB, kvB, oB;
};

__global__ __launch_bounds__(256) void flash_k(FlashP p) {
  const int t = threadIdx.x, w4 = t >> 6, lane = t & 63;
  const int qt = blockIdx.x, h = blockIdx.y, wz = blockIdx.z;
  const int fr = lane & 15, g = lane >> 4, fk = g * 8;
  __shared__ __align__(16) u16 kt[64][72];
  __shared__ __align__(16) u16 vt[64][72];
  __shared__ __align__(16) u16 pl[4][32][72];

  const u16* Q = p.q + (long)wz*p.qB + (long)(qt*128 + w4*32)*p.ldq + h*64;
  const u16* K = p.k + (long)wz*p.kvB + h*64;
  const u16* V = p.v + (long)wz*p.kvB + h*64;

  short8 aq[2][2];
  #pragma unroll
  for (int f = 0; f < 2; ++f) {
    aq[f][0] = *(const short8*)&Q[(long)(f*16 + fr)*p.ldq + fk];
    aq[f][1] = *(const short8*)&Q[(long)(f*16 + fr)*p.ldq + 32 + fk];
  }

  f32x4 acc[2][4] = {};
  float ml[2] = {-3e38f, -3e38f}, ll[2] = {0.f, 0.f};
  const float C = 0.125f * 1.44269504f;     // score-scale * log2(e)

  // staging roles: K coalesced rows; V key-pairs for packed transpose writes
  const int krow = t >> 2, kseg = (t & 3) * 16;
  const int vp = t & 31, vc = (t >> 5) * 8;

  short8 kr0, kr1, vr0, vr1;
  kr0 = *(const short8*)&K[(long)krow*p.ldkv + kseg];
  kr1 = *(const short8*)&K[(long)krow*p.ldkv + kseg + 8];
  vr0 = *(const short8*)&V[(long)(2*vp)*p.ldkv + vc];
  vr1 = *(const short8*)&V[(long)(2*vp + 1)*p.ldkv + vc];

  for (int it = 0; it < 16; ++it) {
    // ---- write staged regs to LDS ----
    *(short8*)&kt[krow][kseg]     = kr0;
    *(short8*)&kt[krow][kseg + 8] = kr1;
    #pragma unroll
    for (int e = 0; e < 8; ++e) {
      const uint32_t pk = (uint32_t)(uint16_t)vr0[e] | ((uint32_t)(uint16_t)vr1[e] << 16);
      *(uint32_t*)&vt[vc + e][2*vp] = pk;
    }
    __syncthreads();

    // ---- prefetch next tile into regs ----
    if (it + 1 < 16) {
      const int kn = (it + 1) * 64;
      kr0 = *(const short8*)&K[(long)(kn + krow)*p.ldkv + kseg];
      kr1 = *(const short8*)&K[(long)(kn + krow)*p.ldkv + kseg + 8];
      vr0 = *(const short8*)&V[(long)(kn + 2*vp)*p.ldkv + vc];
      vr1 = *(const short8*)&V[(long)(kn + 2*vp + 1)*p.ldkv + vc];
    }

    // ---- S^T = K Q^T: kt frags shared by both Q-frags ----
    f32x4 s[2][4] = {};
    __builtin_amdgcn_s_setprio(1);
    #pragma unroll
    for (int ni = 0; ni < 4; ++ni) {
      short8 bk0 = *(const short8*)&kt[ni*16 + fr][fk];
      short8 bk1 = *(const short8*)&kt[ni*16 + fr][32 + fk];
      #pragma unroll
      for (int f = 0; f < 2; ++f) {
        s[f][ni] = __builtin_amdgcn_mfma_f32_16x16x32_bf16(bk0, aq[f][0], s[f][ni], 0, 0, 0);
        s[f][ni] = __builtin_amdgcn_mfma_f32_16x16x32_bf16(bk1, aq[f][1], s[f][ni], 0, 0, 0);
      }
    }
    __builtin_amdgcn_s_setprio(0);

    // ---- online softmax per frag, lane-local row ----
    #pragma unroll
    for (int f = 0; f < 2; ++f) {
      float rm = s[f][0][0];
      #pragma unroll
      for (int ni = 0; ni < 4; ++ni)
        #pragma unroll
        for (int j = 0; j < 4; ++j) rm = fmaxf(rm, s[f][ni][j]);
      rm = fmaxf(rm, __shfl_xor(rm, 16, 64));
      rm = fmaxf(rm, __shfl_xor(rm, 32, 64));
      const float rml = rm * C;

      if (__any(rml > ml[f] + 11.5f)) {
        const float mnl = fmaxf(ml[f], rml);
        const float al = exp2f(ml[f] - mnl);
        const float a0 = __shfl(al, g*4 + 0, 64);
        const float a1 = __shfl(al, g*4 + 1, 64);
        const float a2 = __shfl(al, g*4 + 2, 64);
        const float a3 = __shfl(al, g*4 + 3, 64);
        #pragma unroll
        for (int nv = 0; nv < 4; ++nv) {
          acc[f][nv][0] *= a0; acc[f][nv][1] *= a1;
          acc[f][nv][2] *= a2; acc[f][nv][3] *= a3;
        }
        ll[f] *= al;
        ml[f] = mnl;
      }

      float rs = 0.f;
      u16 pb[4][4];
      #pragma unroll
      for (int ni = 0; ni < 4; ++ni)
        #pragma unroll
        for (int j = 0; j < 4; ++j) {
          const float pv = exp2f(s[f][ni][j]*C - ml[f]);
          rs += pv;
          pb[ni][j] = f2bf(pv);
        }
      rs += __shfl_xor(rs, 16, 64);
      rs += __shfl_xor(rs, 32, 64);
      ll[f] += rs;

      #pragma unroll
      for (int ni = 0; ni < 4; ++ni) {
        short4v pk4;
        pk4[0] = (short)pb[ni][0]; pk4[1] = (short)pb[ni][1];
        pk4[2] = (short)pb[ni][2]; pk4[3] = (short)pb[ni][3];
        *(short4v*)&pl[w4][f*16 + fr][ni*16 + g*4] = pk4;
      }
    }

    // ---- PV accumulate: vt frags shared by both Q-frags ----
    __builtin_amdgcn_s_setprio(1);
    #pragma unroll
    for (int ks = 0; ks < 2; ++ks) {
      short8 pa0 = *(const short8*)&pl[w4][fr][ks*32 + fk];
      short8 pa1 = *(const short8*)&pl[w4][16 + fr][ks*32 + fk];
      #pragma unroll
      for (int nv = 0; nv < 4; ++nv) {
        short8 bvv = *(const short8*)&vt[nv*16 + fr][ks*32 + fk];
        acc[0][nv] = __builtin_amdgcn_mfma_f32_16x16x32_bf16(pa0, bvv, acc[0][nv], 0, 0, 0);
        acc[1][nv] = __builtin_amdgcn_mfma_f32_16x16x32_bf16(pa1, bvv, acc[1][nv], 0, 0, 0);
      }
    }
    __builtin_amdgcn_s_setprio(0);
    __syncthreads();   // protect kt/vt before next tile's LDS writes
  }

  // ---- epilogue per frag ----
  u16* O = p.o + (long)wz*p.oB + (long)(qt*128 + w4*32)*p.ldo + h*64;
  #pragma unroll
  for (int f = 0; f < 2; ++f) {
    const float l0 = __shfl(ll[f], g*4 + 0, 64);
    const float l1 = __shfl(ll[f], g*4 + 1, 64);
    const float l2 = __shfl(ll[f], g*4 + 2, 64);
    const float l3 = __shfl(ll[f], g*4 + 3, 64);
    const float inv[4] = {1.f/l0, 1.f/l1, 1.f/l2, 1.f/l3};
    #pragma unroll
    for (int j = 0; j < 4; ++j)
      #pragma unroll
      for (int nv = 0; nv < 4; ++nv)
        O[(long)(f*16 + g*4 + j)*p.ldo + nv*16 + fr] = f2bf(acc[f][nv][j] * inv[j]);
  }
}

// -------- qs = sum_query @ wq^T + bq  (grid 16, 256 thr, k-split) --------
__global__ void gemv_qs(const float* sq, const float* w, const float* b, float* out) {
  const int t = threadIdx.x, nl = t & 63, kq = t >> 6;
  const int n = blockIdx.x*64 + nl;
  const float* row = w + (long)n * 1024 + kq*256;
  const float* q = sq + kq*256;
  float s = 0.f;
  for (int k = 0; k < 256; k += 4) {
    float4 ww = *(const float4*)&row[k];
    float4 qq = *(const float4*)&q[k];
    s += qq.x*ww.x + qq.y*ww.y + qq.z*ww.z + qq.w*ww.w;
  }
  __shared__ float ps[4][64];
  ps[kq][nl] = s;
  __syncthreads();
  if (t < 64) out[blockIdx.x*64 + t] = ps[0][t]+ps[1][t]+ps[2][t]+ps[3][t] + b[blockIdx.x*64 + t];
}

// ------- summary attention: block (h,w), 256 threads, k-parallel -------
__global__ void sum_attend(const float* qs, const u16* sumkv, float* content, float* pall) {
  const int h = blockIdx.x, w = blockIdx.y, t = threadIdx.x;
  const int lane = t & 63, wv = t >> 6;
  __shared__ float qsh[64];
  __shared__ float sc[1024];
  __shared__ float rmax[4], rsum[4];
  __shared__ float po[4][64];
  if (t < 64) qsh[t] = qs[h*64 + t];
  __syncthreads();
  const u16* kbase = sumkv + (long)w*2097152 + h*64;
  float e[4];
  float mx = -1e30f;
  #pragma unroll
  for (int j = 0; j < 4; ++j) {
    const int k = j*256 + t;
    const u16* krow = kbase + (long)k * 2048;
    float s = 0.f;
    #pragma unroll
    for (int d = 0; d < 64; d += 8) {
      ushort8 kk = *(const ushort8*)&krow[d];
      #pragma unroll
      for (int q = 0; q < 8; ++q) s += qsh[d+q] * b2f(kk[q]);
    }
    s *= 0.125f;
    e[j] = s;
    mx = fmaxf(mx, s);
  }
  #pragma unroll
  for (int o = 32; o; o >>= 1) mx = fmaxf(mx, __shfl_xor(mx, o, 64));
  if (lane == 0) rmax[wv] = mx;
  __syncthreads();
  mx = fmaxf(fmaxf(rmax[0],rmax[1]), fmaxf(rmax[2],rmax[3]));
  float sum = 0.f;
  #pragma unroll
  for (int j = 0; j < 4; ++j) { e[j] = __expf(e[j]-mx); sum += e[j]; }
  #pragma unroll
  for (int o = 32; o; o >>= 1) sum += __shfl_xor(sum, o, 64);
  if (lane == 0) rsum[wv] = sum;
  __syncthreads();
  const float inv = 1.f / (rsum[0]+rsum[1]+rsum[2]+rsum[3]);
  float* pr = pall + ((long)w*16 + h)*1024;
  #pragma unroll
  for (int j = 0; j < 4; ++j) {
    const int k = j*256 + t;
    const float pn = e[j]*inv;
    sc[k] = pn;
    pr[k] = pn;
  }
  __syncthreads();
  const u16* vbase = sumkv + (long)w*2097152 + 1024 + h*64;
  float o = 0.f;
  const int k0 = wv*256;
  for (int k = k0; k < k0+256; ++k) o += sc[k] * b2f(vbase[(long)k*2048 + lane]);
  po[wv][lane] = o;
  __syncthreads();
  if (t < 64) content[(long)w*1024 + h*64 + t] = po[0][t]+po[1][t]+po[2][t]+po[3][t];
}

__global__ void wavg_k(const float* pall, float* wavg) {
  const int w = blockIdx.y, k = blockIdx.x*256 + threadIdx.x;
  float s = 0.f;
  #pragma unroll
  for (int h = 0; h < 16; ++h) s += pall[((long)w*16 + h)*1024 + k];
  wavg[w*1024 + k] = s * (1.f/16.f);
}

// ------- content projection (grid (16,4), 256 thr, k-split) -------
__global__ void contproj_k(const float* content, const float* w_, const float* b, float* out) {
  const int w = blockIdx.y, t = threadIdx.x;
  const int nl = t & 63, kq = t >> 6;
  const int n = blockIdx.x*64 + nl;
  const float* c = content + w*1024 + kq*256;
  const float* row = w_ + (long)n * 1024 + kq*256;
  float s = 0.f;
  for (int k = 0; k < 256; k += 4) {
    float4 ww = *(const float4*)&row[k];
    s += c[k]*ww.x + c[k+1]*ww.y + c[k+2]*ww.z + c[k+3]*ww.w;
  }
  __shared__ float ps[4][64];
  ps[kq][nl] = s;
  __syncthreads();
  if (t < 64) out[w*1024 + blockIdx.x*64 + t] = ps[0][t]+ps[1][t]+ps[2][t]+ps[3][t] + b[blockIdx.x*64 + t];
}

// ------- attn_stats phase A: parallel rank-count (grid (16,4), 256 thr) -----
__global__ void stats1_k(const float* wavg, float* part) {
  const int c = blockIdx.x, w = blockIdx.y, t = threadIdx.x;
  __shared__ float a[1024];
  for (int i = t; i < 1024; i += 256) a[i] = wavg[w*1024 + i];
  __syncthreads();
  const int jl = t & 63, iq = t >> 6;
  const int j = c*64 + jl;
  const float aj = a[j];
  int pr = 0;
  const int i0 = iq*256;
  #pragma unroll 8
  for (int i = i0; i < i0+256; ++i) {
    const float ai = a[i];
    pr += (ai < aj) || (ai == aj && i < j);
  }
  __shared__ int prs[4][64];
  prs[iq][jl] = pr;
  __syncthreads();
  if (t < 64) {
    const int rank = 1 + prs[0][jl] + prs[1][jl] + prs[2][jl] + prs[3][jl];
    float ent = -aj * logf(aj + 1e-8f);
    float gnum = (float)rank * aj;
    float ssum = aj;
    float mx = aj;
    float top5 = (rank >= 1020) ? aj : 0.f;
    #pragma unroll
    for (int o = 32; o; o >>= 1) {
      ent += __shfl_xor(ent, o, 64);
      gnum += __shfl_xor(gnum, o, 64);
      ssum += __shfl_xor(ssum, o, 64);
      mx = fmaxf(mx, __shfl_xor(mx, o, 64));
      top5 += __shfl_xor(top5, o, 64);
    }
    if (t == 0) {
      float* pp = part + ((w*16 + c) * 5);
      pp[0]=ent; pp[1]=gnum; pp[2]=ssum; pp[3]=mx; pp[4]=top5;
    }
  }
}

// ------- attn_stats phase B: reduce 16 chunk-partials (grid 4, 128 thr) -----
__global__ void stats2_k(const float* part, float* stats) {
  const int w = blockIdx.x, t = threadIdx.x;
  const int c = t & 15, stat = t >> 4;
  float v = 0.f;
  const bool active = stat < 5;
  if (active) v = part[(w*16 + c)*5 + stat];
  #pragma unroll
  for (int o = 8; o; o >>= 1) {
    const float ov = __shfl_xor(v, o, 64);
    v = (stat == 3) ? fmaxf(v, ov) : (v + ov);
  }
  __shared__ float r5[5];
  if (active && c == 0) r5[stat] = v;
  __syncthreads();
  if (t == 0) {
    stats[w*4+0] = r5[0];
    stats[w*4+1] = 2.f*r5[1]/(1024.f*r5[2] + 1e-8f) - 1025.f/1024.f;
    stats[w*4+2] = r5[3];
    stats[w*4+3] = r5[4];
  }
}

// ------- pat MLP + summary combine (grid 4, 256 thr, k-split) -------
__global__ void patsum_k(const float* stats, const float* contprj,
                         const float* pw1, const float* pb1, const float* pw2, const float* pb2,
                         const float* combw, const float* combb, float* summ) {
  const int w = blockIdx.x, t = threadIdx.x;
  const int nl = t & 63, kq = t >> 6;
  __shared__ float p1[64], pat[64];
  __shared__ float ps[4][64];
  __shared__ float ps2[4][64];
  if (t < 64) {
    float s = 0.f;
    #pragma unroll
    for (int k = 0; k < 4; ++k) s += stats[w*4+k] * pw1[t*4+k];
    p1[t] = fmaxf(s + pb1[t], 0.f);
  }
  __syncthreads();
  {
    float s = 0.f;
    const float* rw = pw2 + (long)nl*64 + kq*16;
    const float* pp = p1 + kq*16;
    #pragma unroll
    for (int k = 0; k < 16; ++k) s += pp[k] * rw[k];
    ps[kq][nl] = s;
  }
  __syncthreads();
  if (t < 64) pat[t] = ps[0][t]+ps[1][t]+ps[2][t]+ps[3][t] + pb2[t];
  __syncthreads();
  const float* c = contprj + w*1024;
  const float* row = combw + (long)nl * 1088;
  float s = 0.f;
  const int k0 = kq*272;
  for (int k = k0; k < k0+272; ++k) {
    const float rv = row[k];
    const float cv = (k < 1024) ? c[k] : pat[k-1024];
    s += cv * rv;
  }
  ps2[kq][nl] = s;
  __syncthreads();
  if (t < 64) summ[w*64 + t] = ps2[0][t]+ps2[1][t]+ps2[2][t]+ps2[3][t] + combb[t];
}

// ---------------- meta attention + routing (1 block, 64 threads) ------------
__global__ void meta_k(const float* summ, const float* miw, const float* mib,
                       const float* mow, const float* mob, const float* rw1, const float* rb1,
                       const float* rw2, const float* rb2, float* routing) {
  const int t = threadIdx.x;
  __shared__ float qkv[4][192];
  __shared__ float sc[64];
  __shared__ float o[4][64];
  __shared__ float rf[4][64];
  __shared__ float t1[4][64];
  __shared__ float lg[4];
  for (int idx = t; idx < 768; idx += 64) {
    const int w = idx / 192, rrow = idx % 192;
    const float* rw = miw + (long)rrow * 64;
    float s = 0.f;
    for (int k = 0; k < 64; ++k) s += summ[w*64+k] * rw[k];
    qkv[w][rrow] = s + mib[rrow];
  }
  __syncthreads();
  {
    const int h = t >> 4, i = (t >> 2) & 3, j = t & 3;
    float s = 0.f;
    #pragma unroll
    for (int d = 0; d < 16; ++d) s += qkv[i][h*16+d] * qkv[j][64 + h*16+d];
    sc[t] = s * 0.25f;
  }
  __syncthreads();
  if (t < 16) {
    const float a0=sc[t*4], a1=sc[t*4+1], a2=sc[t*4+2], a3=sc[t*4+3];
    const float m = fmaxf(fmaxf(a0,a1), fmaxf(a2,a3));
    const float e0=__expf(a0-m), e1=__expf(a1-m), e2=__expf(a2-m), e3=__expf(a3-m);
    const float s = e0+e1+e2+e3;
    sc[t*4]=e0/s; sc[t*4+1]=e1/s; sc[t*4+2]=e2/s; sc[t*4+3]=e3/s;
  }
  __syncthreads();
  for (int idx = t; idx < 256; idx += 64) {
    const int i = idx >> 6, c = idx & 63, h = c >> 4;
    float s = 0.f;
    #pragma unroll
    for (int j = 0; j < 4; ++j) s += sc[(h*4+i)*4+j] * qkv[j][128 + c];
    o[i][c] = s;
  }
  __syncthreads();
  for (int idx = t; idx < 256; idx += 64) {
    const int i = idx >> 6, n = idx & 63;
    const float* rw = mow + (long)n * 64;
    float s = 0.f;
    for (int k = 0; k < 64; ++k) s += o[i][k] * rw[k];
    rf[i][n] = s + mob[n];
  }
  __syncthreads();
  for (int idx = t; idx < 256; idx += 64) {
    const int i = idx >> 6, n = idx & 63;
    const float* rw = rw1 + (long)n * 64;
    float s = 0.f;
    for (int k = 0; k < 64; ++k) s += rf[i][k] * rw[k];
    t1[i][n] = fmaxf(s + rb1[n], 0.f);
  }
  __syncthreads();
  if (t < 4) {
    float s = 0.f;
    for (int k = 0; k < 64; ++k) s += t1[t][k] * rw2[k];
    lg[t] = s + rb2[0];
  }
  __syncthreads();
  if (t == 0) {
    const float m = fmaxf(fmaxf(lg[0],lg[1]), fmaxf(lg[2],lg[3]));
    float e[4], s = 0.f;
    #pragma unroll
    for (int i = 0; i < 4; ++i) { e[i] = __expf(lg[i]-m); s += e[i]; }
    #pragma unroll
    for (int i = 0; i < 4; ++i) routing[i] = e[i]/s;
  }
}

// ---------------- routing-weighted kv mix ----------------
__global__ void kvr_k(const u16* local, const float* routing, u16* kvr) {
  const int r = blockIdx.y;
  const long e = ((long)blockIdx.x*256 + threadIdx.x) * 8;
  float rm[4]; float s = 0.f;
  #pragma unroll
  for (int w = 0; w < 4; ++w) { rm[w] = (w == r) ? 0.f : routing[w]; s += rm[w]; }
  const float inv = 1.f / (s + 1e-8f);
  ushort8 a0 = *(const ushort8*)&local[e];
  ushort8 a1 = *(const ushort8*)&local[1048576 + e];
  ushort8 a2 = *(const ushort8*)&local[2097152 + e];
  ushort8 a3 = *(const ushort8*)&local[3145728 + e];
  ushort8 out;
  #pragma unroll
  for (int j = 0; j < 8; ++j)
    out[j] = f2b((rm[0]*b2f(a0[j]) + rm[1]*b2f(a1[j]) + rm[2]*b2f(a2[j]) + rm[3]*b2f(a3[j])) * inv);
  *(ushort8*)&kvr[(long)r*1048576 + e] = out;
}

// ---------------------------------------------------------------------------
static void gemm1(hipStream_t st, dim3 grid,
                  const u16* A, long lda, const u16* B, long ldb,
                  u16* C, long ldc, const float* bias,
                  int K, int N, float scale, int act, int outf) {
  GemmP p = {};
  p.A=A; p.B=B; p.C=C; p.bias=bias;
  p.lda=lda; p.ldb=ldb; p.ldc=ldc;
  p.K=K; p.Nstore=N; p.ySplit=1<<30; p.act=act; p.outf=outf; p.scale=scale;
  gemm_nt<<<grid, dim3(512), 0, st>>>(p);
}

extern "C" void kernel_launch(void* const* d_in, const int* in_sizes, int n_in,
                              void* d_out, int out_size, void* d_ws, size_t ws_size,
                              hipStream_t stream) {
  (void)in_sizes; (void)n_in; (void)out_size; (void)ws_size;
  const float* x   = (const float*)d_in[0];
  const float* liw = (const float*)d_in[1];
  const float* lib = (const float*)d_in[2];
  const float* low = (const float*)d_in[3];
  const float* lob = (const float*)d_in[4];
  const float* sq  = (const float*)d_in[5];
  const float* siw = (const float*)d_in[6];
  const float* sib = (const float*)d_in[7];
  const float* sow = (const float*)d_in[8];
  const float* sob = (const float*)d_in[9];
  const float* pw1 = (const float*)d_in[10];
  const float* pb1 = (const float*)d_in[11];
  const float* pw2 = (const float*)d_in[12];
  const float* pb2 = (const float*)d_in[13];
  const float* cbw = (const float*)d_in[14];
  const float* cbb = (const float*)d_in[15];
  const float* miw = (const float*)d_in[16];
  const float* mib = (const float*)d_in[17];
  const float* mow = (const float*)d_in[18];
  const float* mob = (const float*)d_in[19];
  const float* rw1 = (const float*)d_in[20];
  const float* rb1 = (const float*)d_in[21];
  const float* rw2 = (const float*)d_in[22];
  const float* rb2 = (const float*)d_in[23];
  const float* ciw = (const float*)d_in[24];
  const float* cib = (const float*)d_in[25];
  const float* cow = (const float*)d_in[26];
  const float* cob = (const float*)d_in[27];
  const float* gw  = (const float*)d_in[28];
  const float* gb  = (const float*)d_in[29];
  const float* pw  = (const float*)d_in[30];
  const float* pb  = (const float*)d_in[31];

  char* ws = (char*)d_ws;
  u16* qkv    = (u16*)(ws + 0);
  u16* aout   = (u16*)(ws + 25165824);
  u16* local  = (u16*)(ws + 33554432);
  u16* scratch= (u16*)(ws + 41943040);
  u16* s2048  = (u16*)(ws + 79691776);
  u16* cq     = (u16*)(ws + 96468992);
  u16* kvr    = (u16*)(ws + 104857600);
  u16* crossb = (u16*)(ws + 113246208);
  char* sf = ws + 121634816;
  float* qs      = (float*)(sf + 0);
  float* pall    = (float*)(sf + 4096);
  float* wavg    = (float*)(sf + 266240);
  float* content = (float*)(sf + 282624);
  float* contprj = (float*)(sf + 299008);
  float* stats   = (float*)(sf + 315392);
  float* summ    = (float*)(sf + 315456);
  float* routing = (float*)(sf + 316480);
  float* part    = (float*)(sf + 316544);
  u16* siwkvb = (u16*)(ws + 122028032);
  u16* lowb   = (u16*)(ws + 126222336);
  u16* ciwb   = (u16*)(ws + 128319488);
  u16* cowb   = (u16*)(ws + 134610944);
  u16* gwb    = (u16*)(ws + 136708096);
  u16* pwb    = (u16*)(ws + 140902400);
  u16* xb   = crossb;
  u16* liwb = scratch;

  // 0. fp32 -> bf16 conversions
  CvtP cp;
  cp.src[0]=x;   cp.dst[0]=xb;     cp.n[0]=4194304;
  cp.src[1]=liw; cp.dst[1]=liwb;   cp.n[1]=3145728;
  cp.src[2]=low; cp.dst[2]=lowb;   cp.n[2]=1048576;
  cp.src[3]=siw+1048576; cp.dst[3]=siwkvb; cp.n[3]=2097152;
  cp.src[4]=ciw; cp.dst[4]=ciwb;   cp.n[4]=3145728;
  cp.src[5]=cow; cp.dst[5]=cowb;   cp.n[5]=1048576;
  cp.src[6]=gw;  cp.dst[6]=gwb;    cp.n[6]=2097152;
  cp.src[7]=pw;  cp.dst[7]=pwb;    cp.n[7]=1048576;
  cvt_multi<<<dim3(2048, 8), dim3(256), 0, stream>>>(cp);

  // 1. local QKV projection
  gemm1(stream, dim3(32,24), xb,1024, liwb,1024, qkv,3072, lib, 1024, 3072, 1.f, 0, 0);

  // 2. fused local self-attention
  {
    FlashP fp;
    fp.q = qkv; fp.k = qkv + 1024; fp.v = qkv + 2048; fp.o = aout;
    fp.ldq = 3072; fp.ldkv = 3072; fp.ldo = 1024;
    fp.qB = 3145728; fp.kvB = 3145728; fp.oB = 1048576;
    flash_k<<<dim3(8,16,4), dim3(256), 0, stream>>>(fp);
  }

  // 3. local out-projection
  gemm1(stream, dim3(32,8), aout,1024, lowb,1024, local,1024, lob, 1024, 1024, 1.f, 0, 0);

  // 4. combined crossQ (y<8) + summary K/V (y>=8) projections
  {
    GemmP p = {};
    p.A = local; p.lda = 1024; p.K = 1024; p.scale = 1.f;
    p.B = ciwb;   p.C = cq;    p.bias = cib;      p.ldb = 1024; p.ldc = 1024; p.Nstore = 1024;
    p.B2 = siwkvb; p.C2 = s2048; p.bias2 = sib+1024; p.ldb2 = 1024; p.ldc2 = 2048; p.Nstore2 = 2048;
    p.ySplit = 8;
    gemm_nt<<<dim3(32,24), dim3(512), 0, stream>>>(p);
  }

  // 5. summaries
  gemv_qs<<<dim3(16), dim3(256), 0, stream>>>(sq, siw, sib, qs);
  sum_attend<<<dim3(16,4), dim3(256), 0, stream>>>(qs, s2048, content, pall);
  wavg_k<<<dim3(4,4), dim3(256), 0, stream>>>(pall, wavg);
  contproj_k<<<dim3(16,4), dim3(256), 0, stream>>>(content, sow, sob, contprj);
  stats1_k<<<dim3(16,4), dim3(256), 0, stream>>>(wavg, part);
  stats2_k<<<dim3(4), dim3(128), 0, stream>>>(part, stats);
  patsum_k<<<dim3(4), dim3(256), 0, stream>>>(stats, contprj, pw1, pb1, pw2, pb2, cbw, cbb, summ);

  // 6. meta attention + routing
  meta_k<<<dim3(1), dim3(64), 0, stream>>>(summ, miw, mib, mow, mob, rw1, rb1, rw2, rb2, routing);

  // 7. per-rank mixed kv
  kvr_k<<<dim3(512,4), dim3(256), 0, stream>>>(local, routing, kvr);

  // 8. cross K/V projection
  gemm1(stream, dim3(32,16), kvr,1024, ciwb+1048576,1024, s2048,2048, cib+1024, 1024, 2048, 1.f, 0, 0);

  // 9. fused cross attention
  {
    FlashP fp;
    fp.q = cq; fp.k = s2048; fp.v = s2048 + 1024; fp.o = aout;
    fp.ldq = 1024; fp.ldkv = 2048; fp.ldo = 1024;
    fp.qB = 1048576; fp.kvB = 2097152; fp.oB = 1048576;
    flash_k<<<dim3(8,16,4), dim3(256), 0, stream>>>(fp);
  }

  // 10. cross out-projection
  gemm1(stream, dim3(32,8), aout,1024, cowb,1024, crossb,1024, cob, 1024, 1024, 1.f, 0, 0);

  // 11. gate GEMM (dual-K: local@gw_l + cross@gw_c) with fused sigmoid+comb
  {
    GemmP p = {};
    p.A = local; p.A2 = crossb; p.lr = local; p.cr = crossb;
    p.B = gwb; p.C = kvr; p.bias = gb;
    p.lda = 1024; p.ldb = 2048; p.ldc = 1024;
    p.K = 1024; p.Nstore = 1024; p.ySplit = 1<<30; p.act = 2; p.outf = 0; p.scale = 1.f;
    gemm_nt<<<dim3(32,8), dim3(512), 0, stream>>>(p);
  }

  // 12. final projection -> d_out (fp32)
  gemm1(stream, dim3(32,8), kvr,1024, pwb,1024, (u16*)d_out,1024, pb, 1024, 1024, 1.f, 0, 1);
}

// Round 10
// 424.685 us; speedup vs baseline: 2.6950x; 1.0082x over previous
//
#include <hip/hip_runtime.h>
#include <hip/hip_bf16.h>
#include <stdint.h>

typedef uint16_t u16;
typedef __attribute__((ext_vector_type(8))) short short8;
typedef __attribute__((ext_vector_type(4))) short short4v;
typedef __attribute__((ext_vector_type(8))) unsigned short ushort8;
typedef __attribute__((ext_vector_type(4))) float f32x4;

#define AS1 __attribute__((address_space(1)))
#define AS3 __attribute__((address_space(3)))

__device__ __forceinline__ float b2f(u16 u){
  union{uint32_t i; float f;} v; v.i=((uint32_t)u)<<16; return v.f;
}
__device__ __forceinline__ u16 f2b(float f){
  union{uint32_t i; float f;} v; v.f=f;
  return (u16)((v.i + 0x7fffu + ((v.i>>16)&1u))>>16);
}
__device__ __forceinline__ u16 f2bf(float f){   // hw-friendly convert (RTE)
  __hip_bfloat16 h = __float2bfloat16(f);
  return *reinterpret_cast<u16*>(&h);
}

// ---------------- fused fp32 -> bf16 conversions (8 segments, 1 launch) -----
struct CvtP { const float* src[8]; u16* dst[8]; long n[8]; };
__global__ void cvt_multi(CvtP p) {
  const int seg = blockIdx.y;
  const long i = ((long)blockIdx.x*256 + threadIdx.x)*8;
  if (i >= p.n[seg]) return;
  const float* in = p.src[seg];
  float4 a = *(const float4*)&in[i];
  float4 b = *(const float4*)&in[i+4];
  ushort8 o;
  o[0]=f2b(a.x); o[1]=f2b(a.y); o[2]=f2b(a.z); o[3]=f2b(a.w);
  o[4]=f2b(b.x); o[5]=f2b(b.y); o[6]=f2b(b.z); o[7]=f2b(b.w);
  *(ushort8*)&p.dst[seg][i] = o;
}

// ---------------------------------------------------------------------------
// NT GEMM, 128x128 tile, BK=32, 8 waves (512 thr), double-buffered LDS.
// Optional second y-segment (ySplit); optional dual-K (A2: accumulate a
// second A@B' over the next K columns of B); act 2 = fused sigmoid-gate comb.
// ---------------------------------------------------------------------------
struct GemmP {
  const u16* A; const u16* B; u16* C; const float* bias;
  const u16* B2; u16* C2; const float* bias2;
  const u16* A2; const u16* lr; const u16* cr;   // dual-K + comb inputs
  long lda, ldb, ldc, ldb2, ldc2;
  int K, Nstore, Nstore2, ySplit, act, outf;   // act: 0 none, 1 sigmoid, 2 gate-comb
  float scale;
};

__global__ __launch_bounds__(512) void gemm_nt(GemmP p) {
  __shared__ __align__(16) u16 lA[2][4096];
  __shared__ __align__(16) u16 lB[2][4096];
  const int t = threadIdx.x;
  const int wave = t >> 6, lane = t & 63;
  int by = blockIdx.y;
  const u16* Bp; u16* Cp; const float* bias; long ldb, ldc; int nst;
  if (by >= p.ySplit) {
    by -= p.ySplit; Bp = p.B2; Cp = p.C2; bias = p.bias2;
    ldb = p.ldb2; ldc = p.ldc2; nst = p.Nstore2;
  } else {
    Bp = p.B; Cp = p.C; bias = p.bias; ldb = p.ldb; ldc = p.ldc; nst = p.Nstore;
  }
  const u16* B = Bp + (long)by * 128 * ldb;
  const int srow = t >> 2, skk = (t & 3) * 8;
  const int wr = wave >> 2, wc = wave & 3;
  const int fr = lane & 15, fk = (lane >> 4) * 8;
  f32x4 acc[4][2] = {};

  const int nseg = p.A2 ? 2 : 1;
  int cur = 0;
  for (int seg = 0; seg < nseg; ++seg) {
    const u16* A = (seg ? p.A2 : p.A) + (long)blockIdx.x * 128 * p.lda;
    const u16* Bs = B + (long)seg * p.K;
    __builtin_amdgcn_global_load_lds((const AS1 void*)(A + (long)srow*p.lda + skk),
                                     (AS3 void*)&lA[cur][t*8], 16, 0, 0);
    __builtin_amdgcn_global_load_lds((const AS1 void*)(Bs + (long)srow*ldb + skk),
                                     (AS3 void*)&lB[cur][t*8], 16, 0, 0);
    __syncthreads();
    for (int k0 = 0; k0 < p.K; k0 += 32) {
      if (k0 + 32 < p.K) {
        const int nb = cur ^ 1, kn = k0 + 32;
        __builtin_amdgcn_global_load_lds((const AS1 void*)(A + (long)srow*p.lda + kn + skk),
                                         (AS3 void*)&lA[nb][t*8], 16, 0, 0);
        __builtin_amdgcn_global_load_lds((const AS1 void*)(Bs + (long)srow*ldb + kn + skk),
                                         (AS3 void*)&lB[nb][t*8], 16, 0, 0);
      }
      short8 av[4], bv[2];
      #pragma unroll
      for (int mi = 0; mi < 4; ++mi) av[mi] = *(const short8*)&lA[cur][(wr*64 + mi*16 + fr)*32 + fk];
      #pragma unroll
      for (int ni = 0; ni < 2; ++ni) bv[ni] = *(const short8*)&lB[cur][(wc*32 + ni*16 + fr)*32 + fk];
      #pragma unroll
      for (int mi = 0; mi < 4; ++mi)
        #pragma unroll
        for (int ni = 0; ni < 2; ++ni)
          acc[mi][ni] = __builtin_amdgcn_mfma_f32_16x16x32_bf16(av[mi], bv[ni], acc[mi][ni], 0, 0, 0);
      __syncthreads();
      cur ^= 1;
    }
  }

  const int rbase = blockIdx.x*128 + wr*64;
  const int cbase = by*128 + wc*32;
  const int rsub = (lane >> 4) * 4;
  #pragma unroll
  for (int ni = 0; ni < 2; ++ni) {
    const int col = cbase + ni*16 + fr;
    if (col >= nst) continue;
    const float bs = bias ? bias[col] : 0.f;
    #pragma unroll
    for (int mi = 0; mi < 4; ++mi) {
      #pragma unroll
      for (int j = 0; j < 4; ++j) {
        float v = acc[mi][ni][j] * p.scale + bs;
        const long idx = (long)(rbase + mi*16 + rsub + j) * ldc + col;
        if (p.act == 2) {
          const float gv = 1.f / (1.f + __expf(-v));
          const float cv = b2f(p.cr[idx]);
          const float lv = b2f(p.lr[idx]);
          Cp[idx] = f2b(gv*cv + (1.f - gv)*lv);
        } else {
          if (p.act == 1) v = 1.f / (1.f + __expf(-v));
          if (p.outf) ((float*)Cp)[idx] = v;
          else        Cp[idx] = f2b(v);
        }
      }
    }
  }
}

// ---------------------------------------------------------------------------
// Fused flash attention, swapped-QK^T softmax, 2 Q-frags per wave (32 rows).
// 1-D grid of 512, XCD-aware decode: bid = qt*64 + wz*16 + h, so the 8
// qtile-blocks sharing one (h,wz) K/V slice have bid%8 = h%8 -> same XCD L2
// (K/V slice fetched once per XCD instead of 8x).
// ---------------------------------------------------------------------------
struct FlashP {
  const u16 *q, *k, *v; u16* o;
  long ldq, ldkv, ldo;
  long qB, kvB, oB;
};

__global__ __launch_bounds__(256) void flash_k(FlashP p) {
  const int t = threadIdx.x, w4 = t >> 6, lane = t & 63;
  const int bid = blockIdx.x;
  const int qt = bid >> 6;           // 0..7
  const int h  = bid & 15;           // 0..15
  const int wz = (bid >> 4) & 3;     // 0..3
  const int fr = lane & 15, g = lane >> 4, fk = g * 8;
  __shared__ __align__(16) u16 kt[64][72];
  __shared__ __align__(16) u16 vt[64][72];
  __shared__ __align__(16) u16 pl[4][32][72];

  const u16* Q = p.q + (long)wz*p.qB + (long)(qt*128 + w4*32)*p.ldq + h*64;
  const u16* K = p.k + (long)wz*p.kvB + h*64;
  const u16* V = p.v + (long)wz*p.kvB + h*64;

  short8 aq[2][2];
  #pragma unroll
  for (int f = 0; f < 2; ++f) {
    aq[f][0] = *(const short8*)&Q[(long)(f*16 + fr)*p.ldq + fk];
    aq[f][1] = *(const short8*)&Q[(long)(f*16 + fr)*p.ldq + 32 + fk];
  }

  f32x4 acc[2][4] = {};
  float ml[2] = {-3e38f, -3e38f}, ll[2] = {0.f, 0.f};
  const float C = 0.125f * 1.44269504f;     // score-scale * log2(e)

  // staging roles: K coalesced rows; V key-pairs for packed transpose writes
  const int krow = t >> 2, kseg = (t & 3) * 16;
  const int vp = t & 31, vc = (t >> 5) * 8;

  short8 kr0, kr1, vr0, vr1;
  kr0 = *(const short8*)&K[(long)krow*p.ldkv + kseg];
  kr1 = *(const short8*)&K[(long)krow*p.ldkv + kseg + 8];
  vr0 = *(const short8*)&V[(long)(2*vp)*p.ldkv + vc];
  vr1 = *(const short8*)&V[(long)(2*vp + 1)*p.ldkv + vc];

  for (int it = 0; it < 16; ++it) {
    // ---- write staged regs to LDS ----
    *(short8*)&kt[krow][kseg]     = kr0;
    *(short8*)&kt[krow][kseg + 8] = kr1;
    #pragma unroll
    for (int e = 0; e < 8; ++e) {
      const uint32_t pk = (uint32_t)(uint16_t)vr0[e] | ((uint32_t)(uint16_t)vr1[e] << 16);
      *(uint32_t*)&vt[vc + e][2*vp] = pk;
    }
    __syncthreads();

    // ---- prefetch next tile into regs ----
    if (it + 1 < 16) {
      const int kn = (it + 1) * 64;
      kr0 = *(const short8*)&K[(long)(kn + krow)*p.ldkv + kseg];
      kr1 = *(const short8*)&K[(long)(kn + krow)*p.ldkv + kseg + 8];
      vr0 = *(const short8*)&V[(long)(kn + 2*vp)*p.ldkv + vc];
      vr1 = *(const short8*)&V[(long)(kn + 2*vp + 1)*p.ldkv + vc];
    }

    // ---- S^T = K Q^T: kt frags shared by both Q-frags ----
    f32x4 s[2][4] = {};
    __builtin_amdgcn_s_setprio(1);
    #pragma unroll
    for (int ni = 0; ni < 4; ++ni) {
      short8 bk0 = *(const short8*)&kt[ni*16 + fr][fk];
      short8 bk1 = *(const short8*)&kt[ni*16 + fr][32 + fk];
      #pragma unroll
      for (int f = 0; f < 2; ++f) {
        s[f][ni] = __builtin_amdgcn_mfma_f32_16x16x32_bf16(bk0, aq[f][0], s[f][ni], 0, 0, 0);
        s[f][ni] = __builtin_amdgcn_mfma_f32_16x16x32_bf16(bk1, aq[f][1], s[f][ni], 0, 0, 0);
      }
    }
    __builtin_amdgcn_s_setprio(0);

    // ---- online softmax per frag, lane-local row ----
    #pragma unroll
    for (int f = 0; f < 2; ++f) {
      float rm = s[f][0][0];
      #pragma unroll
      for (int ni = 0; ni < 4; ++ni)
        #pragma unroll
        for (int j = 0; j < 4; ++j) rm = fmaxf(rm, s[f][ni][j]);
      rm = fmaxf(rm, __shfl_xor(rm, 16, 64));
      rm = fmaxf(rm, __shfl_xor(rm, 32, 64));
      const float rml = rm * C;

      if (__any(rml > ml[f] + 11.5f)) {
        const float mnl = fmaxf(ml[f], rml);
        const float al = exp2f(ml[f] - mnl);
        const float a0 = __shfl(al, g*4 + 0, 64);
        const float a1 = __shfl(al, g*4 + 1, 64);
        const float a2 = __shfl(al, g*4 + 2, 64);
        const float a3 = __shfl(al, g*4 + 3, 64);
        #pragma unroll
        for (int nv = 0; nv < 4; ++nv) {
          acc[f][nv][0] *= a0; acc[f][nv][1] *= a1;
          acc[f][nv][2] *= a2; acc[f][nv][3] *= a3;
        }
        ll[f] *= al;
        ml[f] = mnl;
      }

      float rs = 0.f;
      u16 pb[4][4];
      #pragma unroll
      for (int ni = 0; ni < 4; ++ni)
        #pragma unroll
        for (int j = 0; j < 4; ++j) {
          const float pv = exp2f(s[f][ni][j]*C - ml[f]);
          rs += pv;
          pb[ni][j] = f2bf(pv);
        }
      rs += __shfl_xor(rs, 16, 64);
      rs += __shfl_xor(rs, 32, 64);
      ll[f] += rs;

      #pragma unroll
      for (int ni = 0; ni < 4; ++ni) {
        short4v pk4;
        pk4[0] = (short)pb[ni][0]; pk4[1] = (short)pb[ni][1];
        pk4[2] = (short)pb[ni][2]; pk4[3] = (short)pb[ni][3];
        *(short4v*)&pl[w4][f*16 + fr][ni*16 + g*4] = pk4;
      }
    }

    // ---- PV accumulate: vt frags shared by both Q-frags ----
    __builtin_amdgcn_s_setprio(1);
    #pragma unroll
    for (int ks = 0; ks < 2; ++ks) {
      short8 pa0 = *(const short8*)&pl[w4][fr][ks*32 + fk];
      short8 pa1 = *(const short8*)&pl[w4][16 + fr][ks*32 + fk];
      #pragma unroll
      for (int nv = 0; nv < 4; ++nv) {
        short8 bvv = *(const short8*)&vt[nv*16 + fr][ks*32 + fk];
        acc[0][nv] = __builtin_amdgcn_mfma_f32_16x16x32_bf16(pa0, bvv, acc[0][nv], 0, 0, 0);
        acc[1][nv] = __builtin_amdgcn_mfma_f32_16x16x32_bf16(pa1, bvv, acc[1][nv], 0, 0, 0);
      }
    }
    __builtin_amdgcn_s_setprio(0);
    __syncthreads();   // protect kt/vt before next tile's LDS writes
  }

  // ---- epilogue per frag ----
  u16* O = p.o + (long)wz*p.oB + (long)(qt*128 + w4*32)*p.ldo + h*64;
  #pragma unroll
  for (int f = 0; f < 2; ++f) {
    const float l0 = __shfl(ll[f], g*4 + 0, 64);
    const float l1 = __shfl(ll[f], g*4 + 1, 64);
    const float l2 = __shfl(ll[f], g*4 + 2, 64);
    const float l3 = __shfl(ll[f], g*4 + 3, 64);
    const float inv[4] = {1.f/l0, 1.f/l1, 1.f/l2, 1.f/l3};
    #pragma unroll
    for (int j = 0; j < 4; ++j)
      #pragma unroll
      for (int nv = 0; nv < 4; ++nv)
        O[(long)(f*16 + g*4 + j)*p.ldo + nv*16 + fr] = f2bf(acc[f][nv][j] * inv[j]);
  }
}

// -------- qs = sum_query @ wq^T + bq  (grid 16, 256 thr, k-split) --------
__global__ void gemv_qs(const float* sq, const float* w, const float* b, float* out) {
  const int t = threadIdx.x, nl = t & 63, kq = t >> 6;
  const int n = blockIdx.x*64 + nl;
  const float* row = w + (long)n * 1024 + kq*256;
  const float* q = sq + kq*256;
  float s = 0.f;
  for (int k = 0; k < 256; k += 4) {
    float4 ww = *(const float4*)&row[k];
    float4 qq = *(const float4*)&q[k];
    s += qq.x*ww.x + qq.y*ww.y + qq.z*ww.z + qq.w*ww.w;
  }
  __shared__ float ps[4][64];
  ps[kq][nl] = s;
  __syncthreads();
  if (t < 64) out[blockIdx.x*64 + t] = ps[0][t]+ps[1][t]+ps[2][t]+ps[3][t] + b[blockIdx.x*64 + t];
}

// ------- summary attention: block (h,w), 256 threads, k-parallel -------
__global__ void sum_attend(const float* qs, const u16* sumkv, float* content, float* pall) {
  const int h = blockIdx.x, w = blockIdx.y, t = threadIdx.x;
  const int lane = t & 63, wv = t >> 6;
  __shared__ float qsh[64];
  __shared__ float sc[1024];
  __shared__ float rmax[4], rsum[4];
  __shared__ float po[4][64];
  if (t < 64) qsh[t] = qs[h*64 + t];
  __syncthreads();
  const u16* kbase = sumkv + (long)w*2097152 + h*64;
  float e[4];
  float mx = -1e30f;
  #pragma unroll
  for (int j = 0; j < 4; ++j) {
    const int k = j*256 + t;
    const u16* krow = kbase + (long)k * 2048;
    float s = 0.f;
    #pragma unroll
    for (int d = 0; d < 64; d += 8) {
      ushort8 kk = *(const ushort8*)&krow[d];
      #pragma unroll
      for (int q = 0; q < 8; ++q) s += qsh[d+q] * b2f(kk[q]);
    }
    s *= 0.125f;
    e[j] = s;
    mx = fmaxf(mx, s);
  }
  #pragma unroll
  for (int o = 32; o; o >>= 1) mx = fmaxf(mx, __shfl_xor(mx, o, 64));
  if (lane == 0) rmax[wv] = mx;
  __syncthreads();
  mx = fmaxf(fmaxf(rmax[0],rmax[1]), fmaxf(rmax[2],rmax[3]));
  float sum = 0.f;
  #pragma unroll
  for (int j = 0; j < 4; ++j) { e[j] = __expf(e[j]-mx); sum += e[j]; }
  #pragma unroll
  for (int o = 32; o; o >>= 1) sum += __shfl_xor(sum, o, 64);
  if (lane == 0) rsum[wv] = sum;
  __syncthreads();
  const float inv = 1.f / (rsum[0]+rsum[1]+rsum[2]+rsum[3]);
  float* pr = pall + ((long)w*16 + h)*1024;
  #pragma unroll
  for (int j = 0; j < 4; ++j) {
    const int k = j*256 + t;
    const float pn = e[j]*inv;
    sc[k] = pn;
    pr[k] = pn;
  }
  __syncthreads();
  const u16* vbase = sumkv + (long)w*2097152 + 1024 + h*64;
  float o = 0.f;
  const int k0 = wv*256;
  for (int k = k0; k < k0+256; ++k) o += sc[k] * b2f(vbase[(long)k*2048 + lane]);
  po[wv][lane] = o;
  __syncthreads();
  if (t < 64) content[(long)w*1024 + h*64 + t] = po[0][t]+po[1][t]+po[2][t]+po[3][t];
}

__global__ void wavg_k(const float* pall, float* wavg) {
  const int w = blockIdx.y, k = blockIdx.x*256 + threadIdx.x;
  float s = 0.f;
  #pragma unroll
  for (int h = 0; h < 16; ++h) s += pall[((long)w*16 + h)*1024 + k];
  wavg[w*1024 + k] = s * (1.f/16.f);
}

// ------- content projection (grid (16,4), 256 thr, k-split) -------
__global__ void contproj_k(const float* content, const float* w_, const float* b, float* out) {
  const int w = blockIdx.y, t = threadIdx.x;
  const int nl = t & 63, kq = t >> 6;
  const int n = blockIdx.x*64 + nl;
  const float* c = content + w*1024 + kq*256;
  const float* row = w_ + (long)n * 1024 + kq*256;
  float s = 0.f;
  for (int k = 0; k < 256; k += 4) {
    float4 ww = *(const float4*)&row[k];
    s += c[k]*ww.x + c[k+1]*ww.y + c[k+2]*ww.z + c[k+3]*ww.w;
  }
  __shared__ float ps[4][64];
  ps[kq][nl] = s;
  __syncthreads();
  if (t < 64) out[w*1024 + blockIdx.x*64 + t] = ps[0][t]+ps[1][t]+ps[2][t]+ps[3][t] + b[blockIdx.x*64 + t];
}

// ------- attn_stats phase A: parallel rank-count (grid (16,4), 256 thr) -----
__global__ void stats1_k(const float* wavg, float* part) {
  const int c = blockIdx.x, w = blockIdx.y, t = threadIdx.x;
  __shared__ float a[1024];
  for (int i = t; i < 1024; i += 256) a[i] = wavg[w*1024 + i];
  __syncthreads();
  const int jl = t & 63, iq = t >> 6;
  const int j = c*64 + jl;
  const float aj = a[j];
  int pr = 0;
  const int i0 = iq*256;
  #pragma unroll 8
  for (int i = i0; i < i0+256; ++i) {
    const float ai = a[i];
    pr += (ai < aj) || (ai == aj && i < j);
  }
  __shared__ int prs[4][64];
  prs[iq][jl] = pr;
  __syncthreads();
  if (t < 64) {
    const int rank = 1 + prs[0][jl] + prs[1][jl] + prs[2][jl] + prs[3][jl];
    float ent = -aj * logf(aj + 1e-8f);
    float gnum = (float)rank * aj;
    float ssum = aj;
    float mx = aj;
    float top5 = (rank >= 1020) ? aj : 0.f;
    #pragma unroll
    for (int o = 32; o; o >>= 1) {
      ent += __shfl_xor(ent, o, 64);
      gnum += __shfl_xor(gnum, o, 64);
      ssum += __shfl_xor(ssum, o, 64);
      mx = fmaxf(mx, __shfl_xor(mx, o, 64));
      top5 += __shfl_xor(top5, o, 64);
    }
    if (t == 0) {
      float* pp = part + ((w*16 + c) * 5);
      pp[0]=ent; pp[1]=gnum; pp[2]=ssum; pp[3]=mx; pp[4]=top5;
    }
  }
}

// ------- attn_stats phase B: reduce 16 chunk-partials (grid 4, 128 thr) -----
__global__ void stats2_k(const float* part, float* stats) {
  const int w = blockIdx.x, t = threadIdx.x;
  const int c = t & 15, stat = t >> 4;
  float v = 0.f;
  const bool active = stat < 5;
  if (active) v = part[(w*16 + c)*5 + stat];
  #pragma unroll
  for (int o = 8; o; o >>= 1) {
    const float ov = __shfl_xor(v, o, 64);
    v = (stat == 3) ? fmaxf(v, ov) : (v + ov);
  }
  __shared__ float r5[5];
  if (active && c == 0) r5[stat] = v;
  __syncthreads();
  if (t == 0) {
    stats[w*4+0] = r5[0];
    stats[w*4+1] = 2.f*r5[1]/(1024.f*r5[2] + 1e-8f) - 1025.f/1024.f;
    stats[w*4+2] = r5[3];
    stats[w*4+3] = r5[4];
  }
}

// ------- pat MLP + summary combine (grid 4, 256 thr, k-split) -------
__global__ void patsum_k(const float* stats, const float* contprj,
                         const float* pw1, const float* pb1, const float* pw2, const float* pb2,
                         const float* combw, const float* combb, float* summ) {
  const int w = blockIdx.x, t = threadIdx.x;
  const int nl = t & 63, kq = t >> 6;
  __shared__ float p1[64], pat[64];
  __shared__ float ps[4][64];
  __shared__ float ps2[4][64];
  if (t < 64) {
    float s = 0.f;
    #pragma unroll
    for (int k = 0; k < 4; ++k) s += stats[w*4+k] * pw1[t*4+k];
    p1[t] = fmaxf(s + pb1[t], 0.f);
  }
  __syncthreads();
  {
    float s = 0.f;
    const float* rw = pw2 + (long)nl*64 + kq*16;
    const float* pp = p1 + kq*16;
    #pragma unroll
    for (int k = 0; k < 16; ++k) s += pp[k] * rw[k];
    ps[kq][nl] = s;
  }
  __syncthreads();
  if (t < 64) pat[t] = ps[0][t]+ps[1][t]+ps[2][t]+ps[3][t] + pb2[t];
  __syncthreads();
  const float* c = contprj + w*1024;
  const float* row = combw + (long)nl * 1088;
  float s = 0.f;
  const int k0 = kq*272;
  for (int k = k0; k < k0+272; ++k) {
    const float rv = row[k];
    const float cv = (k < 1024) ? c[k] : pat[k-1024];
    s += cv * rv;
  }
  ps2[kq][nl] = s;
  __syncthreads();
  if (t < 64) summ[w*64 + t] = ps2[0][t]+ps2[1][t]+ps2[2][t]+ps2[3][t] + combb[t];
}

// ---------------- meta attention + routing (1 block, 64 threads) ------------
__global__ void meta_k(const float* summ, const float* miw, const float* mib,
                       const float* mow, const float* mob, const float* rw1, const float* rb1,
                       const float* rw2, const float* rb2, float* routing) {
  const int t = threadIdx.x;
  __shared__ float qkv[4][192];
  __shared__ float sc[64];
  __shared__ float o[4][64];
  __shared__ float rf[4][64];
  __shared__ float t1[4][64];
  __shared__ float lg[4];
  for (int idx = t; idx < 768; idx += 64) {
    const int w = idx / 192, rrow = idx % 192;
    const float* rw = miw + (long)rrow * 64;
    float s = 0.f;
    for (int k = 0; k < 64; ++k) s += summ[w*64+k] * rw[k];
    qkv[w][rrow] = s + mib[rrow];
  }
  __syncthreads();
  {
    const int h = t >> 4, i = (t >> 2) & 3, j = t & 3;
    float s = 0.f;
    #pragma unroll
    for (int d = 0; d < 16; ++d) s += qkv[i][h*16+d] * qkv[j][64 + h*16+d];
    sc[t] = s * 0.25f;
  }
  __syncthreads();
  if (t < 16) {
    const float a0=sc[t*4], a1=sc[t*4+1], a2=sc[t*4+2], a3=sc[t*4+3];
    const float m = fmaxf(fmaxf(a0,a1), fmaxf(a2,a3));
    const float e0=__expf(a0-m), e1=__expf(a1-m), e2=__expf(a2-m), e3=__expf(a3-m);
    const float s = e0+e1+e2+e3;
    sc[t*4]=e0/s; sc[t*4+1]=e1/s; sc[t*4+2]=e2/s; sc[t*4+3]=e3/s;
  }
  __syncthreads();
  for (int idx = t; idx < 256; idx += 64) {
    const int i = idx >> 6, c = idx & 63, h = c >> 4;
    float s = 0.f;
    #pragma unroll
    for (int j = 0; j < 4; ++j) s += sc[(h*4+i)*4+j] * qkv[j][128 + c];
    o[i][c] = s;
  }
  __syncthreads();
  for (int idx = t; idx < 256; idx += 64) {
    const int i = idx >> 6, n = idx & 63;
    const float* rw = mow + (long)n * 64;
    float s = 0.f;
    for (int k = 0; k < 64; ++k) s += o[i][k] * rw[k];
    rf[i][n] = s + mob[n];
  }
  __syncthreads();
  for (int idx = t; idx < 256; idx += 64) {
    const int i = idx >> 6, n = idx & 63;
    const float* rw = rw1 + (long)n * 64;
    float s = 0.f;
    for (int k = 0; k < 64; ++k) s += rf[i][k] * rw[k];
    t1[i][n] = fmaxf(s + rb1[n], 0.f);
  }
  __syncthreads();
  if (t < 4) {
    float s = 0.f;
    for (int k = 0; k < 64; ++k) s += t1[t][k] * rw2[k];
    lg[t] = s + rb2[0];
  }
  __syncthreads();
  if (t == 0) {
    const float m = fmaxf(fmaxf(lg[0],lg[1]), fmaxf(lg[2],lg[3]));
    float e[4], s = 0.f;
    #pragma unroll
    for (int i = 0; i < 4; ++i) { e[i] = __expf(lg[i]-m); s += e[i]; }
    #pragma unroll
    for (int i = 0; i < 4; ++i) routing[i] = e[i]/s;
  }
}

// ---------------- routing-weighted kv mix ----------------
__global__ void kvr_k(const u16* local, const float* routing, u16* kvr) {
  const int r = blockIdx.y;
  const long e = ((long)blockIdx.x*256 + threadIdx.x) * 8;
  float rm[4]; float s = 0.f;
  #pragma unroll
  for (int w = 0; w < 4; ++w) { rm[w] = (w == r) ? 0.f : routing[w]; s += rm[w]; }
  const float inv = 1.f / (s + 1e-8f);
  ushort8 a0 = *(const ushort8*)&local[e];
  ushort8 a1 = *(const ushort8*)&local[1048576 + e];
  ushort8 a2 = *(const ushort8*)&local[2097152 + e];
  ushort8 a3 = *(const ushort8*)&local[3145728 + e];
  ushort8 out;
  #pragma unroll
  for (int j = 0; j < 8; ++j)
    out[j] = f2b((rm[0]*b2f(a0[j]) + rm[1]*b2f(a1[j]) + rm[2]*b2f(a2[j]) + rm[3]*b2f(a3[j])) * inv);
  *(ushort8*)&kvr[(long)r*1048576 + e] = out;
}

// ---------------------------------------------------------------------------
static void gemm1(hipStream_t st, dim3 grid,
                  const u16* A, long lda, const u16* B, long ldb,
                  u16* C, long ldc, const float* bias,
                  int K, int N, float scale, int act, int outf) {
  GemmP p = {};
  p.A=A; p.B=B; p.C=C; p.bias=bias;
  p.lda=lda; p.ldb=ldb; p.ldc=ldc;
  p.K=K; p.Nstore=N; p.ySplit=1<<30; p.act=act; p.outf=outf; p.scale=scale;
  gemm_nt<<<grid, dim3(512), 0, st>>>(p);
}

extern "C" void kernel_launch(void* const* d_in, const int* in_sizes, int n_in,
                              void* d_out, int out_size, void* d_ws, size_t ws_size,
                              hipStream_t stream) {
  (void)in_sizes; (void)n_in; (void)out_size; (void)ws_size;
  const float* x   = (const float*)d_in[0];
  const float* liw = (const float*)d_in[1];
  const float* lib = (const float*)d_in[2];
  const float* low = (const float*)d_in[3];
  const float* lob = (const float*)d_in[4];
  const float* sq  = (const float*)d_in[5];
  const float* siw = (const float*)d_in[6];
  const float* sib = (const float*)d_in[7];
  const float* sow = (const float*)d_in[8];
  const float* sob = (const float*)d_in[9];
  const float* pw1 = (const float*)d_in[10];
  const float* pb1 = (const float*)d_in[11];
  const float* pw2 = (const float*)d_in[12];
  const float* pb2 = (const float*)d_in[13];
  const float* cbw = (const float*)d_in[14];
  const float* cbb = (const float*)d_in[15];
  const float* miw = (const float*)d_in[16];
  const float* mib = (const float*)d_in[17];
  const float* mow = (const float*)d_in[18];
  const float* mob = (const float*)d_in[19];
  const float* rw1 = (const float*)d_in[20];
  const float* rb1 = (const float*)d_in[21];
  const float* rw2 = (const float*)d_in[22];
  const float* rb2 = (const float*)d_in[23];
  const float* ciw = (const float*)d_in[24];
  const float* cib = (const float*)d_in[25];
  const float* cow = (const float*)d_in[26];
  const float* cob = (const float*)d_in[27];
  const float* gw  = (const float*)d_in[28];
  const float* gb  = (const float*)d_in[29];
  const float* pw  = (const float*)d_in[30];
  const float* pb  = (const float*)d_in[31];

  char* ws = (char*)d_ws;
  u16* qkv    = (u16*)(ws + 0);
  u16* aout   = (u16*)(ws + 25165824);
  u16* local  = (u16*)(ws + 33554432);
  u16* scratch= (u16*)(ws + 41943040);
  u16* s2048  = (u16*)(ws + 79691776);
  u16* cq     = (u16*)(ws + 96468992);
  u16* kvr    = (u16*)(ws + 104857600);
  u16* crossb = (u16*)(ws + 113246208);
  char* sf = ws + 121634816;
  float* qs      = (float*)(sf + 0);
  float* pall    = (float*)(sf + 4096);
  float* wavg    = (float*)(sf + 266240);
  float* content = (float*)(sf + 282624);
  float* contprj = (float*)(sf + 299008);
  float* stats   = (float*)(sf + 315392);
  float* summ    = (float*)(sf + 315456);
  float* routing = (float*)(sf + 316480);
  float* part    = (float*)(sf + 316544);
  u16* siwkvb = (u16*)(ws + 122028032);
  u16* lowb   = (u16*)(ws + 126222336);
  u16* ciwb   = (u16*)(ws + 128319488);
  u16* cowb   = (u16*)(ws + 134610944);
  u16* gwb    = (u16*)(ws + 136708096);
  u16* pwb    = (u16*)(ws + 140902400);
  u16* xb   = crossb;
  u16* liwb = scratch;

  // 0. fp32 -> bf16 conversions
  CvtP cp;
  cp.src[0]=x;   cp.dst[0]=xb;     cp.n[0]=4194304;
  cp.src[1]=liw; cp.dst[1]=liwb;   cp.n[1]=3145728;
  cp.src[2]=low; cp.dst[2]=lowb;   cp.n[2]=1048576;
  cp.src[3]=siw+1048576; cp.dst[3]=siwkvb; cp.n[3]=2097152;
  cp.src[4]=ciw; cp.dst[4]=ciwb;   cp.n[4]=3145728;
  cp.src[5]=cow; cp.dst[5]=cowb;   cp.n[5]=1048576;
  cp.src[6]=gw;  cp.dst[6]=gwb;    cp.n[6]=2097152;
  cp.src[7]=pw;  cp.dst[7]=pwb;    cp.n[7]=1048576;
  cvt_multi<<<dim3(2048, 8), dim3(256), 0, stream>>>(cp);

  // 1. local QKV projection
  gemm1(stream, dim3(32,24), xb,1024, liwb,1024, qkv,3072, lib, 1024, 3072, 1.f, 0, 0);

  // 2. fused local self-attention (XCD-swizzled 1-D grid)
  {
    FlashP fp;
    fp.q = qkv; fp.k = qkv + 1024; fp.v = qkv + 2048; fp.o = aout;
    fp.ldq = 3072; fp.ldkv = 3072; fp.ldo = 1024;
    fp.qB = 3145728; fp.kvB = 3145728; fp.oB = 1048576;
    flash_k<<<dim3(512), dim3(256), 0, stream>>>(fp);
  }

  // 3. local out-projection
  gemm1(stream, dim3(32,8), aout,1024, lowb,1024, local,1024, lob, 1024, 1024, 1.f, 0, 0);

  // 4. combined crossQ (y<8) + summary K/V (y>=8) projections
  {
    GemmP p = {};
    p.A = local; p.lda = 1024; p.K = 1024; p.scale = 1.f;
    p.B = ciwb;   p.C = cq;    p.bias = cib;      p.ldb = 1024; p.ldc = 1024; p.Nstore = 1024;
    p.B2 = siwkvb; p.C2 = s2048; p.bias2 = sib+1024; p.ldb2 = 1024; p.ldc2 = 2048; p.Nstore2 = 2048;
    p.ySplit = 8;
    gemm_nt<<<dim3(32,24), dim3(512), 0, stream>>>(p);
  }

  // 5. summaries
  gemv_qs<<<dim3(16), dim3(256), 0, stream>>>(sq, siw, sib, qs);
  sum_attend<<<dim3(16,4), dim3(256), 0, stream>>>(qs, s2048, content, pall);
  wavg_k<<<dim3(4,4), dim3(256), 0, stream>>>(pall, wavg);
  contproj_k<<<dim3(16,4), dim3(256), 0, stream>>>(content, sow, sob, contprj);
  stats1_k<<<dim3(16,4), dim3(256), 0, stream>>>(wavg, part);
  stats2_k<<<dim3(4), dim3(128), 0, stream>>>(part, stats);
  patsum_k<<<dim3(4), dim3(256), 0, stream>>>(stats, contprj, pw1, pb1, pw2, pb2, cbw, cbb, summ);

  // 6. meta attention + routing
  meta_k<<<dim3(1), dim3(64), 0, stream>>>(summ, miw, mib, mow, mob, rw1, rb1, rw2, rb2, routing);

  // 7. per-rank mixed kv
  kvr_k<<<dim3(512,4), dim3(256), 0, stream>>>(local, routing, kvr);

  // 8. cross K/V projection
  gemm1(stream, dim3(32,16), kvr,1024, ciwb+1048576,1024, s2048,2048, cib+1024, 1024, 2048, 1.f, 0, 0);

  // 9. fused cross attention (XCD-swizzled 1-D grid)
  {
    FlashP fp;
    fp.q = cq; fp.k = s2048; fp.v = s2048 + 1024; fp.o = aout;
    fp.ldq = 1024; fp.ldkv = 2048; fp.ldo = 1024;
    fp.qB = 1048576; fp.kvB = 2097152; fp.oB = 1048576;
    flash_k<<<dim3(512), dim3(256), 0, stream>>>(fp);
  }

  // 10. cross out-projection
  gemm1(stream, dim3(32,8), aout,1024, cowb,1024, crossb,1024, cob, 1024, 1024, 1.f, 0, 0);

  // 11. gate GEMM (dual-K: local@gw_l + cross@gw_c) with fused sigmoid+comb
  {
    GemmP p = {};
    p.A = local; p.A2 = crossb; p.lr = local; p.cr = crossb;
    p.B = gwb; p.C = kvr; p.bias = gb;
    p.lda = 1024; p.ldb = 2048; p.ldc = 1024;
    p.K = 1024; p.Nstore = 1024; p.ySplit = 1<<30; p.act = 2; p.outf = 0; p.scale = 1.f;
    gemm_nt<<<dim3(32,8), dim3(512), 0, stream>>>(p);
  }

  // 12. final projection -> d_out (fp32)
  gemm1(stream, dim3(32,8), kvr,1024, pwb,1024, (u16*)d_out,1024, pb, 1024, 1024, 1.f, 0, 1);
}